// Round 6
// baseline (2374.807 us; speedup 1.0000x reference)
//
#include <hip/hip_runtime.h>
#include <hip/hip_bf16.h>
#include <cstdint>
#include <cstddef>

#define BATCH 4096
#define DIM   2048
#define FEAT  16384

typedef __attribute__((ext_vector_type(8))) short s8v;
typedef __attribute__((ext_vector_type(8))) _Float16 h8v;
typedef __attribute__((ext_vector_type(4))) float f4v;

__device__ __forceinline__ unsigned short f2bf(float f){
  unsigned u = __float_as_uint(f);
  unsigned r = u + 0x7FFFu + ((u >> 16) & 1u);
  return (unsigned short)(r >> 16);
}
__device__ __forceinline__ float bf2f(unsigned short h){
  return __uint_as_float(((unsigned)h) << 16);
}
__device__ __forceinline__ void split3(float v, unsigned short &h, unsigned short &m, unsigned short &l){
  h = f2bf(v);
  float r1 = v - bf2f(h);
  m = f2bf(r1);
  float r2 = r1 - bf2f(m);
  l = f2bf(r2);
}

// fp16 2-way split: v = h + l/2048 (l stored x2048 to stay in normal range)
__device__ __forceinline__ void split2(float v, unsigned short &h, unsigned short &l){
  _Float16 hf = (_Float16)v;
  _Float16 lf = (_Float16)((v - (float)hf) * 2048.0f);
  h = __builtin_bit_cast(unsigned short, hf);
  l = __builtin_bit_cast(unsigned short, lf);
}

__device__ __forceinline__ void gload16(const void* g, void* l){
  __builtin_amdgcn_global_load_lds(
      (const __attribute__((address_space(1))) void*)g,
      (__attribute__((address_space(3))) void*)l, 16, 0, 0);
}

// ===========================================================================
// PATH A: fp16 2-split planes + FUSED dual-GEMM (acts + kest in one kernel)
// ===========================================================================

// x -> 2 fp16 planes of (x - b_dec)
__global__ __launch_bounds__(256)
void splitX(const float* __restrict__ x, const float* __restrict__ bdec,
            unsigned short* __restrict__ p0, unsigned short* __restrict__ p1)
{
  const size_t i = ((size_t)blockIdx.x * 256 + threadIdx.x) * 4;
  const int col = (int)(i & (DIM - 1));
  const float4 v = *(const float4*)(x + i);
  const float4 b = *(const float4*)(bdec + col);
  float e0 = v.x - b.x, e1 = v.y - b.y, e2 = v.z - b.z, e3 = v.w - b.w;
  ushort4 H, L;
  split2(e0, H.x, L.x); split2(e1, H.y, L.y);
  split2(e2, H.z, L.z); split2(e3, H.w, L.w);
  *(ushort4*)(p0 + i) = H; *(ushort4*)(p1 + i) = L;
}

// W -> 2 fp16 planes
__global__ __launch_bounds__(256)
void splitW(const float* __restrict__ w,
            unsigned short* __restrict__ p0, unsigned short* __restrict__ p1)
{
  const size_t i = ((size_t)blockIdx.x * 256 + threadIdx.x) * 4;
  const float4 v = *(const float4*)(w + i);
  ushort4 H, L;
  split2(v.x, H.x, L.x); split2(v.y, H.y, L.y);
  split2(v.z, H.z, L.z); split2(v.w, H.w, L.w);
  *(ushort4*)(p0 + i) = H; *(ushort4*)(p1 + i) = L;
}

// Fused dual GEMM: C1 = A*B1^T (-> relu+bias -> acts), C2 = A*B2^T (-> kest zpart)
// A = x planes (gload16-staged), B1 = Wenc planes (gload16-staged),
// B2 = Wk1 fp32 (reg-staged + in-kernel split2 + swizzled ds_write, T14 split).
// 8 waves: wv<4 -> C1, wv>=4 -> C2. 128x128 tiles, BK=32, LDS dbuf 2x48KB.
// Per product: C = hh + (hl + lh)/2048. Swapped-operand MFMA -> row-major C frag.
__global__ __launch_bounds__(512, 2)
void gemmf(const unsigned short* __restrict__ Ah_, const unsigned short* __restrict__ Al_,
           const unsigned short* __restrict__ B1h_, const unsigned short* __restrict__ B1l_,
           const float* __restrict__ Wk1,
           const float* __restrict__ benc, const float* __restrict__ bk1,
           const float* __restrict__ w2,
           float* __restrict__ acts, float* __restrict__ zpart)
{
  extern __shared__ char smem[];           // 2 bufs x (3 mats x 128 rows x 128 B) = 96 KB
  const int tid  = threadIdx.x;
  const int lane = tid & 63, wv = tid >> 6;          // wv 0..7

  // XCD walk (round-4/5 proven): per XCD 8x8 block squares
  const int bid = blockIdx.x;
  const int xcd = bid & 7;
  const int idx = bid >> 3;          // [0,512)
  const int sq  = idx >> 6;          // [0,8)
  const int s   = idx & 63;
  const int bx  = (xcd << 4) | ((sq & 1) << 3) | (s & 7);   // [0,128)
  const int by  = ((sq >> 1) << 3) | (s >> 3);              // [0,32)
  const int row0 = by << 7, col0 = bx << 7;

  const int role = wv >> 2;                 // 0: acts GEMM, 1: kest GEMM
  const int wloc = wv & 3;
  const int wr = (wloc & 1) << 6, wc = (wloc >> 1) << 6;

  f4v acc[4][4], acc2[4][4];
  #pragma unroll
  for (int i = 0; i < 4; ++i)
    #pragma unroll
    for (int j = 0; j < 4; ++j){
      acc[i][j]  = (f4v){0.f, 0.f, 0.f, 0.f};
      acc2[i][j] = (f4v){0.f, 0.f, 0.f, 0.f};
    }

  // ---- gload staging precompute: A (16 chunks) + B1 (16 chunks), 4/wave ----
  const unsigned short* gsrc[4];
  unsigned ldsoff[4];
  #pragma unroll
  for (int j = 0; j < 4; ++j){
    const int q = (wv << 2) + j;       // 0..31
    const int mat = q >> 4;            // 0=A, 1=B1
    const int chunk = q & 15;
    const int r  = (chunk << 3) + (lane >> 3);
    const int gl = (lane & 7) ^ (r & 7);
    const int co = (gl & 3) << 3;
    const unsigned short* hi = (mat == 0) ? Ah_ : B1h_;
    const unsigned short* lo = (mat == 0) ? Al_ : B1l_;
    const int rowg = ((mat == 0) ? row0 : col0) + r;
    gsrc[j]  = ((gl < 4) ? hi : lo) + (size_t)rowg * DIM + co;
    ldsoff[j] = (unsigned)(mat * 16384 + chunk * 1024);
  }

  // ---- B2 (Wk1 fp32) reg-staging precompute: 2 float4 chunks/thread ----
  const float* b2src[2];
  unsigned b2hi[2], b2lo[2];
  #pragma unroll
  for (int c = 0; c < 2; ++c){
    const int cc  = (tid << 1) + c;        // 0..1023
    const int r   = cc >> 3;               // 0..127
    const int cb4 = (cc & 7) << 2;         // 0,4,...,28
    const int glh = cb4 >> 3;              // 0..3
    const int ph  = glh ^ (r & 7);
    const int pl  = (glh + 4) ^ (r & 7);
    b2src[c] = Wk1 + (size_t)(col0 + r) * DIM + cb4;
    b2hi[c] = (unsigned)(2 * 16384 + r * 128 + ph * 16 + ((cb4 & 7) << 1));
    b2lo[c] = (unsigned)(2 * 16384 + r * 128 + pl * 16 + ((cb4 & 7) << 1));
  }

  const int fr16 = lane & 15;
  const int kg   = lane >> 4;
  const int bmat = 1 + role;
  int ra[4], rb[4];
  #pragma unroll
  for (int f = 0; f < 4; ++f){ ra[f] = wr + (f << 4) + fr16; rb[f] = wc + (f << 4) + fr16; }

  #define LDFRAG(bf, mat, r, hb) \
    (*(const h8v*)(smem + (bf) * 49152 + (mat) * 16384 + (r) * 128 + (((((hb) + kg) ^ ((r) & 7)) << 4))))

  float4 b2v[2];
  #define STAGE_LOAD(bf, ko)                                                   \
    {                                                                          \
      _Pragma("unroll")                                                        \
      for (int j = 0; j < 4; ++j)                                              \
        gload16(gsrc[j] + (ko), smem + (bf) * 49152 + ldsoff[j]);              \
      b2v[0] = *(const float4*)(b2src[0] + (ko));                              \
      b2v[1] = *(const float4*)(b2src[1] + (ko));                              \
    }
  #define STAGE_WRITE(bf)                                                      \
    {                                                                          \
      _Pragma("unroll")                                                        \
      for (int c = 0; c < 2; ++c){                                             \
        ushort4 H, L;                                                          \
        split2(b2v[c].x, H.x, L.x); split2(b2v[c].y, H.y, L.y);                \
        split2(b2v[c].z, H.z, L.z); split2(b2v[c].w, H.w, L.w);                \
        *(ushort4*)(smem + (bf) * 49152 + b2hi[c]) = H;                        \
        *(ushort4*)(smem + (bf) * 49152 + b2lo[c]) = L;                        \
      }                                                                        \
    }

  int cur = 0;
  STAGE_LOAD(0, 0);
  STAGE_WRITE(0);
  __syncthreads();

  for (int kt = 0; kt < DIM / 32; ++kt){
    const bool haveNext = (kt < DIM / 32 - 1);
    if (haveNext) STAGE_LOAD(cur ^ 1, (kt + 1) << 5);

    h8v Ahf[4], Bhf[4], Xl[4];
    #pragma unroll
    for (int f = 0; f < 4; ++f) Ahf[f] = LDFRAG(cur, 0, ra[f], 0);
    #pragma unroll
    for (int f = 0; f < 4; ++f) Bhf[f] = LDFRAG(cur, bmat, rb[f], 0);
    __builtin_amdgcn_s_setprio(1);
    #pragma unroll
    for (int fi = 0; fi < 4; ++fi)
      #pragma unroll
      for (int fj = 0; fj < 4; ++fj)
        acc[fi][fj] = __builtin_amdgcn_mfma_f32_16x16x32_f16(Bhf[fj], Ahf[fi], acc[fi][fj], 0, 0, 0);
    #pragma unroll
    for (int f = 0; f < 4; ++f) Xl[f] = LDFRAG(cur, 0, ra[f], 4);   // A lo
    #pragma unroll
    for (int fi = 0; fi < 4; ++fi)
      #pragma unroll
      for (int fj = 0; fj < 4; ++fj)
        acc2[fi][fj] = __builtin_amdgcn_mfma_f32_16x16x32_f16(Bhf[fj], Xl[fi], acc2[fi][fj], 0, 0, 0);
    #pragma unroll
    for (int f = 0; f < 4; ++f) Xl[f] = LDFRAG(cur, bmat, rb[f], 4); // B lo
    #pragma unroll
    for (int fi = 0; fi < 4; ++fi)
      #pragma unroll
      for (int fj = 0; fj < 4; ++fj)
        acc2[fi][fj] = __builtin_amdgcn_mfma_f32_16x16x32_f16(Xl[fj], Ahf[fi], acc2[fi][fj], 0, 0, 0);
    __builtin_amdgcn_s_setprio(0);

    if (haveNext) STAGE_WRITE(cur ^ 1);
    __syncthreads();
    cur ^= 1;
  }
  #undef LDFRAG
  #undef STAGE_LOAD
  #undef STAGE_WRITE

  // Swapped-operand C frag: lane holds C[m = lane&15][n = (lane>>4)*4 + reg]
  const float LSC = 1.0f / 2048.0f;
  const int mloc = lane & 15;
  const int nq   = (lane >> 4) << 2;   // 0,4,8,12
  if (role == 0){
    #pragma unroll
    for (int fi = 0; fi < 4; ++fi){
      const int grow = row0 + wr + (fi << 4) + mloc;
      #pragma unroll
      for (int fj = 0; fj < 4; ++fj){
        const int gcol = col0 + wc + (fj << 4) + nq;
        const float4 be = *(const float4*)(benc + gcol);
        f4v v;
        v[0] = fmaxf(acc[fi][fj][0] + LSC * acc2[fi][fj][0] + be.x, 0.f);
        v[1] = fmaxf(acc[fi][fj][1] + LSC * acc2[fi][fj][1] + be.y, 0.f);
        v[2] = fmaxf(acc[fi][fj][2] + LSC * acc2[fi][fj][2] + be.z, 0.f);
        v[3] = fmaxf(acc[fi][fj][3] + LSC * acc2[fi][fj][3] + be.w, 0.f);
        *(f4v*)(acts + (size_t)grow * FEAT + gcol) = v;
      }
    }
  } else {
    #pragma unroll
    for (int fi = 0; fi < 4; ++fi){
      float ssum = 0.f;
      #pragma unroll
      for (int fj = 0; fj < 4; ++fj){
        const int gcol = col0 + wc + (fj << 4) + nq;
        const float4 be = *(const float4*)(bk1 + gcol);
        const float4 wk = *(const float4*)(w2 + gcol);
        float h0 = fmaxf(acc[fi][fj][0] + LSC * acc2[fi][fj][0] + be.x, 0.f);
        float h1 = fmaxf(acc[fi][fj][1] + LSC * acc2[fi][fj][1] + be.y, 0.f);
        float h2 = fmaxf(acc[fi][fj][2] + LSC * acc2[fi][fj][2] + be.z, 0.f);
        float h3 = fmaxf(acc[fi][fj][3] + LSC * acc2[fi][fj][3] + be.w, 0.f);
        ssum = fmaf(h0, wk.x, ssum);
        ssum = fmaf(h1, wk.y, ssum);
        ssum = fmaf(h2, wk.z, ssum);
        ssum = fmaf(h3, wk.w, ssum);
      }
      ssum += __shfl_xor(ssum, 16);
      ssum += __shfl_xor(ssum, 32);
      if (lane < 16){
        const int grow = row0 + wr + (fi << 4) + lane;
        zpart[(size_t)grow * 256 + (bx << 1) + (wc >> 6)] = ssum;
      }
    }
  }
}

// ===========================================================================
// PATH B (fallback, proven round-1): on-the-fly bf16 3-split GEMM
// ===========================================================================
template<int MODE>
__global__ __launch_bounds__(256)
void gemm6(const float* __restrict__ X, const float* __restrict__ bsub,
           const float* __restrict__ W, const float* __restrict__ bias,
           const float* __restrict__ w2, float* __restrict__ acts,
           float* __restrict__ zpart)
{
  __shared__ unsigned short sA[3][128][32];
  __shared__ unsigned short sB[3][128][32];
  const int tid  = threadIdx.x;
  const int row0 = blockIdx.y << 7;
  const int col0 = blockIdx.x << 7;
  const int lane = tid & 63, wv = tid >> 6;
  const int wr = (wv & 1) << 6, wc = (wv >> 1) << 6;
  const int fr = lane & 15;
  const int gsw = (((lane >> 4) ^ ((fr >> 1) & 3)) << 3);

  f4v acc[4][4];
  #pragma unroll
  for (int i = 0; i < 4; ++i)
    #pragma unroll
    for (int j = 0; j < 4; ++j)
      acc[i][j] = (f4v){0.f, 0.f, 0.f, 0.f};

  const int rs = tid >> 3;
  const int cb = (tid & 7) << 2;
  const int gq = cb >> 3;

  for (int kt = 0; kt < DIM / 32; ++kt){
    const int k0 = kt << 5;
    #pragma unroll
    for (int i = 0; i < 4; ++i){
      const int r  = (i << 5) + rs;
      const int cs = ((gq ^ ((r >> 1) & 3)) << 3) + (cb & 7);
      {
        const float4 xv = *(const float4*)(X + (size_t)(row0 + r) * DIM + k0 + cb);
        const float4 bd = *(const float4*)(bsub + k0 + cb);
        float v0 = xv.x - bd.x, v1 = xv.y - bd.y, v2 = xv.z - bd.z, v3 = xv.w - bd.w;
        ushort4 H, M, L;
        split3(v0, H.x, M.x, L.x); split3(v1, H.y, M.y, L.y);
        split3(v2, H.z, M.z, L.z); split3(v3, H.w, M.w, L.w);
        *(ushort4*)&sA[0][r][cs] = H;
        *(ushort4*)&sA[1][r][cs] = M;
        *(ushort4*)&sA[2][r][cs] = L;
      }
      {
        const float4 wv4 = *(const float4*)(W + (size_t)(col0 + r) * DIM + k0 + cb);
        ushort4 H, M, L;
        split3(wv4.x, H.x, M.x, L.x); split3(wv4.y, H.y, M.y, L.y);
        split3(wv4.z, H.z, M.z, L.z); split3(wv4.w, H.w, M.w, L.w);
        *(ushort4*)&sB[0][r][cs] = H;
        *(ushort4*)&sB[1][r][cs] = M;
        *(ushort4*)&sB[2][r][cs] = L;
      }
    }
    __syncthreads();
    #pragma unroll
    for (int pa = 0; pa < 3; ++pa){
      s8v a[4];
      #pragma unroll
      for (int fi = 0; fi < 4; ++fi)
        a[fi] = *(const s8v*)&sA[pa][wr + (fi << 4) + fr][gsw];
      #pragma unroll
      for (int pb = 0; pb < 3 - pa; ++pb){
        s8v b[4];
        #pragma unroll
        for (int fj = 0; fj < 4; ++fj)
          b[fj] = *(const s8v*)&sB[pb][wc + (fj << 4) + fr][gsw];
        #pragma unroll
        for (int fi = 0; fi < 4; ++fi)
          #pragma unroll
          for (int fj = 0; fj < 4; ++fj)
            acc[fi][fj] = __builtin_amdgcn_mfma_f32_16x16x32_bf16(a[fi], b[fj], acc[fi][fj], 0, 0, 0);
      }
    }
    __syncthreads();
  }

  const int rq = (lane >> 4) << 2;
  if (MODE == 0){
    #pragma unroll
    for (int fj = 0; fj < 4; ++fj){
      const int gcol = col0 + wc + (fj << 4) + fr;
      const float be = bias[gcol];
      #pragma unroll
      for (int fi = 0; fi < 4; ++fi){
        #pragma unroll
        for (int r = 0; r < 4; ++r){
          const int grow = row0 + wr + (fi << 4) + rq + r;
          float v = acc[fi][fj][r] + be;
          v = fmaxf(v, 0.f);
          acts[(size_t)grow * FEAT + gcol] = v;
        }
      }
    }
  } else {
    float be[4], wk[4];
    #pragma unroll
    for (int fj = 0; fj < 4; ++fj){
      const int gcol = col0 + wc + (fj << 4) + fr;
      be[fj] = bias[gcol];
      wk[fj] = w2[gcol];
    }
    #pragma unroll
    for (int fi = 0; fi < 4; ++fi){
      #pragma unroll
      for (int r = 0; r < 4; ++r){
        float s = 0.f;
        #pragma unroll
        for (int fj = 0; fj < 4; ++fj){
          float h = fmaxf(acc[fi][fj][r] + be[fj], 0.f);
          s = fmaf(h, wk[fj], s);
        }
        s += __shfl_xor(s, 1);
        s += __shfl_xor(s, 2);
        s += __shfl_xor(s, 4);
        s += __shfl_xor(s, 8);
        if (fr == 0){
          const int grow = row0 + wr + (fi << 4) + rq + r;
          zpart[(size_t)grow * 256 + (blockIdx.x << 1) + (wc >> 6)] = s;
        }
      }
    }
  }
}

// ===========================================================================
// shared tail kernels
// ===========================================================================
__global__ __launch_bounds__(256)
void zreduce(const float* __restrict__ zpart, const float* __restrict__ bk2,
             const int* __restrict__ kp, int* __restrict__ mrow)
{
  const int row  = blockIdx.x * 4 + (threadIdx.x >> 6);
  const int lane = threadIdx.x & 63;
  const float* zp = zpart + (size_t)row * 256;
  float s = zp[lane] + zp[lane + 64] + zp[lane + 128] + zp[lane + 192];
  s += __shfl_xor(s, 1);
  s += __shfl_xor(s, 2);
  s += __shfl_xor(s, 4);
  s += __shfl_xor(s, 8);
  s += __shfl_xor(s, 16);
  s += __shfl_xor(s, 32);
  if (lane == 0){
    float z = s + bk2[0];
    float kest = 2.f * (float)(*kp) * (1.f / (1.f + expf(-z)));
    int m = (int)ceilf(kest);
    m = min(max(m, 0), 128);
    mrow[row] = m;
  }
}

__device__ __forceinline__ void radix_find(int* hist, int nbins, int need, int tid,
                                           int* out3, int* blksum)
{
  const int per  = nbins >> 8;
  const int base = tid * per;
  int bs = 0;
  for (int j = 0; j < per; ++j) bs += hist[base + j];
  blksum[tid] = bs;
  __syncthreads();
  if (tid == 0){
    int a2 = 0;
    for (int t = 255; t >= 0; --t){ int v = blksum[t]; blksum[t] = a2; a2 += v; }
  }
  __syncthreads();
  int ch = blksum[tid];
  for (int j = per - 1; j >= 0; --j){
    const int b = base + j;
    const int c = hist[b];
    if (ch < need && need <= ch + c){ out3[0] = b; out3[1] = need - ch; out3[2] = ch; }
    ch += c;
  }
  __syncthreads();
}

__global__ __launch_bounds__(256)
void select_topk(const float* __restrict__ acts, const int* __restrict__ mrow,
                 int* __restrict__ selIdx, float* __restrict__ selVal)
{
  __shared__ int hist[2048];
  __shared__ int blksum[256];
  __shared__ int out3[4];
  __shared__ unsigned listU[2048];
  __shared__ int lcnt;

  const int row = blockIdx.x, tid = threadIdx.x;
  const int m = mrow[row];
  const float* rp = acts + (size_t)row * FEAT;

  for (int i = tid; i < 2048; i += 256) hist[i] = 0;
  __syncthreads();
  // pass 1 (vectorized): histogram of bits [31:21]
  for (int it = 0; it < 16; ++it){
    const int i4 = (it << 8) + tid;
    const uint4 u4 = *(const uint4*)(rp + ((size_t)i4 << 2));
    if (u4.x) atomicAdd(&hist[u4.x >> 21], 1);
    if (u4.y) atomicAdd(&hist[u4.y >> 21], 1);
    if (u4.z) atomicAdd(&hist[u4.z >> 21], 1);
    if (u4.w) atomicAdd(&hist[u4.w >> 21], 1);
  }
  __syncthreads();
  radix_find(hist, 2048, m, tid, out3, blksum);
  const int bin1 = out3[0];
  const int rem1 = out3[1];

  if (tid == 0) lcnt = 0;
  __syncthreads();
  // pass 2 (vectorized): collect bin1 candidates (values only)
  for (int it = 0; it < 16; ++it){
    const int i4 = (it << 8) + tid;
    const uint4 u4 = *(const uint4*)(rp + ((size_t)i4 << 2));
    if ((int)(u4.x >> 21) == bin1){ int p = atomicAdd(&lcnt, 1); if (p < 2048) listU[p] = u4.x; }
    if ((int)(u4.y >> 21) == bin1){ int p = atomicAdd(&lcnt, 1); if (p < 2048) listU[p] = u4.y; }
    if ((int)(u4.z >> 21) == bin1){ int p = atomicAdd(&lcnt, 1); if (p < 2048) listU[p] = u4.z; }
    if ((int)(u4.w >> 21) == bin1){ int p = atomicAdd(&lcnt, 1); if (p < 2048) listU[p] = u4.w; }
  }
  __syncthreads();
  const int L = min(lcnt, 2048);

  for (int i = tid; i < 2048; i += 256) hist[i] = 0;
  __syncthreads();
  for (int i = tid; i < L; i += 256) atomicAdd(&hist[(listU[i] >> 10) & 0x7FF], 1);
  __syncthreads();
  radix_find(hist, 2048, rem1, tid, out3, blksum);
  const int bin2 = out3[0];
  const int rem2 = out3[1];

  for (int i = tid; i < 1024; i += 256) hist[i] = 0;
  __syncthreads();
  for (int i = tid; i < L; i += 256){
    unsigned u = listU[i];
    if ((int)((u >> 10) & 0x7FF) == bin2) atomicAdd(&hist[u & 0x3FF], 1);
  }
  __syncthreads();
  radix_find(hist, 1024, rem2, tid, out3, blksum);
  const int bin3 = out3[0];
  const int mEq  = out3[1];

  const unsigned tbits = ((unsigned)bin1 << 21) | ((unsigned)bin2 << 10) | (unsigned)bin3;

  // pass 3 (unchanged, tie-exact): wave 0, deterministic index order
  if (tid < 64){
    const int base = row << 7;
    int cnt = 0;
    for (int c = 0; c < 256; ++c){
      const int i = (c << 6) + tid;
      const unsigned u = __float_as_uint(rp[i]);
      const bool g = (u > tbits);
      const unsigned long long mk = __ballot(g);
      if (g){
        int pos = cnt + __popcll(mk & ((1ull << tid) - 1ull));
        selIdx[base + pos] = i;
        selVal[base + pos] = __uint_as_float(u);
      }
      cnt += __popcll(mk);
    }
    int eqs = 0;
    for (int c = 0; c < 256 && eqs < mEq; ++c){
      const int i = (c << 6) + tid;
      const unsigned u = __float_as_uint(rp[i]);
      const bool e = (u == tbits);
      const unsigned long long mk = __ballot(e);
      if (e){
        int p = eqs + __popcll(mk & ((1ull << tid) - 1ull));
        if (p < mEq){
          selIdx[base + cnt + p] = i;
          selVal[base + cnt + p] = __uint_as_float(u);
        }
      }
      eqs += __popcll(mk);
    }
  }
}

__global__ __launch_bounds__(256)
void transpose_dec(const float* __restrict__ Wd, float* __restrict__ WdT)
{
  __shared__ float t[64][65];
  const int f0 = blockIdx.x << 6, d0 = blockIdx.y << 6;
  const int tx = threadIdx.x & 15, ty = threadIdx.x >> 4;
  #pragma unroll
  for (int r = 0; r < 4; ++r){
    const int d = ty + (r << 4);
    const float4 v = *(const float4*)(Wd + (size_t)(d0 + d) * FEAT + f0 + (tx << 2));
    t[d][(tx << 2) + 0] = v.x;
    t[d][(tx << 2) + 1] = v.y;
    t[d][(tx << 2) + 2] = v.z;
    t[d][(tx << 2) + 3] = v.w;
  }
  __syncthreads();
  #pragma unroll
  for (int r = 0; r < 4; ++r){
    const int f = ty + (r << 4);
    float4 o;
    o.x = t[(tx << 2) + 0][f];
    o.y = t[(tx << 2) + 1][f];
    o.z = t[(tx << 2) + 2][f];
    o.w = t[(tx << 2) + 3][f];
    *(float4*)(WdT + (size_t)(f0 + f) * DIM + d0 + (tx << 2)) = o;
  }
}

__global__ __launch_bounds__(256)
void decode_k(const float* __restrict__ WdT, const int* __restrict__ selIdx,
              const float* __restrict__ selVal, const int* __restrict__ mrow,
              const float* __restrict__ bdec, float* __restrict__ out)
{
  __shared__ int   sI[128];
  __shared__ float sV[128];
  const int row = blockIdx.x, tid = threadIdx.x;
  const int m = mrow[row];
  if (tid < m){
    sI[tid] = selIdx[(row << 7) + tid];
    sV[tid] = selVal[(row << 7) + tid];
  }
  __syncthreads();
  const int d = tid << 3;
  float a[8];
  {
    const float4 b0 = *(const float4*)(bdec + d);
    const float4 b1 = *(const float4*)(bdec + d + 4);
    a[0] = b0.x; a[1] = b0.y; a[2] = b0.z; a[3] = b0.w;
    a[4] = b1.x; a[5] = b1.y; a[6] = b1.z; a[7] = b1.w;
  }
  for (int i = 0; i < m; ++i){
    const float v = sV[i];
    const float* wp = WdT + (size_t)sI[i] * DIM + d;
    const float4 w0 = *(const float4*)wp;
    const float4 w1 = *(const float4*)(wp + 4);
    a[0] = fmaf(v, w0.x, a[0]); a[1] = fmaf(v, w0.y, a[1]);
    a[2] = fmaf(v, w0.z, a[2]); a[3] = fmaf(v, w0.w, a[3]);
    a[4] = fmaf(v, w1.x, a[4]); a[5] = fmaf(v, w1.y, a[5]);
    a[6] = fmaf(v, w1.z, a[6]); a[7] = fmaf(v, w1.w, a[7]);
  }
  float4 o0 = {a[0], a[1], a[2], a[3]};
  float4 o1 = {a[4], a[5], a[6], a[7]};
  *(float4*)(out + (size_t)row * DIM + d)     = o0;
  *(float4*)(out + (size_t)row * DIM + d + 4) = o1;
}

// ===========================================================================
extern "C" void kernel_launch(void* const* d_in, const int* in_sizes, int n_in,
                              void* d_out, int out_size, void* d_ws, size_t ws_size,
                              hipStream_t stream)
{
  const float* x    = (const float*)d_in[0];
  const float* Wenc = (const float*)d_in[1];
  const float* benc = (const float*)d_in[2];
  const float* Wk1  = (const float*)d_in[3];
  const float* bk1  = (const float*)d_in[4];
  const float* Wk2  = (const float*)d_in[5];
  const float* bk2  = (const float*)d_in[6];
  const float* Wdec = (const float*)d_in[7];
  const float* bdec = (const float*)d_in[8];
  const int*   kp   = (const int*)d_in[9];
  float* out = (float*)d_out;

  char* ws = (char*)d_ws;
  const size_t XS_BYTES   = (size_t)BATCH * DIM * 2;      // 16 MB per plane
  const size_t ACTS_BYTES = (size_t)BATCH * FEAT * 4;     // 256 MB
  const size_t WP_BYTES   = (size_t)FEAT * DIM * 2;       // 64 MB per plane
  const size_t NEED_A = 2 * XS_BYTES + ACTS_BYTES + 2 * WP_BYTES
                      + 4194304 + 16384 + 2097152 + 2097152;

  if (ws_size >= NEED_A){
    // ---------------- PATH A: fused dual-GEMM ----------------
    unsigned short* xs0 = (unsigned short*)ws;
    unsigned short* xs1 = (unsigned short*)(ws + XS_BYTES);
    char* p = ws + 2 * XS_BYTES;
    float* acts = (float*)p;
    float* WdT  = (float*)p;                 // aliased after select
    p += ACTS_BYTES;
    unsigned short* wp0 = (unsigned short*)p;
    unsigned short* wp1 = (unsigned short*)(p + WP_BYTES);
    p += 2 * WP_BYTES;
    float* zpart  = (float*)p;               p += 4194304;
    int*   mrow   = (int*)p;                 p += 16384;
    int*   selIdx = (int*)p;                 p += 2097152;
    float* selVal = (float*)p;

    splitX<<<dim3(BATCH * DIM / 1024), dim3(256), 0, stream>>>(x, bdec, xs0, xs1);
    splitW<<<dim3(FEAT * DIM / 1024), dim3(256), 0, stream>>>(Wenc, wp0, wp1);
    gemmf<<<dim3(4096), dim3(512), 98304, stream>>>(xs0, xs1, wp0, wp1, Wk1,
                                                    benc, bk1, Wk2, acts, zpart);
    zreduce<<<dim3(BATCH / 4), dim3(256), 0, stream>>>(zpart, bk2, kp, mrow);
    select_topk<<<dim3(BATCH), dim3(256), 0, stream>>>(acts, mrow, selIdx, selVal);
    transpose_dec<<<dim3(FEAT / 64, DIM / 64), dim3(256), 0, stream>>>(Wdec, WdT);
    decode_k<<<dim3(BATCH), dim3(256), 0, stream>>>(WdT, selIdx, selVal, mrow, bdec, out);
  } else {
    // ---------------- PATH B: proven round-1 fallback ----------------
    float* acts   = (float*)ws;
    float* WdT    = (float*)ws;
    float* zpart  = (float*)(ws + ACTS_BYTES);
    int*   mrow   = (int*)  (ws + ACTS_BYTES + 4194304);
    int*   selIdx = (int*)  (ws + ACTS_BYTES + 4194304 + 16384);
    float* selVal = (float*)(ws + ACTS_BYTES + 4194304 + 16384 + 2097152);

    dim3 gg(FEAT / 128, BATCH / 128);
    gemm6<0><<<gg, dim3(256), 0, stream>>>(x, bdec, Wenc, benc, nullptr, acts, nullptr);
    gemm6<1><<<gg, dim3(256), 0, stream>>>(x, bdec, Wk1, bk1, Wk2, nullptr, zpart);
    zreduce<<<dim3(BATCH / 4), dim3(256), 0, stream>>>(zpart, bk2, kp, mrow);
    select_topk<<<dim3(BATCH), dim3(256), 0, stream>>>(acts, mrow, selIdx, selVal);
    transpose_dec<<<dim3(FEAT / 64, DIM / 64), dim3(256), 0, stream>>>(Wdec, WdT);
    decode_k<<<dim3(BATCH), dim3(256), 0, stream>>>(WdT, selIdx, selVal, mrow, bdec, out);
  }
}

// Round 7
// 2081.054 us; speedup vs baseline: 1.1412x; 1.1412x over previous
//
#include <hip/hip_runtime.h>
#include <hip/hip_bf16.h>
#include <cstdint>
#include <cstddef>

#define BATCH 4096
#define DIM   2048
#define FEAT  16384

typedef __attribute__((ext_vector_type(8))) short s8v;
typedef __attribute__((ext_vector_type(8))) _Float16 h8v;
typedef __attribute__((ext_vector_type(4))) float f4v;

__device__ __forceinline__ unsigned short f2bf(float f){
  unsigned u = __float_as_uint(f);
  unsigned r = u + 0x7FFFu + ((u >> 16) & 1u);
  return (unsigned short)(r >> 16);
}
__device__ __forceinline__ float bf2f(unsigned short h){
  return __uint_as_float(((unsigned)h) << 16);
}
__device__ __forceinline__ void split3(float v, unsigned short &h, unsigned short &m, unsigned short &l){
  h = f2bf(v);
  float r1 = v - bf2f(h);
  m = f2bf(r1);
  float r2 = r1 - bf2f(m);
  l = f2bf(r2);
}

// fp16 2-way split: v = h + l/2048 (l stored x2048 to stay in normal range)
__device__ __forceinline__ void split2(float v, unsigned short &h, unsigned short &l){
  _Float16 hf = (_Float16)v;
  _Float16 lf = (_Float16)((v - (float)hf) * 2048.0f);
  h = __builtin_bit_cast(unsigned short, hf);
  l = __builtin_bit_cast(unsigned short, lf);
}

__device__ __forceinline__ void gload16(const void* g, void* l){
  __builtin_amdgcn_global_load_lds(
      (const __attribute__((address_space(1))) void*)g,
      (__attribute__((address_space(3))) void*)l, 16, 0, 0);
}

// ===========================================================================
// PATH A: fp16 2-split planes + pipelined global_load_lds GEMM (3 products)
// ===========================================================================

// x -> 2 fp16 planes of (x - b_dec)
__global__ __launch_bounds__(256)
void splitX(const float* __restrict__ x, const float* __restrict__ bdec,
            unsigned short* __restrict__ p0, unsigned short* __restrict__ p1)
{
  const size_t i = ((size_t)blockIdx.x * 256 + threadIdx.x) * 4;
  const int col = (int)(i & (DIM - 1));
  const float4 v = *(const float4*)(x + i);
  const float4 b = *(const float4*)(bdec + col);
  float e0 = v.x - b.x, e1 = v.y - b.y, e2 = v.z - b.z, e3 = v.w - b.w;
  ushort4 H, L;
  split2(e0, H.x, L.x); split2(e1, H.y, L.y);
  split2(e2, H.z, L.z); split2(e3, H.w, L.w);
  *(ushort4*)(p0 + i) = H; *(ushort4*)(p1 + i) = L;
}

// W -> 2 fp16 planes
__global__ __launch_bounds__(256)
void splitW(const float* __restrict__ w,
            unsigned short* __restrict__ p0, unsigned short* __restrict__ p1)
{
  const size_t i = ((size_t)blockIdx.x * 256 + threadIdx.x) * 4;
  const float4 v = *(const float4*)(w + i);
  ushort4 H, L;
  split2(v.x, H.x, L.x); split2(v.y, H.y, L.y);
  split2(v.z, H.z, L.z); split2(v.w, H.w, L.w);
  *(ushort4*)(p0 + i) = H; *(ushort4*)(p1 + i) = L;
}

// Plane GEMM: C = Ah*Bh + (Ah*Bl + Al*Bh)/2048  (fp32-equivalent)
// 128x128 tile, BK=32, 4 waves, LDS double-buffer + T3-min pipeline
// (STAGE next -> MFMA current -> one barrier). Swapped-operand MFMA
// (mfma(b,a) = row-major C frag) -> coalesced float4 C-stores (nontemporal).
template<int MODE>
__global__ __launch_bounds__(256, 2)
void gemmp(const unsigned short* __restrict__ Ah_, const unsigned short* __restrict__ Al_,
           const unsigned short* __restrict__ Bh_, const unsigned short* __restrict__ Bl_,
           const float* __restrict__ bias, const float* __restrict__ w2,
           float* __restrict__ acts, float* __restrict__ zpart)
{
  // [buf][0]=Ah|Al rows, [buf][1]=Bh|Bl rows (128 rows x 128 bytes each)
  __shared__ unsigned short sAB[2][2][128][64];
  const int tid  = threadIdx.x;
  const int lane = tid & 63, wv = tid >> 6;

  // per-XCD 8x8 block squares (round-4/5 proven walk)
  const int bid = blockIdx.x;
  const int xcd = bid & 7;
  const int idx = bid >> 3;          // [0,512)
  const int sq  = idx >> 6;          // [0,8)
  const int s   = idx & 63;
  const int bx  = (xcd << 4) | ((sq & 1) << 3) | (s & 7);   // [0,128)
  const int by  = ((sq >> 1) << 3) | (s >> 3);              // [0,32)
  const int row0 = by << 7, col0 = bx << 7;

  const int wr = (wv & 1) << 6, wc = (wv >> 1) << 6;

  f4v acc[4][4], acc2[4][4];
  #pragma unroll
  for (int i = 0; i < 4; ++i)
    #pragma unroll
    for (int j = 0; j < 4; ++j){
      acc[i][j]  = (f4v){0.f, 0.f, 0.f, 0.f};
      acc2[i][j] = (f4v){0.f, 0.f, 0.f, 0.f};
    }

  // ---- staging precompute: 2 tiles x 4 issues per thread ----
  const int sr = lane >> 3;   // row within 8-row stripe
  const int gp = lane & 7;    // physical 16B group
  const unsigned short* gsrc[2][4];
  #pragma unroll
  for (int j = 0; j < 4; ++j){
    const int r  = (((wv << 2) + j) << 3) + sr;      // 0..127
    const int gl = gp ^ (r & 7);                     // logical group
    const int co = (gl & 3) << 3;                    // k-element offset
    gsrc[0][j] = ((gl < 4) ? Ah_ : Al_) + (size_t)(row0 + r) * DIM + co;
    gsrc[1][j] = ((gl < 4) ? Bh_ : Bl_) + (size_t)(col0 + r) * DIM + co;
  }

  const int fr16 = lane & 15;
  const int kg   = lane >> 4;
  int ra[4], rb[4];
  #pragma unroll
  for (int f = 0; f < 4; ++f){ ra[f] = wr + (f << 4) + fr16; rb[f] = wc + (f << 4) + fr16; }

  #define LDFRAG(bf, b, r, hb) (*(const h8v*)&sAB[bf][b][r][(((hb) + kg) ^ ((r) & 7)) << 3])
  #define STAGE(bf, ko)                                                      \
    {                                                                        \
      _Pragma("unroll")                                                      \
      for (int b = 0; b < 2; ++b)                                            \
        _Pragma("unroll")                                                    \
        for (int j = 0; j < 4; ++j)                                          \
          gload16(gsrc[b][j] + (ko), &sAB[bf][b][(((wv << 2) + j) << 3)][0]);\
    }

  int cur = 0;
  STAGE(0, 0);
  __syncthreads();

  for (int kt = 0; kt < DIM / 32; ++kt){
    if (kt < DIM / 32 - 1) STAGE(cur ^ 1, (kt + 1) << 5);

    h8v Ah[4], Bh[4], Xl[4];
    #pragma unroll
    for (int f = 0; f < 4; ++f) Ah[f] = LDFRAG(cur, 0, ra[f], 0);
    #pragma unroll
    for (int f = 0; f < 4; ++f) Bh[f] = LDFRAG(cur, 1, rb[f], 0);
    #pragma unroll
    for (int fi = 0; fi < 4; ++fi)
      #pragma unroll
      for (int fj = 0; fj < 4; ++fj)
        acc[fi][fj] = __builtin_amdgcn_mfma_f32_16x16x32_f16(Bh[fj], Ah[fi], acc[fi][fj], 0, 0, 0);
    #pragma unroll
    for (int f = 0; f < 4; ++f) Xl[f] = LDFRAG(cur, 0, ra[f], 4);   // Al
    #pragma unroll
    for (int fi = 0; fi < 4; ++fi)
      #pragma unroll
      for (int fj = 0; fj < 4; ++fj)
        acc2[fi][fj] = __builtin_amdgcn_mfma_f32_16x16x32_f16(Bh[fj], Xl[fi], acc2[fi][fj], 0, 0, 0);
    #pragma unroll
    for (int f = 0; f < 4; ++f) Xl[f] = LDFRAG(cur, 1, rb[f], 4);   // Bl
    #pragma unroll
    for (int fi = 0; fi < 4; ++fi)
      #pragma unroll
      for (int fj = 0; fj < 4; ++fj)
        acc2[fi][fj] = __builtin_amdgcn_mfma_f32_16x16x32_f16(Xl[fj], Ah[fi], acc2[fi][fj], 0, 0, 0);

    __syncthreads();
    cur ^= 1;
  }
  #undef LDFRAG
  #undef STAGE

  // Swapped-operand C frag: lane holds C[m = lane&15][n = (lane>>4)*4 + reg]
  const float LSC = 1.0f / 2048.0f;
  const int mloc = lane & 15;
  const int nq   = (lane >> 4) << 2;   // 0,4,8,12
  if (MODE == 0){
    #pragma unroll
    for (int fi = 0; fi < 4; ++fi){
      const int grow = row0 + wr + (fi << 4) + mloc;
      #pragma unroll
      for (int fj = 0; fj < 4; ++fj){
        const int gcol = col0 + wc + (fj << 4) + nq;
        const float4 be = *(const float4*)(bias + gcol);
        f4v v;
        v[0] = fmaxf(acc[fi][fj][0] + LSC * acc2[fi][fj][0] + be.x, 0.f);
        v[1] = fmaxf(acc[fi][fj][1] + LSC * acc2[fi][fj][1] + be.y, 0.f);
        v[2] = fmaxf(acc[fi][fj][2] + LSC * acc2[fi][fj][2] + be.z, 0.f);
        v[3] = fmaxf(acc[fi][fj][3] + LSC * acc2[fi][fj][3] + be.w, 0.f);
        // nontemporal: don't let the 256 MB acts stream evict A/B planes from L2/L3
        __builtin_nontemporal_store(v, (f4v*)(acts + (size_t)grow * FEAT + gcol));
      }
    }
  } else {
    #pragma unroll
    for (int fi = 0; fi < 4; ++fi){
      float ssum = 0.f;
      #pragma unroll
      for (int fj = 0; fj < 4; ++fj){
        const int gcol = col0 + wc + (fj << 4) + nq;
        const float4 be = *(const float4*)(bias + gcol);
        const float4 wk = *(const float4*)(w2 + gcol);
        float h0 = fmaxf(acc[fi][fj][0] + LSC * acc2[fi][fj][0] + be.x, 0.f);
        float h1 = fmaxf(acc[fi][fj][1] + LSC * acc2[fi][fj][1] + be.y, 0.f);
        float h2 = fmaxf(acc[fi][fj][2] + LSC * acc2[fi][fj][2] + be.z, 0.f);
        float h3 = fmaxf(acc[fi][fj][3] + LSC * acc2[fi][fj][3] + be.w, 0.f);
        ssum = fmaf(h0, wk.x, ssum);
        ssum = fmaf(h1, wk.y, ssum);
        ssum = fmaf(h2, wk.z, ssum);
        ssum = fmaf(h3, wk.w, ssum);
      }
      ssum += __shfl_xor(ssum, 16);
      ssum += __shfl_xor(ssum, 32);
      if (lane < 16){
        const int grow = row0 + wr + (fi << 4) + lane;
        zpart[(size_t)grow * 256 + (bx << 1) + (wc >> 6)] = ssum;
      }
    }
  }
}

// ===========================================================================
// PATH B (fallback, proven round-1): on-the-fly bf16 3-split GEMM
// ===========================================================================
template<int MODE>
__global__ __launch_bounds__(256)
void gemm6(const float* __restrict__ X, const float* __restrict__ bsub,
           const float* __restrict__ W, const float* __restrict__ bias,
           const float* __restrict__ w2, float* __restrict__ acts,
           float* __restrict__ zpart)
{
  __shared__ unsigned short sA[3][128][32];
  __shared__ unsigned short sB[3][128][32];
  const int tid  = threadIdx.x;
  const int row0 = blockIdx.y << 7;
  const int col0 = blockIdx.x << 7;
  const int lane = tid & 63, wv = tid >> 6;
  const int wr = (wv & 1) << 6, wc = (wv >> 1) << 6;
  const int fr = lane & 15;
  const int gsw = (((lane >> 4) ^ ((fr >> 1) & 3)) << 3);

  f4v acc[4][4];
  #pragma unroll
  for (int i = 0; i < 4; ++i)
    #pragma unroll
    for (int j = 0; j < 4; ++j)
      acc[i][j] = (f4v){0.f, 0.f, 0.f, 0.f};

  const int rs = tid >> 3;
  const int cb = (tid & 7) << 2;
  const int gq = cb >> 3;

  for (int kt = 0; kt < DIM / 32; ++kt){
    const int k0 = kt << 5;
    #pragma unroll
    for (int i = 0; i < 4; ++i){
      const int r  = (i << 5) + rs;
      const int cs = ((gq ^ ((r >> 1) & 3)) << 3) + (cb & 7);
      {
        const float4 xv = *(const float4*)(X + (size_t)(row0 + r) * DIM + k0 + cb);
        const float4 bd = *(const float4*)(bsub + k0 + cb);
        float v0 = xv.x - bd.x, v1 = xv.y - bd.y, v2 = xv.z - bd.z, v3 = xv.w - bd.w;
        ushort4 H, M, L;
        split3(v0, H.x, M.x, L.x); split3(v1, H.y, M.y, L.y);
        split3(v2, H.z, M.z, L.z); split3(v3, H.w, M.w, L.w);
        *(ushort4*)&sA[0][r][cs] = H;
        *(ushort4*)&sA[1][r][cs] = M;
        *(ushort4*)&sA[2][r][cs] = L;
      }
      {
        const float4 wv4 = *(const float4*)(W + (size_t)(col0 + r) * DIM + k0 + cb);
        ushort4 H, M, L;
        split3(wv4.x, H.x, M.x, L.x); split3(wv4.y, H.y, M.y, L.y);
        split3(wv4.z, H.z, M.z, L.z); split3(wv4.w, H.w, M.w, L.w);
        *(ushort4*)&sB[0][r][cs] = H;
        *(ushort4*)&sB[1][r][cs] = M;
        *(ushort4*)&sB[2][r][cs] = L;
      }
    }
    __syncthreads();
    #pragma unroll
    for (int pa = 0; pa < 3; ++pa){
      s8v a[4];
      #pragma unroll
      for (int fi = 0; fi < 4; ++fi)
        a[fi] = *(const s8v*)&sA[pa][wr + (fi << 4) + fr][gsw];
      #pragma unroll
      for (int pb = 0; pb < 3 - pa; ++pb){
        s8v b[4];
        #pragma unroll
        for (int fj = 0; fj < 4; ++fj)
          b[fj] = *(const s8v*)&sB[pb][wc + (fj << 4) + fr][gsw];
        #pragma unroll
        for (int fi = 0; fi < 4; ++fi)
          #pragma unroll
          for (int fj = 0; fj < 4; ++fj)
            acc[fi][fj] = __builtin_amdgcn_mfma_f32_16x16x32_bf16(a[fi], b[fj], acc[fi][fj], 0, 0, 0);
      }
    }
    __syncthreads();
  }

  const int rq = (lane >> 4) << 2;
  if (MODE == 0){
    #pragma unroll
    for (int fj = 0; fj < 4; ++fj){
      const int gcol = col0 + wc + (fj << 4) + fr;
      const float be = bias[gcol];
      #pragma unroll
      for (int fi = 0; fi < 4; ++fi){
        #pragma unroll
        for (int r = 0; r < 4; ++r){
          const int grow = row0 + wr + (fi << 4) + rq + r;
          float v = acc[fi][fj][r] + be;
          v = fmaxf(v, 0.f);
          acts[(size_t)grow * FEAT + gcol] = v;
        }
      }
    }
  } else {
    float be[4], wk[4];
    #pragma unroll
    for (int fj = 0; fj < 4; ++fj){
      const int gcol = col0 + wc + (fj << 4) + fr;
      be[fj] = bias[gcol];
      wk[fj] = w2[gcol];
    }
    #pragma unroll
    for (int fi = 0; fi < 4; ++fi){
      #pragma unroll
      for (int r = 0; r < 4; ++r){
        float s = 0.f;
        #pragma unroll
        for (int fj = 0; fj < 4; ++fj){
          float h = fmaxf(acc[fi][fj][r] + be[fj], 0.f);
          s = fmaf(h, wk[fj], s);
        }
        s += __shfl_xor(s, 1);
        s += __shfl_xor(s, 2);
        s += __shfl_xor(s, 4);
        s += __shfl_xor(s, 8);
        if (fr == 0){
          const int grow = row0 + wr + (fi << 4) + rq + r;
          zpart[(size_t)grow * 256 + (blockIdx.x << 1) + (wc >> 6)] = s;
        }
      }
    }
  }
}

// ===========================================================================
// shared tail kernels
// ===========================================================================
__global__ __launch_bounds__(256)
void zreduce(const float* __restrict__ zpart, const float* __restrict__ bk2,
             const int* __restrict__ kp, int* __restrict__ mrow)
{
  const int row  = blockIdx.x * 4 + (threadIdx.x >> 6);
  const int lane = threadIdx.x & 63;
  const float* zp = zpart + (size_t)row * 256;
  float s = zp[lane] + zp[lane + 64] + zp[lane + 128] + zp[lane + 192];
  s += __shfl_xor(s, 1);
  s += __shfl_xor(s, 2);
  s += __shfl_xor(s, 4);
  s += __shfl_xor(s, 8);
  s += __shfl_xor(s, 16);
  s += __shfl_xor(s, 32);
  if (lane == 0){
    float z = s + bk2[0];
    float kest = 2.f * (float)(*kp) * (1.f / (1.f + expf(-z)));
    int m = (int)ceilf(kest);
    m = min(max(m, 0), 128);
    mrow[row] = m;
  }
}

__device__ __forceinline__ void radix_find(int* hist, int nbins, int need, int tid,
                                           int* out3, int* blksum)
{
  const int per  = nbins >> 8;
  const int base = tid * per;
  int bs = 0;
  for (int j = 0; j < per; ++j) bs += hist[base + j];
  blksum[tid] = bs;
  __syncthreads();
  if (tid == 0){
    int a2 = 0;
    for (int t = 255; t >= 0; --t){ int v = blksum[t]; blksum[t] = a2; a2 += v; }
  }
  __syncthreads();
  int ch = blksum[tid];
  for (int j = per - 1; j >= 0; --j){
    const int b = base + j;
    const int c = hist[b];
    if (ch < need && need <= ch + c){ out3[0] = b; out3[1] = need - ch; out3[2] = ch; }
    ch += c;
  }
  __syncthreads();
}

__global__ __launch_bounds__(256)
void select_topk(const float* __restrict__ acts, const int* __restrict__ mrow,
                 int* __restrict__ selIdx, float* __restrict__ selVal)
{
  __shared__ int hist[2048];
  __shared__ int blksum[256];
  __shared__ int out3[4];
  __shared__ unsigned listU[2048];
  __shared__ int lcnt;

  const int row = blockIdx.x, tid = threadIdx.x;
  const int m = mrow[row];
  const float* rp = acts + (size_t)row * FEAT;

  for (int i = tid; i < 2048; i += 256) hist[i] = 0;
  __syncthreads();
  // pass 1 (vectorized): histogram of bits [31:21]
  for (int it = 0; it < 16; ++it){
    const int i4 = (it << 8) + tid;
    const uint4 u4 = *(const uint4*)(rp + ((size_t)i4 << 2));
    if (u4.x) atomicAdd(&hist[u4.x >> 21], 1);
    if (u4.y) atomicAdd(&hist[u4.y >> 21], 1);
    if (u4.z) atomicAdd(&hist[u4.z >> 21], 1);
    if (u4.w) atomicAdd(&hist[u4.w >> 21], 1);
  }
  __syncthreads();
  radix_find(hist, 2048, m, tid, out3, blksum);
  const int bin1 = out3[0];
  const int rem1 = out3[1];

  if (tid == 0) lcnt = 0;
  __syncthreads();
  // pass 2 (vectorized): collect bin1 candidates (values only)
  for (int it = 0; it < 16; ++it){
    const int i4 = (it << 8) + tid;
    const uint4 u4 = *(const uint4*)(rp + ((size_t)i4 << 2));
    if ((int)(u4.x >> 21) == bin1){ int p = atomicAdd(&lcnt, 1); if (p < 2048) listU[p] = u4.x; }
    if ((int)(u4.y >> 21) == bin1){ int p = atomicAdd(&lcnt, 1); if (p < 2048) listU[p] = u4.y; }
    if ((int)(u4.z >> 21) == bin1){ int p = atomicAdd(&lcnt, 1); if (p < 2048) listU[p] = u4.z; }
    if ((int)(u4.w >> 21) == bin1){ int p = atomicAdd(&lcnt, 1); if (p < 2048) listU[p] = u4.w; }
  }
  __syncthreads();
  const int L = min(lcnt, 2048);

  for (int i = tid; i < 2048; i += 256) hist[i] = 0;
  __syncthreads();
  for (int i = tid; i < L; i += 256) atomicAdd(&hist[(listU[i] >> 10) & 0x7FF], 1);
  __syncthreads();
  radix_find(hist, 2048, rem1, tid, out3, blksum);
  const int bin2 = out3[0];
  const int rem2 = out3[1];

  for (int i = tid; i < 1024; i += 256) hist[i] = 0;
  __syncthreads();
  for (int i = tid; i < L; i += 256){
    unsigned u = listU[i];
    if ((int)((u >> 10) & 0x7FF) == bin2) atomicAdd(&hist[u & 0x3FF], 1);
  }
  __syncthreads();
  radix_find(hist, 1024, rem2, tid, out3, blksum);
  const int bin3 = out3[0];
  const int mEq  = out3[1];

  const unsigned tbits = ((unsigned)bin1 << 21) | ((unsigned)bin2 << 10) | (unsigned)bin3;

  // pass 3 (tie-exact): wave 0, deterministic index order
  if (tid < 64){
    const int base = row << 7;
    int cnt = 0;
    for (int c = 0; c < 256; ++c){
      const int i = (c << 6) + tid;
      const unsigned u = __float_as_uint(rp[i]);
      const bool g = (u > tbits);
      const unsigned long long mk = __ballot(g);
      if (g){
        int pos = cnt + __popcll(mk & ((1ull << tid) - 1ull));
        selIdx[base + pos] = i;
        selVal[base + pos] = __uint_as_float(u);
      }
      cnt += __popcll(mk);
    }
    int eqs = 0;
    for (int c = 0; c < 256 && eqs < mEq; ++c){
      const int i = (c << 6) + tid;
      const unsigned u = __float_as_uint(rp[i]);
      const bool e = (u == tbits);
      const unsigned long long mk = __ballot(e);
      if (e){
        int p = eqs + __popcll(mk & ((1ull << tid) - 1ull));
        if (p < mEq){
          selIdx[base + cnt + p] = i;
          selVal[base + cnt + p] = __uint_as_float(u);
        }
      }
      eqs += __popcll(mk);
    }
  }
}

// W_dec [DIM][FEAT] fp32 -> WdT16 [FEAT][DIM] fp16 (halves decode gather bytes)
__global__ __launch_bounds__(256)
void transpose_dec(const float* __restrict__ Wd, _Float16* __restrict__ WdT16)
{
  __shared__ float t[64][65];
  const int f0 = blockIdx.x << 6, d0 = blockIdx.y << 6;
  const int tx = threadIdx.x & 15, ty = threadIdx.x >> 4;
  #pragma unroll
  for (int r = 0; r < 4; ++r){
    const int d = ty + (r << 4);
    const float4 v = *(const float4*)(Wd + (size_t)(d0 + d) * FEAT + f0 + (tx << 2));
    t[d][(tx << 2) + 0] = v.x;
    t[d][(tx << 2) + 1] = v.y;
    t[d][(tx << 2) + 2] = v.z;
    t[d][(tx << 2) + 3] = v.w;
  }
  __syncthreads();
  #pragma unroll
  for (int r = 0; r < 4; ++r){
    const int f = ty + (r << 4);
    ushort4 o;
    o.x = __builtin_bit_cast(unsigned short, (_Float16)t[(tx << 2) + 0][f]);
    o.y = __builtin_bit_cast(unsigned short, (_Float16)t[(tx << 2) + 1][f]);
    o.z = __builtin_bit_cast(unsigned short, (_Float16)t[(tx << 2) + 2][f]);
    o.w = __builtin_bit_cast(unsigned short, (_Float16)t[(tx << 2) + 3][f]);
    *(ushort4*)(WdT16 + (size_t)(f0 + f) * DIM + d0 + (tx << 2)) = o;
  }
}

__global__ __launch_bounds__(256)
void decode_k(const _Float16* __restrict__ WdT16, const int* __restrict__ selIdx,
              const float* __restrict__ selVal, const int* __restrict__ mrow,
              const float* __restrict__ bdec, float* __restrict__ out)
{
  __shared__ int   sI[128];
  __shared__ float sV[128];
  const int row = blockIdx.x, tid = threadIdx.x;
  const int m = mrow[row];
  if (tid < m){
    sI[tid] = selIdx[(row << 7) + tid];
    sV[tid] = selVal[(row << 7) + tid];
  }
  __syncthreads();
  const int d = tid << 3;
  float a[8];
  {
    const float4 b0 = *(const float4*)(bdec + d);
    const float4 b1 = *(const float4*)(bdec + d + 4);
    a[0] = b0.x; a[1] = b0.y; a[2] = b0.z; a[3] = b0.w;
    a[4] = b1.x; a[5] = b1.y; a[6] = b1.z; a[7] = b1.w;
  }
  for (int i = 0; i < m; ++i){
    const float v = sV[i];
    const h8v w = *(const h8v*)(WdT16 + (size_t)sI[i] * DIM + d);
    #pragma unroll
    for (int j = 0; j < 8; ++j)
      a[j] = fmaf(v, (float)w[j], a[j]);
  }
  float4 o0 = {a[0], a[1], a[2], a[3]};
  float4 o1 = {a[4], a[5], a[6], a[7]};
  *(float4*)(out + (size_t)row * DIM + d)     = o0;
  *(float4*)(out + (size_t)row * DIM + d + 4) = o1;
}

// ===========================================================================
extern "C" void kernel_launch(void* const* d_in, const int* in_sizes, int n_in,
                              void* d_out, int out_size, void* d_ws, size_t ws_size,
                              hipStream_t stream)
{
  const float* x    = (const float*)d_in[0];
  const float* Wenc = (const float*)d_in[1];
  const float* benc = (const float*)d_in[2];
  const float* Wk1  = (const float*)d_in[3];
  const float* bk1  = (const float*)d_in[4];
  const float* Wk2  = (const float*)d_in[5];
  const float* bk2  = (const float*)d_in[6];
  const float* Wdec = (const float*)d_in[7];
  const float* bdec = (const float*)d_in[8];
  const int*   kp   = (const int*)d_in[9];
  float* out = (float*)d_out;

  char* ws = (char*)d_ws;
  const size_t XS_BYTES   = (size_t)BATCH * DIM * 2;      // 16 MB per plane
  const size_t ACTS_BYTES = (size_t)BATCH * FEAT * 4;     // 256 MB
  const size_t WP_BYTES   = (size_t)FEAT * DIM * 2;       // 64 MB per plane
  const size_t NEED_A = 2 * XS_BYTES + ACTS_BYTES + 2 * WP_BYTES
                      + 4194304 + 16384 + 2097152 + 2097152;

  if (ws_size >= NEED_A){
    // ---------------- PATH A: fp16 2-split planes, twin GEMMs ----------------
    unsigned short* xs0 = (unsigned short*)ws;
    unsigned short* xs1 = (unsigned short*)(ws + XS_BYTES);
    char* p = ws + 2 * XS_BYTES;
    float* acts = (float*)p;
    _Float16* WdT16 = (_Float16*)p;          // aliased after select (64 MB < 256 MB)
    p += ACTS_BYTES;
    unsigned short* wp0 = (unsigned short*)p;
    unsigned short* wp1 = (unsigned short*)(p + WP_BYTES);
    p += 2 * WP_BYTES;
    float* zpart  = (float*)p;               p += 4194304;
    int*   mrow   = (int*)p;                 p += 16384;
    int*   selIdx = (int*)p;                 p += 2097152;
    float* selVal = (float*)p;

    splitX<<<dim3(BATCH * DIM / 1024), dim3(256), 0, stream>>>(x, bdec, xs0, xs1);
    // kest GEMM first (so Wp region can be reused for Wenc planes)
    splitW<<<dim3(FEAT * DIM / 1024), dim3(256), 0, stream>>>(Wk1, wp0, wp1);
    gemmp<1><<<dim3(4096), dim3(256), 0, stream>>>(xs0, xs1, wp0, wp1,
                                                   bk1, Wk2, nullptr, zpart);
    zreduce<<<dim3(BATCH / 4), dim3(256), 0, stream>>>(zpart, bk2, kp, mrow);
    splitW<<<dim3(FEAT * DIM / 1024), dim3(256), 0, stream>>>(Wenc, wp0, wp1);
    gemmp<0><<<dim3(4096), dim3(256), 0, stream>>>(xs0, xs1, wp0, wp1,
                                                   benc, nullptr, acts, nullptr);
    select_topk<<<dim3(BATCH), dim3(256), 0, stream>>>(acts, mrow, selIdx, selVal);
    transpose_dec<<<dim3(FEAT / 64, DIM / 64), dim3(256), 0, stream>>>(Wdec, WdT16);
    decode_k<<<dim3(BATCH), dim3(256), 0, stream>>>(WdT16, selIdx, selVal, mrow, bdec, out);
  } else {
    // ---------------- PATH B: proven round-1 fallback ----------------
    float* acts   = (float*)ws;
    _Float16* WdT16 = (_Float16*)ws;
    float* zpart  = (float*)(ws + ACTS_BYTES);
    int*   mrow   = (int*)  (ws + ACTS_BYTES + 4194304);
    int*   selIdx = (int*)  (ws + ACTS_BYTES + 4194304 + 16384);
    float* selVal = (float*)(ws + ACTS_BYTES + 4194304 + 16384 + 2097152);

    dim3 gg(FEAT / 128, BATCH / 128);
    gemm6<0><<<gg, dim3(256), 0, stream>>>(x, bdec, Wenc, benc, nullptr, acts, nullptr);
    gemm6<1><<<gg, dim3(256), 0, stream>>>(x, bdec, Wk1, bk1, Wk2, nullptr, zpart);
    zreduce<<<dim3(BATCH / 4), dim3(256), 0, stream>>>(zpart, bk2, kp, mrow);
    select_topk<<<dim3(BATCH), dim3(256), 0, stream>>>(acts, mrow, selIdx, selVal);
    transpose_dec<<<dim3(FEAT / 64, DIM / 64), dim3(256), 0, stream>>>(Wdec, WdT16);
    decode_k<<<dim3(BATCH), dim3(256), 0, stream>>>(WdT16, selIdx, selVal, mrow, bdec, out);
  }
}

// Round 8
// 1853.566 us; speedup vs baseline: 1.2812x; 1.1227x over previous
//
#include <hip/hip_runtime.h>
#include <hip/hip_bf16.h>
#include <cstdint>
#include <cstddef>

#define BATCH 4096
#define DIM   2048
#define FEAT  16384

typedef __attribute__((ext_vector_type(8))) short s8v;
typedef __attribute__((ext_vector_type(8))) _Float16 h8v;
typedef __attribute__((ext_vector_type(4))) float f4v;

__device__ __forceinline__ unsigned short f2bf(float f){
  unsigned u = __float_as_uint(f);
  unsigned r = u + 0x7FFFu + ((u >> 16) & 1u);
  return (unsigned short)(r >> 16);
}
__device__ __forceinline__ float bf2f(unsigned short h){
  return __uint_as_float(((unsigned)h) << 16);
}
__device__ __forceinline__ void split3(float v, unsigned short &h, unsigned short &m, unsigned short &l){
  h = f2bf(v);
  float r1 = v - bf2f(h);
  m = f2bf(r1);
  float r2 = r1 - bf2f(m);
  l = f2bf(r2);
}

// fp16 2-way split: v = h + l/2048 (l stored x2048 to stay in normal range)
__device__ __forceinline__ void split2(float v, unsigned short &h, unsigned short &l){
  _Float16 hf = (_Float16)v;
  _Float16 lf = (_Float16)((v - (float)hf) * 2048.0f);
  h = __builtin_bit_cast(unsigned short, hf);
  l = __builtin_bit_cast(unsigned short, lf);
}

__device__ __forceinline__ void gload16(const void* g, void* l){
  __builtin_amdgcn_global_load_lds(
      (const __attribute__((address_space(1))) void*)g,
      (__attribute__((address_space(3))) void*)l, 16, 0, 0);
}

// ===========================================================================
// PATH A: fp16 2-split planes + pipelined global_load_lds GEMM (3 products)
// ===========================================================================

// x -> 2 fp16 planes of (x - b_dec)
__global__ __launch_bounds__(256)
void splitX(const float* __restrict__ x, const float* __restrict__ bdec,
            unsigned short* __restrict__ p0, unsigned short* __restrict__ p1)
{
  const size_t i = ((size_t)blockIdx.x * 256 + threadIdx.x) * 4;
  const int col = (int)(i & (DIM - 1));
  const float4 v = *(const float4*)(x + i);
  const float4 b = *(const float4*)(bdec + col);
  float e0 = v.x - b.x, e1 = v.y - b.y, e2 = v.z - b.z, e3 = v.w - b.w;
  ushort4 H, L;
  split2(e0, H.x, L.x); split2(e1, H.y, L.y);
  split2(e2, H.z, L.z); split2(e3, H.w, L.w);
  *(ushort4*)(p0 + i) = H; *(ushort4*)(p1 + i) = L;
}

// W -> 2 fp16 planes
__global__ __launch_bounds__(256)
void splitW(const float* __restrict__ w,
            unsigned short* __restrict__ p0, unsigned short* __restrict__ p1)
{
  const size_t i = ((size_t)blockIdx.x * 256 + threadIdx.x) * 4;
  const float4 v = *(const float4*)(w + i);
  ushort4 H, L;
  split2(v.x, H.x, L.x); split2(v.y, H.y, L.y);
  split2(v.z, H.z, L.z); split2(v.w, H.w, L.w);
  *(ushort4*)(p0 + i) = H; *(ushort4*)(p1 + i) = L;
}

// Plane GEMM: C = Ah*Bh + (Ah*Bl + Al*Bh)/2048  (fp32-equivalent)
// 128x128 tile, BK=32, 8 waves (wave tile 32x64), LDS double-buffer,
// T3-min pipeline. 64 KB LDS -> 2 blocks/CU = 16 waves/CU for latency hiding.
// Swapped-operand MFMA (mfma(b,a) = row-major C frag) -> float4 nt C-stores.
template<int MODE>
__global__ __launch_bounds__(512, 4)
void gemmp(const unsigned short* __restrict__ Ah_, const unsigned short* __restrict__ Al_,
           const unsigned short* __restrict__ Bh_, const unsigned short* __restrict__ Bl_,
           const float* __restrict__ bias, const float* __restrict__ w2,
           float* __restrict__ acts, float* __restrict__ zpart)
{
  // [buf][0]=Ah|Al rows, [buf][1]=Bh|Bl rows (128 rows x 128 bytes each)
  __shared__ unsigned short sAB[2][2][128][64];
  const int tid  = threadIdx.x;
  const int lane = tid & 63, wv = tid >> 6;          // wv 0..7

  // per-XCD 8x8 block squares (proven walk)
  const int bid = blockIdx.x;
  const int xcd = bid & 7;
  const int idx = bid >> 3;          // [0,512)
  const int sq  = idx >> 6;          // [0,8)
  const int s   = idx & 63;
  const int bx  = (xcd << 4) | ((sq & 1) << 3) | (s & 7);   // [0,128)
  const int by  = ((sq >> 1) << 3) | (s >> 3);              // [0,32)
  const int row0 = by << 7, col0 = bx << 7;

  // wave tile: 32 rows x 64 cols (4 row-groups x 2 col-groups)
  const int wr = (wv & 3) << 5, wc = (wv >> 2) << 6;

  f4v acc[2][4], acc2[2][4];
  #pragma unroll
  for (int i = 0; i < 2; ++i)
    #pragma unroll
    for (int j = 0; j < 4; ++j){
      acc[i][j]  = (f4v){0.f, 0.f, 0.f, 0.f};
      acc2[i][j] = (f4v){0.f, 0.f, 0.f, 0.f};
    }

  // ---- staging precompute: 32 chunks (16 A + 16 B), 4 per wave ----
  const unsigned short* gsrc[4];
  unsigned ldsoff[4];
  #pragma unroll
  for (int j = 0; j < 4; ++j){
    const int q = (wv << 2) + j;       // 0..31
    const int mat = q >> 4;            // 0=A, 1=B
    const int chunk = q & 15;
    const int r  = (chunk << 3) + (lane >> 3);
    const int gl = (lane & 7) ^ (r & 7);
    const int co = (gl & 3) << 3;
    const unsigned short* hi = (mat == 0) ? Ah_ : Bh_;
    const unsigned short* lo = (mat == 0) ? Al_ : Bl_;
    const int rowg = ((mat == 0) ? row0 : col0) + r;
    gsrc[j]  = ((gl < 4) ? hi : lo) + (size_t)rowg * DIM + co;
    ldsoff[j] = (unsigned)(mat * 16384 + chunk * 1024);
  }

  const int fr16 = lane & 15;
  const int kg   = lane >> 4;
  int ra[2], rb[4];
  #pragma unroll
  for (int f = 0; f < 2; ++f) ra[f] = wr + (f << 4) + fr16;
  #pragma unroll
  for (int f = 0; f < 4; ++f) rb[f] = wc + (f << 4) + fr16;

  #define LDFRAG(bf, mat, r, hb) \
    (*(const h8v*)((const char*)sAB + (bf) * 32768 + (mat) * 16384 + (r) * 128 + (((((hb) + kg) ^ ((r) & 7)) << 4))))
  #define STAGE(bf, ko)                                                       \
    {                                                                         \
      _Pragma("unroll")                                                       \
      for (int j = 0; j < 4; ++j)                                             \
        gload16(gsrc[j] + (ko), (char*)sAB + (bf) * 32768 + ldsoff[j]);       \
    }

  int cur = 0;
  STAGE(0, 0);
  __syncthreads();

  for (int kt = 0; kt < DIM / 32; ++kt){
    if (kt < DIM / 32 - 1) STAGE(cur ^ 1, (kt + 1) << 5);

    h8v Ahf[2], Bhf[4], Xl[4];
    #pragma unroll
    for (int f = 0; f < 2; ++f) Ahf[f] = LDFRAG(cur, 0, ra[f], 0);
    #pragma unroll
    for (int f = 0; f < 4; ++f) Bhf[f] = LDFRAG(cur, 1, rb[f], 0);
    #pragma unroll
    for (int fi = 0; fi < 2; ++fi)
      #pragma unroll
      for (int fj = 0; fj < 4; ++fj)
        acc[fi][fj] = __builtin_amdgcn_mfma_f32_16x16x32_f16(Bhf[fj], Ahf[fi], acc[fi][fj], 0, 0, 0);
    #pragma unroll
    for (int f = 0; f < 2; ++f) Xl[f] = LDFRAG(cur, 0, ra[f], 4);   // Al
    #pragma unroll
    for (int fi = 0; fi < 2; ++fi)
      #pragma unroll
      for (int fj = 0; fj < 4; ++fj)
        acc2[fi][fj] = __builtin_amdgcn_mfma_f32_16x16x32_f16(Bhf[fj], Xl[fi], acc2[fi][fj], 0, 0, 0);
    #pragma unroll
    for (int f = 0; f < 4; ++f) Xl[f] = LDFRAG(cur, 1, rb[f], 4);   // Bl
    #pragma unroll
    for (int fi = 0; fi < 2; ++fi)
      #pragma unroll
      for (int fj = 0; fj < 4; ++fj)
        acc2[fi][fj] = __builtin_amdgcn_mfma_f32_16x16x32_f16(Xl[fj], Ahf[fi], acc2[fi][fj], 0, 0, 0);

    __syncthreads();
    cur ^= 1;
  }
  #undef LDFRAG
  #undef STAGE

  // Swapped-operand C frag: lane holds C[m = lane&15][n = (lane>>4)*4 + reg]
  const float LSC = 1.0f / 2048.0f;
  const int mloc = lane & 15;
  const int nq   = (lane >> 4) << 2;   // 0,4,8,12
  if (MODE == 0){
    #pragma unroll
    for (int fi = 0; fi < 2; ++fi){
      const int grow = row0 + wr + (fi << 4) + mloc;
      #pragma unroll
      for (int fj = 0; fj < 4; ++fj){
        const int gcol = col0 + wc + (fj << 4) + nq;
        const float4 be = *(const float4*)(bias + gcol);
        f4v v;
        v[0] = fmaxf(acc[fi][fj][0] + LSC * acc2[fi][fj][0] + be.x, 0.f);
        v[1] = fmaxf(acc[fi][fj][1] + LSC * acc2[fi][fj][1] + be.y, 0.f);
        v[2] = fmaxf(acc[fi][fj][2] + LSC * acc2[fi][fj][2] + be.z, 0.f);
        v[3] = fmaxf(acc[fi][fj][3] + LSC * acc2[fi][fj][3] + be.w, 0.f);
        // nontemporal: keep the 256 MB acts stream from evicting planes
        __builtin_nontemporal_store(v, (f4v*)(acts + (size_t)grow * FEAT + gcol));
      }
    }
  } else {
    #pragma unroll
    for (int fi = 0; fi < 2; ++fi){
      float ssum = 0.f;
      #pragma unroll
      for (int fj = 0; fj < 4; ++fj){
        const int gcol = col0 + wc + (fj << 4) + nq;
        const float4 be = *(const float4*)(bias + gcol);
        const float4 wk = *(const float4*)(w2 + gcol);
        float h0 = fmaxf(acc[fi][fj][0] + LSC * acc2[fi][fj][0] + be.x, 0.f);
        float h1 = fmaxf(acc[fi][fj][1] + LSC * acc2[fi][fj][1] + be.y, 0.f);
        float h2 = fmaxf(acc[fi][fj][2] + LSC * acc2[fi][fj][2] + be.z, 0.f);
        float h3 = fmaxf(acc[fi][fj][3] + LSC * acc2[fi][fj][3] + be.w, 0.f);
        ssum = fmaf(h0, wk.x, ssum);
        ssum = fmaf(h1, wk.y, ssum);
        ssum = fmaf(h2, wk.z, ssum);
        ssum = fmaf(h3, wk.w, ssum);
      }
      ssum += __shfl_xor(ssum, 16);
      ssum += __shfl_xor(ssum, 32);
      if (lane < 16){
        const int grow = row0 + wr + (fi << 4) + lane;
        zpart[(size_t)grow * 256 + (bx << 1) + (wc >> 6)] = ssum;
      }
    }
  }
}

// ===========================================================================
// PATH B (fallback, proven round-1): on-the-fly bf16 3-split GEMM
// ===========================================================================
template<int MODE>
__global__ __launch_bounds__(256)
void gemm6(const float* __restrict__ X, const float* __restrict__ bsub,
           const float* __restrict__ W, const float* __restrict__ bias,
           const float* __restrict__ w2, float* __restrict__ acts,
           float* __restrict__ zpart)
{
  __shared__ unsigned short sA[3][128][32];
  __shared__ unsigned short sB[3][128][32];
  const int tid  = threadIdx.x;
  const int row0 = blockIdx.y << 7;
  const int col0 = blockIdx.x << 7;
  const int lane = tid & 63, wv = tid >> 6;
  const int wr = (wv & 1) << 6, wc = (wv >> 1) << 6;
  const int fr = lane & 15;
  const int gsw = (((lane >> 4) ^ ((fr >> 1) & 3)) << 3);

  f4v acc[4][4];
  #pragma unroll
  for (int i = 0; i < 4; ++i)
    #pragma unroll
    for (int j = 0; j < 4; ++j)
      acc[i][j] = (f4v){0.f, 0.f, 0.f, 0.f};

  const int rs = tid >> 3;
  const int cb = (tid & 7) << 2;
  const int gq = cb >> 3;

  for (int kt = 0; kt < DIM / 32; ++kt){
    const int k0 = kt << 5;
    #pragma unroll
    for (int i = 0; i < 4; ++i){
      const int r  = (i << 5) + rs;
      const int cs = ((gq ^ ((r >> 1) & 3)) << 3) + (cb & 7);
      {
        const float4 xv = *(const float4*)(X + (size_t)(row0 + r) * DIM + k0 + cb);
        const float4 bd = *(const float4*)(bsub + k0 + cb);
        float v0 = xv.x - bd.x, v1 = xv.y - bd.y, v2 = xv.z - bd.z, v3 = xv.w - bd.w;
        ushort4 H, M, L;
        split3(v0, H.x, M.x, L.x); split3(v1, H.y, M.y, L.y);
        split3(v2, H.z, M.z, L.z); split3(v3, H.w, M.w, L.w);
        *(ushort4*)&sA[0][r][cs] = H;
        *(ushort4*)&sA[1][r][cs] = M;
        *(ushort4*)&sA[2][r][cs] = L;
      }
      {
        const float4 wv4 = *(const float4*)(W + (size_t)(col0 + r) * DIM + k0 + cb);
        ushort4 H, M, L;
        split3(wv4.x, H.x, M.x, L.x); split3(wv4.y, H.y, M.y, L.y);
        split3(wv4.z, H.z, M.z, L.z); split3(wv4.w, H.w, M.w, L.w);
        *(ushort4*)&sB[0][r][cs] = H;
        *(ushort4*)&sB[1][r][cs] = M;
        *(ushort4*)&sB[2][r][cs] = L;
      }
    }
    __syncthreads();
    #pragma unroll
    for (int pa = 0; pa < 3; ++pa){
      s8v a[4];
      #pragma unroll
      for (int fi = 0; fi < 4; ++fi)
        a[fi] = *(const s8v*)&sA[pa][wr + (fi << 4) + fr][gsw];
      #pragma unroll
      for (int pb = 0; pb < 3 - pa; ++pb){
        s8v b[4];
        #pragma unroll
        for (int fj = 0; fj < 4; ++fj)
          b[fj] = *(const s8v*)&sB[pb][wc + (fj << 4) + fr][gsw];
        #pragma unroll
        for (int fi = 0; fi < 4; ++fi)
          #pragma unroll
          for (int fj = 0; fj < 4; ++fj)
            acc[fi][fj] = __builtin_amdgcn_mfma_f32_16x16x32_bf16(a[fi], b[fj], acc[fi][fj], 0, 0, 0);
      }
    }
    __syncthreads();
  }

  const int rq = (lane >> 4) << 2;
  if (MODE == 0){
    #pragma unroll
    for (int fj = 0; fj < 4; ++fj){
      const int gcol = col0 + wc + (fj << 4) + fr;
      const float be = bias[gcol];
      #pragma unroll
      for (int fi = 0; fi < 4; ++fi){
        #pragma unroll
        for (int r = 0; r < 4; ++r){
          const int grow = row0 + wr + (fi << 4) + rq + r;
          float v = acc[fi][fj][r] + be;
          v = fmaxf(v, 0.f);
          acts[(size_t)grow * FEAT + gcol] = v;
        }
      }
    }
  } else {
    float be[4], wk[4];
    #pragma unroll
    for (int fj = 0; fj < 4; ++fj){
      const int gcol = col0 + wc + (fj << 4) + fr;
      be[fj] = bias[gcol];
      wk[fj] = w2[gcol];
    }
    #pragma unroll
    for (int fi = 0; fi < 4; ++fi){
      #pragma unroll
      for (int r = 0; r < 4; ++r){
        float s = 0.f;
        #pragma unroll
        for (int fj = 0; fj < 4; ++fj){
          float h = fmaxf(acc[fi][fj][r] + be[fj], 0.f);
          s = fmaf(h, wk[fj], s);
        }
        s += __shfl_xor(s, 1);
        s += __shfl_xor(s, 2);
        s += __shfl_xor(s, 4);
        s += __shfl_xor(s, 8);
        if (fr == 0){
          const int grow = row0 + wr + (fi << 4) + rq + r;
          zpart[(size_t)grow * 256 + (blockIdx.x << 1) + (wc >> 6)] = s;
        }
      }
    }
  }
}

// ===========================================================================
// shared tail kernels
// ===========================================================================
__global__ __launch_bounds__(256)
void zreduce(const float* __restrict__ zpart, const float* __restrict__ bk2,
             const int* __restrict__ kp, int* __restrict__ mrow)
{
  const int row  = blockIdx.x * 4 + (threadIdx.x >> 6);
  const int lane = threadIdx.x & 63;
  const float* zp = zpart + (size_t)row * 256;
  float s = zp[lane] + zp[lane + 64] + zp[lane + 128] + zp[lane + 192];
  s += __shfl_xor(s, 1);
  s += __shfl_xor(s, 2);
  s += __shfl_xor(s, 4);
  s += __shfl_xor(s, 8);
  s += __shfl_xor(s, 16);
  s += __shfl_xor(s, 32);
  if (lane == 0){
    float z = s + bk2[0];
    float kest = 2.f * (float)(*kp) * (1.f / (1.f + expf(-z)));
    int m = (int)ceilf(kest);
    m = min(max(m, 0), 128);
    mrow[row] = m;
  }
}

__device__ __forceinline__ void radix_find(int* hist, int nbins, int need, int tid,
                                           int* out3, int* blksum)
{
  const int per  = nbins >> 8;
  const int base = tid * per;
  int bs = 0;
  for (int j = 0; j < per; ++j) bs += hist[base + j];
  blksum[tid] = bs;
  __syncthreads();
  if (tid == 0){
    int a2 = 0;
    for (int t = 255; t >= 0; --t){ int v = blksum[t]; blksum[t] = a2; a2 += v; }
  }
  __syncthreads();
  int ch = blksum[tid];
  for (int j = per - 1; j >= 0; --j){
    const int b = base + j;
    const int c = hist[b];
    if (ch < need && need <= ch + c){ out3[0] = b; out3[1] = need - ch; out3[2] = ch; }
    ch += c;
  }
  __syncthreads();
}

// Per-row exact top-m: radix passes on candidates; ">"-set emission and
// min-index tie resolution from LDS candidate list (no 3rd full read).
__global__ __launch_bounds__(256)
void select_topk(const float* __restrict__ acts, const int* __restrict__ mrow,
                 int* __restrict__ selIdx, float* __restrict__ selVal)
{
  __shared__ int hist[2048];
  __shared__ int blksum[256];
  __shared__ int out3[4];
  __shared__ unsigned listU[2048];
  __shared__ int listI[2048];
  __shared__ int lcnt;
  __shared__ int gcnt;

  const int row = blockIdx.x, tid = threadIdx.x;
  const int m = mrow[row];
  const float* rp = acts + (size_t)row * FEAT;

  for (int i = tid; i < 2048; i += 256) hist[i] = 0;
  __syncthreads();
  // pass 1 (vectorized): histogram of bits [31:21]
  for (int it = 0; it < 16; ++it){
    const int i4 = (it << 8) + tid;
    const uint4 u4 = *(const uint4*)(rp + ((size_t)i4 << 2));
    if (u4.x) atomicAdd(&hist[u4.x >> 21], 1);
    if (u4.y) atomicAdd(&hist[u4.y >> 21], 1);
    if (u4.z) atomicAdd(&hist[u4.z >> 21], 1);
    if (u4.w) atomicAdd(&hist[u4.w >> 21], 1);
  }
  __syncthreads();
  radix_find(hist, 2048, m, tid, out3, blksum);
  const int bin1 = out3[0];
  const int rem1 = out3[1];

  if (tid == 0){ lcnt = 0; gcnt = 0; }
  __syncthreads();
  // pass 2 (vectorized): collect (val, idx) for all elements with bin >= bin1
  for (int it = 0; it < 16; ++it){
    const int i4 = (it << 8) + tid;
    const uint4 u4 = *(const uint4*)(rp + ((size_t)i4 << 2));
    const int ib = i4 << 2;
    if ((int)(u4.x >> 21) >= bin1){ int p = atomicAdd(&lcnt, 1); if (p < 2048){ listU[p] = u4.x; listI[p] = ib;     } }
    if ((int)(u4.y >> 21) >= bin1){ int p = atomicAdd(&lcnt, 1); if (p < 2048){ listU[p] = u4.y; listI[p] = ib + 1; } }
    if ((int)(u4.z >> 21) >= bin1){ int p = atomicAdd(&lcnt, 1); if (p < 2048){ listU[p] = u4.z; listI[p] = ib + 2; } }
    if ((int)(u4.w >> 21) >= bin1){ int p = atomicAdd(&lcnt, 1); if (p < 2048){ listU[p] = u4.w; listI[p] = ib + 3; } }
  }
  __syncthreads();
  const int L = min(lcnt, 2048);

  // pass 2b: bits [20:10] among bin1 elements
  for (int i = tid; i < 2048; i += 256) hist[i] = 0;
  __syncthreads();
  for (int i = tid; i < L; i += 256){
    unsigned u = listU[i];
    if ((int)(u >> 21) == bin1) atomicAdd(&hist[(u >> 10) & 0x7FF], 1);
  }
  __syncthreads();
  radix_find(hist, 2048, rem1, tid, out3, blksum);
  const int bin2 = out3[0];
  const int rem2 = out3[1];

  // pass 2c: bits [9:0] among bin1:bin2 elements
  const unsigned topbits = (((unsigned)bin1 << 11) | (unsigned)bin2);
  for (int i = tid; i < 1024; i += 256) hist[i] = 0;
  __syncthreads();
  for (int i = tid; i < L; i += 256){
    unsigned u = listU[i];
    if ((u >> 10) == topbits) atomicAdd(&hist[u & 0x3FF], 1);
  }
  __syncthreads();
  radix_find(hist, 1024, rem2, tid, out3, blksum);
  const int bin3 = out3[0];
  const int mEq  = out3[1];

  const unsigned tbits = ((unsigned)bin1 << 21) | ((unsigned)bin2 << 10) | (unsigned)bin3;
  const int base = row << 7;

  // pass 3: emit ">" set from candidates (order irrelevant: decode sums)
  for (int i = tid; i < L; i += 256){
    unsigned u = listU[i];
    if (u > tbits){
      int p = atomicAdd(&gcnt, 1);
      selIdx[base + p] = listI[i];
      selVal[base + p] = __uint_as_float(u);
    }
  }
  __syncthreads();
  // ties: mEq smallest indices among equals (wave 0, iterative min-extract)
  if (tid < 64){
    const int cnt = gcnt;
    for (int e = 0; e < mEq; ++e){
      int best = 0x7FFFFFFF;
      for (int i = tid; i < L; i += 64)
        if (listU[i] == tbits && listI[i] < best) best = listI[i];
      #pragma unroll
      for (int off = 32; off; off >>= 1) best = min(best, __shfl_xor(best, off));
      if (tid == 0){
        selIdx[base + cnt + e] = best;
        selVal[base + cnt + e] = __uint_as_float(tbits);
      }
      for (int i = tid; i < L; i += 64)
        if (listU[i] == tbits && listI[i] == best) listI[i] = 0x7FFFFFFF;
    }
  }
}

// W_dec [DIM][FEAT] fp32 -> WdT16 [FEAT][DIM] fp16 (halves decode gather bytes)
__global__ __launch_bounds__(256)
void transpose_dec(const float* __restrict__ Wd, _Float16* __restrict__ WdT16)
{
  __shared__ float t[64][65];
  const int f0 = blockIdx.x << 6, d0 = blockIdx.y << 6;
  const int tx = threadIdx.x & 15, ty = threadIdx.x >> 4;
  #pragma unroll
  for (int r = 0; r < 4; ++r){
    const int d = ty + (r << 4);
    const float4 v = *(const float4*)(Wd + (size_t)(d0 + d) * FEAT + f0 + (tx << 2));
    t[d][(tx << 2) + 0] = v.x;
    t[d][(tx << 2) + 1] = v.y;
    t[d][(tx << 2) + 2] = v.z;
    t[d][(tx << 2) + 3] = v.w;
  }
  __syncthreads();
  #pragma unroll
  for (int r = 0; r < 4; ++r){
    const int f = ty + (r << 4);
    ushort4 o;
    o.x = __builtin_bit_cast(unsigned short, (_Float16)t[(tx << 2) + 0][f]);
    o.y = __builtin_bit_cast(unsigned short, (_Float16)t[(tx << 2) + 1][f]);
    o.z = __builtin_bit_cast(unsigned short, (_Float16)t[(tx << 2) + 2][f]);
    o.w = __builtin_bit_cast(unsigned short, (_Float16)t[(tx << 2) + 3][f]);
    *(ushort4*)(WdT16 + (size_t)(f0 + f) * DIM + d0 + (tx << 2)) = o;
  }
}

__global__ __launch_bounds__(256)
void decode_k(const _Float16* __restrict__ WdT16, const int* __restrict__ selIdx,
              const float* __restrict__ selVal, const int* __restrict__ mrow,
              const float* __restrict__ bdec, float* __restrict__ out)
{
  __shared__ int   sI[128];
  __shared__ float sV[128];
  const int row = blockIdx.x, tid = threadIdx.x;
  const int m = mrow[row];
  if (tid < m){
    sI[tid] = selIdx[(row << 7) + tid];
    sV[tid] = selVal[(row << 7) + tid];
  }
  __syncthreads();
  const int d = tid << 3;
  float a[8];
  {
    const float4 b0 = *(const float4*)(bdec + d);
    const float4 b1 = *(const float4*)(bdec + d + 4);
    a[0] = b0.x; a[1] = b0.y; a[2] = b0.z; a[3] = b0.w;
    a[4] = b1.x; a[5] = b1.y; a[6] = b1.z; a[7] = b1.w;
  }
  for (int i = 0; i < m; ++i){
    const float v = sV[i];
    const h8v w = *(const h8v*)(WdT16 + (size_t)sI[i] * DIM + d);
    #pragma unroll
    for (int j = 0; j < 8; ++j)
      a[j] = fmaf(v, (float)w[j], a[j]);
  }
  float4 o0 = {a[0], a[1], a[2], a[3]};
  float4 o1 = {a[4], a[5], a[6], a[7]};
  *(float4*)(out + (size_t)row * DIM + d)     = o0;
  *(float4*)(out + (size_t)row * DIM + d + 4) = o1;
}

// ===========================================================================
extern "C" void kernel_launch(void* const* d_in, const int* in_sizes, int n_in,
                              void* d_out, int out_size, void* d_ws, size_t ws_size,
                              hipStream_t stream)
{
  const float* x    = (const float*)d_in[0];
  const float* Wenc = (const float*)d_in[1];
  const float* benc = (const float*)d_in[2];
  const float* Wk1  = (const float*)d_in[3];
  const float* bk1  = (const float*)d_in[4];
  const float* Wk2  = (const float*)d_in[5];
  const float* bk2  = (const float*)d_in[6];
  const float* Wdec = (const float*)d_in[7];
  const float* bdec = (const float*)d_in[8];
  const int*   kp   = (const int*)d_in[9];
  float* out = (float*)d_out;

  char* ws = (char*)d_ws;
  const size_t XS_BYTES   = (size_t)BATCH * DIM * 2;      // 16 MB per plane
  const size_t ACTS_BYTES = (size_t)BATCH * FEAT * 4;     // 256 MB
  const size_t WP_BYTES   = (size_t)FEAT * DIM * 2;       // 64 MB per plane
  const size_t NEED_A = 2 * XS_BYTES + ACTS_BYTES + 2 * WP_BYTES
                      + 4194304 + 16384 + 2097152 + 2097152;

  if (ws_size >= NEED_A){
    // ---------------- PATH A: fp16 2-split planes, twin GEMMs ----------------
    unsigned short* xs0 = (unsigned short*)ws;
    unsigned short* xs1 = (unsigned short*)(ws + XS_BYTES);
    char* p = ws + 2 * XS_BYTES;
    float* acts = (float*)p;
    _Float16* WdT16 = (_Float16*)p;          // aliased after select (64 MB < 256 MB)
    p += ACTS_BYTES;
    unsigned short* wp0 = (unsigned short*)p;
    unsigned short* wp1 = (unsigned short*)(p + WP_BYTES);
    p += 2 * WP_BYTES;
    float* zpart  = (float*)p;               p += 4194304;
    int*   mrow   = (int*)p;                 p += 16384;
    int*   selIdx = (int*)p;                 p += 2097152;
    float* selVal = (float*)p;

    splitX<<<dim3(BATCH * DIM / 1024), dim3(256), 0, stream>>>(x, bdec, xs0, xs1);
    // kest GEMM first (so Wp region can be reused for Wenc planes)
    splitW<<<dim3(FEAT * DIM / 1024), dim3(256), 0, stream>>>(Wk1, wp0, wp1);
    gemmp<1><<<dim3(4096), dim3(512), 0, stream>>>(xs0, xs1, wp0, wp1,
                                                   bk1, Wk2, nullptr, zpart);
    zreduce<<<dim3(BATCH / 4), dim3(256), 0, stream>>>(zpart, bk2, kp, mrow);
    splitW<<<dim3(FEAT * DIM / 1024), dim3(256), 0, stream>>>(Wenc, wp0, wp1);
    gemmp<0><<<dim3(4096), dim3(512), 0, stream>>>(xs0, xs1, wp0, wp1,
                                                   benc, nullptr, acts, nullptr);
    select_topk<<<dim3(BATCH), dim3(256), 0, stream>>>(acts, mrow, selIdx, selVal);
    transpose_dec<<<dim3(FEAT / 64, DIM / 64), dim3(256), 0, stream>>>(Wdec, WdT16);
    decode_k<<<dim3(BATCH), dim3(256), 0, stream>>>(WdT16, selIdx, selVal, mrow, bdec, out);
  } else {
    // ---------------- PATH B: proven round-1 fallback ----------------
    float* acts   = (float*)ws;
    _Float16* WdT16 = (_Float16*)ws;
    float* zpart  = (float*)(ws + ACTS_BYTES);
    int*   mrow   = (int*)  (ws + ACTS_BYTES + 4194304);
    int*   selIdx = (int*)  (ws + ACTS_BYTES + 4194304 + 16384);
    float* selVal = (float*)(ws + ACTS_BYTES + 4194304 + 16384 + 2097152);

    dim3 gg(FEAT / 128, BATCH / 128);
    gemm6<0><<<gg, dim3(256), 0, stream>>>(x, bdec, Wenc, benc, nullptr, acts, nullptr);
    gemm6<1><<<gg, dim3(256), 0, stream>>>(x, bdec, Wk1, bk1, Wk2, nullptr, zpart);
    zreduce<<<dim3(BATCH / 4), dim3(256), 0, stream>>>(zpart, bk2, kp, mrow);
    select_topk<<<dim3(BATCH), dim3(256), 0, stream>>>(acts, mrow, selIdx, selVal);
    transpose_dec<<<dim3(FEAT / 64, DIM / 64), dim3(256), 0, stream>>>(Wdec, WdT16);
    decode_k<<<dim3(BATCH), dim3(256), 0, stream>>>(WdT16, selIdx, selVal, mrow, bdec, out);
  }
}

// Round 9
// 1497.942 us; speedup vs baseline: 1.5854x; 1.2374x over previous
//
#include <hip/hip_runtime.h>
#include <hip/hip_bf16.h>
#include <cstdint>
#include <cstddef>

#define BATCH 4096
#define DIM   2048
#define FEAT  16384

typedef __attribute__((ext_vector_type(8))) short s8v;
typedef __attribute__((ext_vector_type(8))) _Float16 h8v;
typedef __attribute__((ext_vector_type(4))) float f4v;

__device__ __forceinline__ unsigned short f2bf(float f){
  unsigned u = __float_as_uint(f);
  unsigned r = u + 0x7FFFu + ((u >> 16) & 1u);
  return (unsigned short)(r >> 16);
}
__device__ __forceinline__ float bf2f(unsigned short h){
  return __uint_as_float(((unsigned)h) << 16);
}
__device__ __forceinline__ void split3(float v, unsigned short &h, unsigned short &m, unsigned short &l){
  h = f2bf(v);
  float r1 = v - bf2f(h);
  m = f2bf(r1);
  float r2 = r1 - bf2f(m);
  l = f2bf(r2);
}

// fp16 2-way split: v = h + l/2048 (l stored x2048 to stay in normal range)
__device__ __forceinline__ void split2(float v, unsigned short &h, unsigned short &l){
  _Float16 hf = (_Float16)v;
  _Float16 lf = (_Float16)((v - (float)hf) * 2048.0f);
  h = __builtin_bit_cast(unsigned short, hf);
  l = __builtin_bit_cast(unsigned short, lf);
}

__device__ __forceinline__ void gload16(const void* g, void* l){
  __builtin_amdgcn_global_load_lds(
      (const __attribute__((address_space(1))) void*)g,
      (__attribute__((address_space(3))) void*)l, 16, 0, 0);
}

// ===========================================================================
// split kernels
// ===========================================================================
__global__ __launch_bounds__(256)
void splitX(const float* __restrict__ x, const float* __restrict__ bdec,
            unsigned short* __restrict__ p0, unsigned short* __restrict__ p1)
{
  const size_t i = ((size_t)blockIdx.x * 256 + threadIdx.x) * 4;
  const int col = (int)(i & (DIM - 1));
  const float4 v = *(const float4*)(x + i);
  const float4 b = *(const float4*)(bdec + col);
  float e0 = v.x - b.x, e1 = v.y - b.y, e2 = v.z - b.z, e3 = v.w - b.w;
  ushort4 H, L;
  split2(e0, H.x, L.x); split2(e1, H.y, L.y);
  split2(e2, H.z, L.z); split2(e3, H.w, L.w);
  *(ushort4*)(p0 + i) = H; *(ushort4*)(p1 + i) = L;
}

__global__ __launch_bounds__(256)
void splitW(const float* __restrict__ w,
            unsigned short* __restrict__ p0, unsigned short* __restrict__ p1)
{
  const size_t i = ((size_t)blockIdx.x * 256 + threadIdx.x) * 4;
  const float4 v = *(const float4*)(w + i);
  ushort4 H, L;
  split2(v.x, H.x, L.x); split2(v.y, H.y, L.y);
  split2(v.z, H.z, L.z); split2(v.w, H.w, L.w);
  *(ushort4*)(p0 + i) = H; *(ushort4*)(p1 + i) = L;
}

// hi-plane only (for the approx acts GEMM)
__global__ __launch_bounds__(256)
void splitW1(const float* __restrict__ w, unsigned short* __restrict__ p0)
{
  const size_t i = ((size_t)blockIdx.x * 256 + threadIdx.x) * 4;
  const float4 v = *(const float4*)(w + i);
  ushort4 H;
  H.x = __builtin_bit_cast(unsigned short, (_Float16)v.x);
  H.y = __builtin_bit_cast(unsigned short, (_Float16)v.y);
  H.z = __builtin_bit_cast(unsigned short, (_Float16)v.z);
  H.w = __builtin_bit_cast(unsigned short, (_Float16)v.w);
  *(ushort4*)(p0 + i) = H;
}

// ===========================================================================
// kest GEMM (exact fp32-equivalent, proven round-8 512-thread version)
// ===========================================================================
template<int MODE>
__global__ __launch_bounds__(512, 4)
void gemmp(const unsigned short* __restrict__ Ah_, const unsigned short* __restrict__ Al_,
           const unsigned short* __restrict__ Bh_, const unsigned short* __restrict__ Bl_,
           const float* __restrict__ bias, const float* __restrict__ w2,
           float* __restrict__ acts, float* __restrict__ zpart)
{
  __shared__ unsigned short sAB[2][2][128][64];
  const int tid  = threadIdx.x;
  const int lane = tid & 63, wv = tid >> 6;

  const int bid = blockIdx.x;
  const int xcd = bid & 7;
  const int idx = bid >> 3;
  const int sq  = idx >> 6;
  const int s   = idx & 63;
  const int bx  = (xcd << 4) | ((sq & 1) << 3) | (s & 7);
  const int by  = ((sq >> 1) << 3) | (s >> 3);
  const int row0 = by << 7, col0 = bx << 7;

  const int wr = (wv & 3) << 5, wc = (wv >> 2) << 6;

  f4v acc[2][4], acc2[2][4];
  #pragma unroll
  for (int i = 0; i < 2; ++i)
    #pragma unroll
    for (int j = 0; j < 4; ++j){
      acc[i][j]  = (f4v){0.f, 0.f, 0.f, 0.f};
      acc2[i][j] = (f4v){0.f, 0.f, 0.f, 0.f};
    }

  const unsigned short* gsrc[4];
  unsigned ldsoff[4];
  #pragma unroll
  for (int j = 0; j < 4; ++j){
    const int q = (wv << 2) + j;
    const int mat = q >> 4;
    const int chunk = q & 15;
    const int r  = (chunk << 3) + (lane >> 3);
    const int gl = (lane & 7) ^ (r & 7);
    const int co = (gl & 3) << 3;
    const unsigned short* hi = (mat == 0) ? Ah_ : Bh_;
    const unsigned short* lo = (mat == 0) ? Al_ : Bl_;
    const int rowg = ((mat == 0) ? row0 : col0) + r;
    gsrc[j]  = ((gl < 4) ? hi : lo) + (size_t)rowg * DIM + co;
    ldsoff[j] = (unsigned)(mat * 16384 + chunk * 1024);
  }

  const int fr16 = lane & 15;
  const int kg   = lane >> 4;
  int ra[2], rb[4];
  #pragma unroll
  for (int f = 0; f < 2; ++f) ra[f] = wr + (f << 4) + fr16;
  #pragma unroll
  for (int f = 0; f < 4; ++f) rb[f] = wc + (f << 4) + fr16;

  #define LDFRAG(bf, mat, r, hb) \
    (*(const h8v*)((const char*)sAB + (bf) * 32768 + (mat) * 16384 + (r) * 128 + (((((hb) + kg) ^ ((r) & 7)) << 4))))
  #define STAGE(bf, ko)                                                       \
    {                                                                         \
      _Pragma("unroll")                                                       \
      for (int j = 0; j < 4; ++j)                                             \
        gload16(gsrc[j] + (ko), (char*)sAB + (bf) * 32768 + ldsoff[j]);       \
    }

  int cur = 0;
  STAGE(0, 0);
  __syncthreads();

  for (int kt = 0; kt < DIM / 32; ++kt){
    if (kt < DIM / 32 - 1) STAGE(cur ^ 1, (kt + 1) << 5);

    h8v Ahf[2], Bhf[4], Xl[4];
    #pragma unroll
    for (int f = 0; f < 2; ++f) Ahf[f] = LDFRAG(cur, 0, ra[f], 0);
    #pragma unroll
    for (int f = 0; f < 4; ++f) Bhf[f] = LDFRAG(cur, 1, rb[f], 0);
    #pragma unroll
    for (int fi = 0; fi < 2; ++fi)
      #pragma unroll
      for (int fj = 0; fj < 4; ++fj)
        acc[fi][fj] = __builtin_amdgcn_mfma_f32_16x16x32_f16(Bhf[fj], Ahf[fi], acc[fi][fj], 0, 0, 0);
    #pragma unroll
    for (int f = 0; f < 2; ++f) Xl[f] = LDFRAG(cur, 0, ra[f], 4);
    #pragma unroll
    for (int fi = 0; fi < 2; ++fi)
      #pragma unroll
      for (int fj = 0; fj < 4; ++fj)
        acc2[fi][fj] = __builtin_amdgcn_mfma_f32_16x16x32_f16(Bhf[fj], Xl[fi], acc2[fi][fj], 0, 0, 0);
    #pragma unroll
    for (int f = 0; f < 4; ++f) Xl[f] = LDFRAG(cur, 1, rb[f], 4);
    #pragma unroll
    for (int fi = 0; fi < 2; ++fi)
      #pragma unroll
      for (int fj = 0; fj < 4; ++fj)
        acc2[fi][fj] = __builtin_amdgcn_mfma_f32_16x16x32_f16(Xl[fj], Ahf[fi], acc2[fi][fj], 0, 0, 0);

    __syncthreads();
    cur ^= 1;
  }
  #undef LDFRAG
  #undef STAGE

  const float LSC = 1.0f / 2048.0f;
  const int mloc = lane & 15;
  const int nq   = (lane >> 4) << 2;
  if (MODE == 0){
    #pragma unroll
    for (int fi = 0; fi < 2; ++fi){
      const int grow = row0 + wr + (fi << 4) + mloc;
      #pragma unroll
      for (int fj = 0; fj < 4; ++fj){
        const int gcol = col0 + wc + (fj << 4) + nq;
        const float4 be = *(const float4*)(bias + gcol);
        f4v v;
        v[0] = fmaxf(acc[fi][fj][0] + LSC * acc2[fi][fj][0] + be.x, 0.f);
        v[1] = fmaxf(acc[fi][fj][1] + LSC * acc2[fi][fj][1] + be.y, 0.f);
        v[2] = fmaxf(acc[fi][fj][2] + LSC * acc2[fi][fj][2] + be.z, 0.f);
        v[3] = fmaxf(acc[fi][fj][3] + LSC * acc2[fi][fj][3] + be.w, 0.f);
        __builtin_nontemporal_store(v, (f4v*)(acts + (size_t)grow * FEAT + gcol));
      }
    }
  } else {
    #pragma unroll
    for (int fi = 0; fi < 2; ++fi){
      float ssum = 0.f;
      #pragma unroll
      for (int fj = 0; fj < 4; ++fj){
        const int gcol = col0 + wc + (fj << 4) + nq;
        const float4 be = *(const float4*)(bias + gcol);
        const float4 wk = *(const float4*)(w2 + gcol);
        float h0 = fmaxf(acc[fi][fj][0] + LSC * acc2[fi][fj][0] + be.x, 0.f);
        float h1 = fmaxf(acc[fi][fj][1] + LSC * acc2[fi][fj][1] + be.y, 0.f);
        float h2 = fmaxf(acc[fi][fj][2] + LSC * acc2[fi][fj][2] + be.z, 0.f);
        float h3 = fmaxf(acc[fi][fj][3] + LSC * acc2[fi][fj][3] + be.w, 0.f);
        ssum = fmaf(h0, wk.x, ssum);
        ssum = fmaf(h1, wk.y, ssum);
        ssum = fmaf(h2, wk.z, ssum);
        ssum = fmaf(h3, wk.w, ssum);
      }
      ssum += __shfl_xor(ssum, 16);
      ssum += __shfl_xor(ssum, 32);
      if (lane < 16){
        const int grow = row0 + wr + (fi << 4) + lane;
        zpart[(size_t)grow * 256 + (bx << 1) + (wc >> 6)] = ssum;
      }
    }
  }
}

// ===========================================================================
// Approx acts GEMM: single fp16 product (hi planes only). 128x128 tile,
// BK=32, 4 waves (64x64/wave), dbuf T3-min pipeline, 32 KB LDS.
// LDS rows are 64 B; 16B-group swizzle sw(r) = (r>>1)&3 (2-way = free).
// Swapped-operand MFMA -> row-major C frag -> nt float4 stores.
// ===========================================================================
__global__ __launch_bounds__(256, 4)
void gemma(const unsigned short* __restrict__ Ah_, const unsigned short* __restrict__ Bh_,
           const float* __restrict__ bias, float* __restrict__ acts)
{
  __shared__ unsigned short sAB[2][2][128][32];   // 32 KB
  const int tid  = threadIdx.x;
  const int lane = tid & 63, wv = tid >> 6;

  const int bid = blockIdx.x;
  const int xcd = bid & 7;
  const int idx = bid >> 3;
  const int sq  = idx >> 6;
  const int s   = idx & 63;
  const int bx  = (xcd << 4) | ((sq & 1) << 3) | (s & 7);
  const int by  = ((sq >> 1) << 3) | (s >> 3);
  const int row0 = by << 7, col0 = bx << 7;

  const int wr = (wv & 1) << 6, wc = (wv >> 1) << 6;

  f4v acc[4][4];
  #pragma unroll
  for (int i = 0; i < 4; ++i)
    #pragma unroll
    for (int j = 0; j < 4; ++j)
      acc[i][j] = (f4v){0.f, 0.f, 0.f, 0.f};

  // staging: 16 chunks (8 A + 8 B) of 1024 B; 4 per wave, 1 gload16 each
  const unsigned short* gsrc[4];
  unsigned ldsoff[4];
  #pragma unroll
  for (int j = 0; j < 4; ++j){
    const int q = (wv << 2) + j;       // 0..15
    const int mat = q >> 3;            // 0=A, 1=B
    const int chunk = q & 7;
    const int r  = (chunk << 4) + (lane >> 2);      // 0..127
    const int gl = (lane & 3) ^ ((r >> 1) & 3);
    const int rowg = ((mat == 0) ? row0 : col0) + r;
    gsrc[j]  = ((mat == 0) ? Ah_ : Bh_) + (size_t)rowg * DIM + (gl << 3);
    ldsoff[j] = (unsigned)(mat * 8192 + chunk * 1024);
  }

  const int fr16 = lane & 15;
  const int kg   = lane >> 4;          // 0..3
  int ra[4], rb[4];
  #pragma unroll
  for (int f = 0; f < 4; ++f){ ra[f] = wr + (f << 4) + fr16; rb[f] = wc + (f << 4) + fr16; }

  #define LDFRAGA(bf, mat, r) \
    (*(const h8v*)((const char*)sAB + (bf) * 16384 + (mat) * 8192 + (r) * 64 + (((kg ^ (((r) >> 1) & 3)) << 4))))
  #define STAGEA(bf, ko)                                                      \
    {                                                                         \
      _Pragma("unroll")                                                       \
      for (int j = 0; j < 4; ++j)                                             \
        gload16(gsrc[j] + (ko), (char*)sAB + (bf) * 16384 + ldsoff[j]);       \
    }

  int cur = 0;
  STAGEA(0, 0);
  __syncthreads();

  for (int kt = 0; kt < DIM / 32; ++kt){
    if (kt < DIM / 32 - 1) STAGEA(cur ^ 1, (kt + 1) << 5);

    h8v Ahf[4], Bhf[4];
    #pragma unroll
    for (int f = 0; f < 4; ++f) Ahf[f] = LDFRAGA(cur, 0, ra[f]);
    #pragma unroll
    for (int f = 0; f < 4; ++f) Bhf[f] = LDFRAGA(cur, 1, rb[f]);
    #pragma unroll
    for (int fi = 0; fi < 4; ++fi)
      #pragma unroll
      for (int fj = 0; fj < 4; ++fj)
        acc[fi][fj] = __builtin_amdgcn_mfma_f32_16x16x32_f16(Bhf[fj], Ahf[fi], acc[fi][fj], 0, 0, 0);

    __syncthreads();
    cur ^= 1;
  }
  #undef LDFRAGA
  #undef STAGEA

  const int mloc = lane & 15;
  const int nq   = (lane >> 4) << 2;
  #pragma unroll
  for (int fi = 0; fi < 4; ++fi){
    const int grow = row0 + wr + (fi << 4) + mloc;
    #pragma unroll
    for (int fj = 0; fj < 4; ++fj){
      const int gcol = col0 + wc + (fj << 4) + nq;
      const float4 be = *(const float4*)(bias + gcol);
      f4v v;
      v[0] = fmaxf(acc[fi][fj][0] + be.x, 0.f);
      v[1] = fmaxf(acc[fi][fj][1] + be.y, 0.f);
      v[2] = fmaxf(acc[fi][fj][2] + be.z, 0.f);
      v[3] = fmaxf(acc[fi][fj][3] + be.w, 0.f);
      __builtin_nontemporal_store(v, (f4v*)(acts + (size_t)grow * FEAT + gcol));
    }
  }
}

// ===========================================================================
// tail kernels
// ===========================================================================
__global__ __launch_bounds__(256)
void zreduce(const float* __restrict__ zpart, const float* __restrict__ bk2,
             const int* __restrict__ kp, int* __restrict__ mrow)
{
  const int row  = blockIdx.x * 4 + (threadIdx.x >> 6);
  const int lane = threadIdx.x & 63;
  const float* zp = zpart + (size_t)row * 256;
  float s = zp[lane] + zp[lane + 64] + zp[lane + 128] + zp[lane + 192];
  s += __shfl_xor(s, 1);
  s += __shfl_xor(s, 2);
  s += __shfl_xor(s, 4);
  s += __shfl_xor(s, 8);
  s += __shfl_xor(s, 16);
  s += __shfl_xor(s, 32);
  if (lane == 0){
    float z = s + bk2[0];
    float kest = 2.f * (float)(*kp) * (1.f / (1.f + expf(-z)));
    int m = (int)ceilf(kest);
    m = min(max(m, 0), 128);
    mrow[row] = m;
  }
}

__device__ __forceinline__ void radix_find(int* hist, int nbins, int need, int tid,
                                           int* out3, int* blksum)
{
  const int per  = nbins >> 8;
  const int base = tid * per;
  int bs = 0;
  for (int j = 0; j < per; ++j) bs += hist[base + j];
  blksum[tid] = bs;
  __syncthreads();
  if (tid == 0){
    int a2 = 0;
    for (int t = 255; t >= 0; --t){ int v = blksum[t]; blksum[t] = a2; a2 += v; }
  }
  __syncthreads();
  int ch = blksum[tid];
  for (int j = per - 1; j >= 0; --j){
    const int b = base + j;
    const int c = hist[b];
    if (ch < need && need <= ch + c){ out3[0] = b; out3[1] = need - ch; out3[2] = ch; }
    ch += c;
  }
  __syncthreads();
}

// Band select on approx acts:
//  - radix-find m-th approx value vm
//  - definite: approx > vm + EPS2  (EPS2 = 0.01 = 32 sigma of approx error)
//  - ambiguous: |approx - vm| <= EPS2 -> exact fp64 recompute -> fill rest
__global__ __launch_bounds__(256)
void select_band(const float* __restrict__ acts, const float* __restrict__ x,
                 const float* __restrict__ bdec, const float* __restrict__ Wenc,
                 const int* __restrict__ mrow, int* __restrict__ selIdx,
                 float* __restrict__ selVal, int* __restrict__ scount)
{
  __shared__ int hist[2048];        // later reused as float xcs[2048]
  __shared__ int blksum[256];
  __shared__ int out3[4];
  __shared__ unsigned listU[2048];
  __shared__ int listI[2048];
  __shared__ int lcnt, dcnt, acnt;
  __shared__ unsigned ambU[64];
  __shared__ int ambI[64];
  __shared__ double ambE[64];
  __shared__ double wred[4];

  const int row = blockIdx.x, tid = threadIdx.x;
  const int m = mrow[row];
  const float* rp = acts + (size_t)row * FEAT;
  const int base = row << 7;

  for (int i = tid; i < 2048; i += 256) hist[i] = 0;
  __syncthreads();
  for (int it = 0; it < 16; ++it){
    const int i4 = (it << 8) + tid;
    const uint4 u4 = *(const uint4*)(rp + ((size_t)i4 << 2));
    if (u4.x) atomicAdd(&hist[u4.x >> 21], 1);
    if (u4.y) atomicAdd(&hist[u4.y >> 21], 1);
    if (u4.z) atomicAdd(&hist[u4.z >> 21], 1);
    if (u4.w) atomicAdd(&hist[u4.w >> 21], 1);
  }
  __syncthreads();
  radix_find(hist, 2048, m, tid, out3, blksum);
  const int bin1 = out3[0];
  const int rem1 = out3[1];
  const int bin1m1 = (bin1 > 1) ? bin1 - 1 : 1;   // include one bin below for the band

  if (tid == 0){ lcnt = 0; dcnt = 0; acnt = 0; }
  __syncthreads();
  for (int it = 0; it < 16; ++it){
    const int i4 = (it << 8) + tid;
    const uint4 u4 = *(const uint4*)(rp + ((size_t)i4 << 2));
    const int ib = i4 << 2;
    if (u4.x && (int)(u4.x >> 21) >= bin1m1){ int p = atomicAdd(&lcnt, 1); if (p < 2048){ listU[p] = u4.x; listI[p] = ib;     } }
    if (u4.y && (int)(u4.y >> 21) >= bin1m1){ int p = atomicAdd(&lcnt, 1); if (p < 2048){ listU[p] = u4.y; listI[p] = ib + 1; } }
    if (u4.z && (int)(u4.z >> 21) >= bin1m1){ int p = atomicAdd(&lcnt, 1); if (p < 2048){ listU[p] = u4.z; listI[p] = ib + 2; } }
    if (u4.w && (int)(u4.w >> 21) >= bin1m1){ int p = atomicAdd(&lcnt, 1); if (p < 2048){ listU[p] = u4.w; listI[p] = ib + 3; } }
  }
  __syncthreads();
  const int L = min(lcnt, 2048);

  // bits [20:10] among bin1 elements
  for (int i = tid; i < 2048; i += 256) hist[i] = 0;
  __syncthreads();
  for (int i = tid; i < L; i += 256){
    unsigned u = listU[i];
    if ((int)(u >> 21) == bin1) atomicAdd(&hist[(u >> 10) & 0x7FF], 1);
  }
  __syncthreads();
  radix_find(hist, 2048, rem1, tid, out3, blksum);
  const int bin2 = out3[0];
  const int rem2 = out3[1];

  // bits [9:0]
  const unsigned topbits = (((unsigned)bin1 << 11) | (unsigned)bin2);
  for (int i = tid; i < 1024; i += 256) hist[i] = 0;
  __syncthreads();
  for (int i = tid; i < L; i += 256){
    unsigned u = listU[i];
    if ((u >> 10) == topbits) atomicAdd(&hist[u & 0x3FF], 1);
  }
  __syncthreads();
  radix_find(hist, 1024, rem2, tid, out3, blksum);
  const int bin3 = out3[0];

  const unsigned tbits = ((unsigned)bin1 << 21) | ((unsigned)bin2 << 10) | (unsigned)bin3;
  const float vm = __uint_as_float(tbits);
  const float EPS2 = 0.01f;
  const float lo_cut = vm - EPS2, hi_cut = vm + EPS2;

  // definite emission + ambiguous collection
  for (int i = tid; i < L; i += 256){
    const float f = __uint_as_float(listU[i]);
    if (f > hi_cut){
      int p = atomicAdd(&dcnt, 1);
      selIdx[base + p] = listI[i];
      selVal[base + p] = f;
    } else if (f >= lo_cut){
      int p = atomicAdd(&acnt, 1);
      if (p < 64){ ambU[p] = listU[i]; ambI[p] = listI[i]; }
    }
  }
  __syncthreads();
  const int D = dcnt;
  const int A = min(acnt, 64);
  int need = m - D;
  if (need < 0) need = 0;
  if (need > A) need = A;

  if (need > 0){
    // stage xc = x[row] - bdec in LDS (reuse hist)
    float* xcs = (float*)hist;
    for (int j = tid; j < DIM; j += 256)
      xcs[j] = x[(size_t)row * DIM + j] - bdec[j];
    __syncthreads();
    const int lane = tid & 63, wv = tid >> 6;
    for (int c = 0; c < A; ++c){
      const float* wrow = Wenc + (size_t)ambI[c] * DIM;
      double sd = 0.0;
      for (int j = tid; j < DIM; j += 256)
        sd += (double)xcs[j] * (double)wrow[j];
      #pragma unroll
      for (int off = 32; off; off >>= 1) sd += __shfl_xor(sd, off);
      if (lane == 0) wred[wv] = sd;
      __syncthreads();
      if (tid == 0) ambE[c] = wred[0] + wred[1] + wred[2] + wred[3];
      __syncthreads();
    }
    // pick `need` largest by (exact desc, index asc)
    if (tid == 0){
      for (int e = 0; e < need; ++e){
        int best = -1;
        for (int c = 0; c < A; ++c){
          if (ambI[c] < 0) continue;
          if (best < 0 || ambE[c] > ambE[best] ||
              (ambE[c] == ambE[best] && ambI[c] < ambI[best])) best = c;
        }
        selIdx[base + D + e] = ambI[best];
        selVal[base + D + e] = __uint_as_float(ambU[best]);
        ambI[best] = -1;
      }
    }
  }
  if (tid == 0) scount[row] = D + need;
}

// W_dec [DIM][FEAT] fp32 -> WdT16 [FEAT][DIM] fp16
__global__ __launch_bounds__(256)
void transpose_dec(const float* __restrict__ Wd, _Float16* __restrict__ WdT16)
{
  __shared__ float t[64][65];
  const int f0 = blockIdx.x << 6, d0 = blockIdx.y << 6;
  const int tx = threadIdx.x & 15, ty = threadIdx.x >> 4;
  #pragma unroll
  for (int r = 0; r < 4; ++r){
    const int d = ty + (r << 4);
    const float4 v = *(const float4*)(Wd + (size_t)(d0 + d) * FEAT + f0 + (tx << 2));
    t[d][(tx << 2) + 0] = v.x;
    t[d][(tx << 2) + 1] = v.y;
    t[d][(tx << 2) + 2] = v.z;
    t[d][(tx << 2) + 3] = v.w;
  }
  __syncthreads();
  #pragma unroll
  for (int r = 0; r < 4; ++r){
    const int f = ty + (r << 4);
    ushort4 o;
    o.x = __builtin_bit_cast(unsigned short, (_Float16)t[(tx << 2) + 0][f]);
    o.y = __builtin_bit_cast(unsigned short, (_Float16)t[(tx << 2) + 1][f]);
    o.z = __builtin_bit_cast(unsigned short, (_Float16)t[(tx << 2) + 2][f]);
    o.w = __builtin_bit_cast(unsigned short, (_Float16)t[(tx << 2) + 3][f]);
    *(ushort4*)(WdT16 + (size_t)(f0 + f) * DIM + d0 + (tx << 2)) = o;
  }
}

__global__ __launch_bounds__(256)
void decode_k(const _Float16* __restrict__ WdT16, const int* __restrict__ selIdx,
              const float* __restrict__ selVal, const int* __restrict__ scount,
              const float* __restrict__ bdec, float* __restrict__ out)
{
  __shared__ int   sI[128];
  __shared__ float sV[128];
  const int row = blockIdx.x, tid = threadIdx.x;
  const int m = scount[row];
  if (tid < m){
    sI[tid] = selIdx[(row << 7) + tid];
    sV[tid] = selVal[(row << 7) + tid];
  }
  __syncthreads();
  const int d = tid << 3;
  float a[8];
  {
    const float4 b0 = *(const float4*)(bdec + d);
    const float4 b1 = *(const float4*)(bdec + d + 4);
    a[0] = b0.x; a[1] = b0.y; a[2] = b0.z; a[3] = b0.w;
    a[4] = b1.x; a[5] = b1.y; a[6] = b1.z; a[7] = b1.w;
  }
  for (int i = 0; i < m; ++i){
    const float v = sV[i];
    const h8v w = *(const h8v*)(WdT16 + (size_t)sI[i] * DIM + d);
    #pragma unroll
    for (int j = 0; j < 8; ++j)
      a[j] = fmaf(v, (float)w[j], a[j]);
  }
  float4 o0 = {a[0], a[1], a[2], a[3]};
  float4 o1 = {a[4], a[5], a[6], a[7]};
  *(float4*)(out + (size_t)row * DIM + d)     = o0;
  *(float4*)(out + (size_t)row * DIM + d + 4) = o1;
}

// ===========================================================================
extern "C" void kernel_launch(void* const* d_in, const int* in_sizes, int n_in,
                              void* d_out, int out_size, void* d_ws, size_t ws_size,
                              hipStream_t stream)
{
  const float* x    = (const float*)d_in[0];
  const float* Wenc = (const float*)d_in[1];
  const float* benc = (const float*)d_in[2];
  const float* Wk1  = (const float*)d_in[3];
  const float* bk1  = (const float*)d_in[4];
  const float* Wk2  = (const float*)d_in[5];
  const float* bk2  = (const float*)d_in[6];
  const float* Wdec = (const float*)d_in[7];
  const float* bdec = (const float*)d_in[8];
  const int*   kp   = (const int*)d_in[9];
  float* out = (float*)d_out;

  char* ws = (char*)d_ws;
  const size_t XS_BYTES   = (size_t)BATCH * DIM * 2;      // 16 MB per plane
  const size_t ACTS_BYTES = (size_t)BATCH * FEAT * 4;     // 256 MB
  const size_t WP_BYTES   = (size_t)FEAT * DIM * 2;       // 64 MB per plane
  const size_t NEED_A = 2 * XS_BYTES + ACTS_BYTES + 2 * WP_BYTES
                      + 4194304 + 16384 + 2097152 + 2097152 + 16384;

  // ---------------- PATH A ----------------
  unsigned short* xs0 = (unsigned short*)ws;
  unsigned short* xs1 = (unsigned short*)(ws + XS_BYTES);
  char* p = ws + 2 * XS_BYTES;
  float* acts = (float*)p;
  _Float16* WdT16 = (_Float16*)p;          // aliased after select
  p += ACTS_BYTES;
  unsigned short* wp0 = (unsigned short*)p;
  unsigned short* wp1 = (unsigned short*)(p + WP_BYTES);
  p += 2 * WP_BYTES;
  float* zpart  = (float*)p;               p += 4194304;
  int*   mrow   = (int*)p;                 p += 16384;
  int*   selIdx = (int*)p;                 p += 2097152;
  float* selVal = (float*)p;               p += 2097152;
  int*   scount = (int*)p;

  (void)ws_size; (void)NEED_A; (void)in_sizes; (void)n_in; (void)out_size;

  splitX<<<dim3(BATCH * DIM / 1024), dim3(256), 0, stream>>>(x, bdec, xs0, xs1);
  // exact kest GEMM first (wp reused afterwards)
  splitW<<<dim3(FEAT * DIM / 1024), dim3(256), 0, stream>>>(Wk1, wp0, wp1);
  gemmp<1><<<dim3(4096), dim3(512), 0, stream>>>(xs0, xs1, wp0, wp1,
                                                 bk1, Wk2, nullptr, zpart);
  zreduce<<<dim3(BATCH / 4), dim3(256), 0, stream>>>(zpart, bk2, kp, mrow);
  // approx acts GEMM (hi planes only)
  splitW1<<<dim3(FEAT * DIM / 1024), dim3(256), 0, stream>>>(Wenc, wp0);
  gemma<<<dim3(4096), dim3(256), 0, stream>>>(xs0, wp0, benc, acts);
  select_band<<<dim3(BATCH), dim3(256), 0, stream>>>(acts, x, bdec, Wenc, mrow,
                                                     selIdx, selVal, scount);
  transpose_dec<<<dim3(FEAT / 64, DIM / 64), dim3(256), 0, stream>>>(Wdec, WdT16);
  decode_k<<<dim3(BATCH), dim3(256), 0, stream>>>(WdT16, selIdx, selVal, scount, bdec, out);
}

// Round 10
// 1253.421 us; speedup vs baseline: 1.8947x; 1.1951x over previous
//
#include <hip/hip_runtime.h>
#include <hip/hip_bf16.h>
#include <cstdint>
#include <cstddef>

#define BATCH 4096
#define DIM   2048
#define FEAT  16384
#define MAXF  2048          // cap on flagged rows for exact kest recompute

typedef __attribute__((ext_vector_type(8))) short s8v;
typedef __attribute__((ext_vector_type(8))) _Float16 h8v;
typedef __attribute__((ext_vector_type(4))) float f4v;

__device__ __forceinline__ void split2(float v, unsigned short &h, unsigned short &l){
  _Float16 hf = (_Float16)v;
  _Float16 lf = (_Float16)((v - (float)hf) * 2048.0f);
  h = __builtin_bit_cast(unsigned short, hf);
  l = __builtin_bit_cast(unsigned short, lf);
}

__device__ __forceinline__ void gload16(const void* g, void* l){
  __builtin_amdgcn_global_load_lds(
      (const __attribute__((address_space(1))) void*)g,
      (__attribute__((address_space(3))) void*)l, 16, 0, 0);
}

// ===========================================================================
// split kernels
// ===========================================================================
__global__ __launch_bounds__(256)
void splitX(const float* __restrict__ x, const float* __restrict__ bdec,
            unsigned short* __restrict__ p0, unsigned short* __restrict__ p1)
{
  const size_t i = ((size_t)blockIdx.x * 256 + threadIdx.x) * 4;
  const int col = (int)(i & (DIM - 1));
  const float4 v = *(const float4*)(x + i);
  const float4 b = *(const float4*)(bdec + col);
  float e0 = v.x - b.x, e1 = v.y - b.y, e2 = v.z - b.z, e3 = v.w - b.w;
  ushort4 H, L;
  split2(e0, H.x, L.x); split2(e1, H.y, L.y);
  split2(e2, H.z, L.z); split2(e3, H.w, L.w);
  *(ushort4*)(p0 + i) = H; *(ushort4*)(p1 + i) = L;
}

__global__ __launch_bounds__(256)
void splitW(const float* __restrict__ w,
            unsigned short* __restrict__ p0, unsigned short* __restrict__ p1)
{
  const size_t i = ((size_t)blockIdx.x * 256 + threadIdx.x) * 4;
  const float4 v = *(const float4*)(w + i);
  ushort4 H, L;
  split2(v.x, H.x, L.x); split2(v.y, H.y, L.y);
  split2(v.z, H.z, L.z); split2(v.w, H.w, L.w);
  *(ushort4*)(p0 + i) = H; *(ushort4*)(p1 + i) = L;
}

// hi-plane only
__global__ __launch_bounds__(256)
void splitW1(const float* __restrict__ w, unsigned short* __restrict__ p0)
{
  const size_t i = ((size_t)blockIdx.x * 256 + threadIdx.x) * 4;
  const float4 v = *(const float4*)(w + i);
  ushort4 H;
  H.x = __builtin_bit_cast(unsigned short, (_Float16)v.x);
  H.y = __builtin_bit_cast(unsigned short, (_Float16)v.y);
  H.z = __builtin_bit_cast(unsigned short, (_Float16)v.z);
  H.w = __builtin_bit_cast(unsigned short, (_Float16)v.w);
  *(ushort4*)(p0 + i) = H;
}

// ===========================================================================
// Approx GEMM (1 fp16 product, hi planes). MODE 0: relu+bias -> acts store.
// MODE 1: relu+bias then w2-weighted col reduce -> zpart (kest approx).
// 128x128 tile, BK=32, 4 waves, dbuf T3-min pipeline, 32 KB LDS.
// ===========================================================================
template<int MODE>
__global__ __launch_bounds__(256, 4)
void gemma(const unsigned short* __restrict__ Ah_, const unsigned short* __restrict__ Bh_,
           const float* __restrict__ bias, const float* __restrict__ w2,
           float* __restrict__ acts, float* __restrict__ zpart)
{
  __shared__ unsigned short sAB[2][2][128][32];   // 32 KB
  const int tid  = threadIdx.x;
  const int lane = tid & 63, wv = tid >> 6;

  const int bid = blockIdx.x;
  const int xcd = bid & 7;
  const int idx = bid >> 3;
  const int sq  = idx >> 6;
  const int s   = idx & 63;
  const int bx  = (xcd << 4) | ((sq & 1) << 3) | (s & 7);
  const int by  = ((sq >> 1) << 3) | (s >> 3);
  const int row0 = by << 7, col0 = bx << 7;

  const int wr = (wv & 1) << 6, wc = (wv >> 1) << 6;

  f4v acc[4][4];
  #pragma unroll
  for (int i = 0; i < 4; ++i)
    #pragma unroll
    for (int j = 0; j < 4; ++j)
      acc[i][j] = (f4v){0.f, 0.f, 0.f, 0.f};

  const unsigned short* gsrc[4];
  unsigned ldsoff[4];
  #pragma unroll
  for (int j = 0; j < 4; ++j){
    const int q = (wv << 2) + j;       // 0..15
    const int mat = q >> 3;            // 0=A, 1=B
    const int chunk = q & 7;
    const int r  = (chunk << 4) + (lane >> 2);      // 0..127
    const int gl = (lane & 3) ^ ((r >> 1) & 3);
    const int rowg = ((mat == 0) ? row0 : col0) + r;
    gsrc[j]  = ((mat == 0) ? Ah_ : Bh_) + (size_t)rowg * DIM + (gl << 3);
    ldsoff[j] = (unsigned)(mat * 8192 + chunk * 1024);
  }

  const int fr16 = lane & 15;
  const int kg   = lane >> 4;
  int ra[4], rb[4];
  #pragma unroll
  for (int f = 0; f < 4; ++f){ ra[f] = wr + (f << 4) + fr16; rb[f] = wc + (f << 4) + fr16; }

  #define LDFRAGA(bf, mat, r) \
    (*(const h8v*)((const char*)sAB + (bf) * 16384 + (mat) * 8192 + (r) * 64 + (((kg ^ (((r) >> 1) & 3)) << 4))))
  #define STAGEA(bf, ko)                                                      \
    {                                                                         \
      _Pragma("unroll")                                                       \
      for (int j = 0; j < 4; ++j)                                             \
        gload16(gsrc[j] + (ko), (char*)sAB + (bf) * 16384 + ldsoff[j]);       \
    }

  int cur = 0;
  STAGEA(0, 0);
  __syncthreads();

  for (int kt = 0; kt < DIM / 32; ++kt){
    if (kt < DIM / 32 - 1) STAGEA(cur ^ 1, (kt + 1) << 5);

    h8v Ahf[4], Bhf[4];
    #pragma unroll
    for (int f = 0; f < 4; ++f) Ahf[f] = LDFRAGA(cur, 0, ra[f]);
    #pragma unroll
    for (int f = 0; f < 4; ++f) Bhf[f] = LDFRAGA(cur, 1, rb[f]);
    #pragma unroll
    for (int fi = 0; fi < 4; ++fi)
      #pragma unroll
      for (int fj = 0; fj < 4; ++fj)
        acc[fi][fj] = __builtin_amdgcn_mfma_f32_16x16x32_f16(Bhf[fj], Ahf[fi], acc[fi][fj], 0, 0, 0);

    __syncthreads();
    cur ^= 1;
  }
  #undef LDFRAGA
  #undef STAGEA

  const int mloc = lane & 15;
  const int nq   = (lane >> 4) << 2;
  if (MODE == 0){
    #pragma unroll
    for (int fi = 0; fi < 4; ++fi){
      const int grow = row0 + wr + (fi << 4) + mloc;
      #pragma unroll
      for (int fj = 0; fj < 4; ++fj){
        const int gcol = col0 + wc + (fj << 4) + nq;
        const float4 be = *(const float4*)(bias + gcol);
        f4v v;
        v[0] = fmaxf(acc[fi][fj][0] + be.x, 0.f);
        v[1] = fmaxf(acc[fi][fj][1] + be.y, 0.f);
        v[2] = fmaxf(acc[fi][fj][2] + be.z, 0.f);
        v[3] = fmaxf(acc[fi][fj][3] + be.w, 0.f);
        __builtin_nontemporal_store(v, (f4v*)(acts + (size_t)grow * FEAT + gcol));
      }
    }
  } else {
    #pragma unroll
    for (int fi = 0; fi < 4; ++fi){
      float ssum = 0.f;
      #pragma unroll
      for (int fj = 0; fj < 4; ++fj){
        const int gcol = col0 + wc + (fj << 4) + nq;
        const float4 be = *(const float4*)(bias + gcol);
        const float4 wk = *(const float4*)(w2 + gcol);
        float h0 = fmaxf(acc[fi][fj][0] + be.x, 0.f);
        float h1 = fmaxf(acc[fi][fj][1] + be.y, 0.f);
        float h2 = fmaxf(acc[fi][fj][2] + be.z, 0.f);
        float h3 = fmaxf(acc[fi][fj][3] + be.w, 0.f);
        ssum = fmaf(h0, wk.x, ssum);
        ssum = fmaf(h1, wk.y, ssum);
        ssum = fmaf(h2, wk.z, ssum);
        ssum = fmaf(h3, wk.w, ssum);
      }
      ssum += __shfl_xor(ssum, 16);
      ssum += __shfl_xor(ssum, 32);
      if (lane < 16){
        const int grow = row0 + wr + (fi << 4) + lane;
        zpart[(size_t)grow * 256 + (bx << 1) + (wc >> 6)] = ssum;
      }
    }
  }
}

// ===========================================================================
// Exact kest GEMM on GATHERED flagged rows (3-product fp32-equivalent).
// grid = 16 row-panels x 128 col-panels; early-exit past *nflag.
// Writes zexact[pos*256 + colblk] (pos = position in rowList).
// ===========================================================================
__global__ __launch_bounds__(512, 4)
void gemmx(const unsigned short* __restrict__ Ah_, const unsigned short* __restrict__ Al_,
           const unsigned short* __restrict__ Bh_, const unsigned short* __restrict__ Bl_,
           const float* __restrict__ bias, const float* __restrict__ w2,
           const int* __restrict__ rowList, const int* __restrict__ nflagp,
           float* __restrict__ zexact)
{
  const int panel = blockIdx.x >> 7;          // 0..15
  const int bx    = blockIdx.x & 127;
  const int row0p = panel << 7;
  if (row0p >= *nflagp) return;
  const int col0 = bx << 7;

  __shared__ unsigned short sAB[2][2][128][64];
  const int tid  = threadIdx.x;
  const int lane = tid & 63, wv = tid >> 6;
  const int wr = (wv & 3) << 5, wc = (wv >> 2) << 6;

  f4v acc[2][4], acc2[2][4];
  #pragma unroll
  for (int i = 0; i < 2; ++i)
    #pragma unroll
    for (int j = 0; j < 4; ++j){
      acc[i][j]  = (f4v){0.f, 0.f, 0.f, 0.f};
      acc2[i][j] = (f4v){0.f, 0.f, 0.f, 0.f};
    }

  const unsigned short* gsrc[4];
  unsigned ldsoff[4];
  #pragma unroll
  for (int j = 0; j < 4; ++j){
    const int q = (wv << 2) + j;
    const int mat = q >> 4;
    const int chunk = q & 15;
    const int r  = (chunk << 3) + (lane >> 3);
    const int gl = (lane & 7) ^ (r & 7);
    const int co = (gl & 3) << 3;
    const unsigned short* hi = (mat == 0) ? Ah_ : Bh_;
    const unsigned short* lo = (mat == 0) ? Al_ : Bl_;
    const int rowg = (mat == 0) ? rowList[row0p + r] : (col0 + r);
    gsrc[j]  = ((gl < 4) ? hi : lo) + (size_t)rowg * DIM + co;
    ldsoff[j] = (unsigned)(mat * 16384 + chunk * 1024);
  }

  const int fr16 = lane & 15;
  const int kg   = lane >> 4;
  int ra[2], rb[4];
  #pragma unroll
  for (int f = 0; f < 2; ++f) ra[f] = wr + (f << 4) + fr16;
  #pragma unroll
  for (int f = 0; f < 4; ++f) rb[f] = wc + (f << 4) + fr16;

  #define LDFRAG(bf, mat, r, hb) \
    (*(const h8v*)((const char*)sAB + (bf) * 32768 + (mat) * 16384 + (r) * 128 + (((((hb) + kg) ^ ((r) & 7)) << 4))))
  #define STAGE(bf, ko)                                                       \
    {                                                                         \
      _Pragma("unroll")                                                       \
      for (int j = 0; j < 4; ++j)                                             \
        gload16(gsrc[j] + (ko), (char*)sAB + (bf) * 32768 + ldsoff[j]);       \
    }

  int cur = 0;
  STAGE(0, 0);
  __syncthreads();

  for (int kt = 0; kt < DIM / 32; ++kt){
    if (kt < DIM / 32 - 1) STAGE(cur ^ 1, (kt + 1) << 5);

    h8v Ahf[2], Bhf[4], Xl[4];
    #pragma unroll
    for (int f = 0; f < 2; ++f) Ahf[f] = LDFRAG(cur, 0, ra[f], 0);
    #pragma unroll
    for (int f = 0; f < 4; ++f) Bhf[f] = LDFRAG(cur, 1, rb[f], 0);
    #pragma unroll
    for (int fi = 0; fi < 2; ++fi)
      #pragma unroll
      for (int fj = 0; fj < 4; ++fj)
        acc[fi][fj] = __builtin_amdgcn_mfma_f32_16x16x32_f16(Bhf[fj], Ahf[fi], acc[fi][fj], 0, 0, 0);
    #pragma unroll
    for (int f = 0; f < 2; ++f) Xl[f] = LDFRAG(cur, 0, ra[f], 4);
    #pragma unroll
    for (int fi = 0; fi < 2; ++fi)
      #pragma unroll
      for (int fj = 0; fj < 4; ++fj)
        acc2[fi][fj] = __builtin_amdgcn_mfma_f32_16x16x32_f16(Bhf[fj], Xl[fi], acc2[fi][fj], 0, 0, 0);
    #pragma unroll
    for (int f = 0; f < 4; ++f) Xl[f] = LDFRAG(cur, 1, rb[f], 4);
    #pragma unroll
    for (int fi = 0; fi < 2; ++fi)
      #pragma unroll
      for (int fj = 0; fj < 4; ++fj)
        acc2[fi][fj] = __builtin_amdgcn_mfma_f32_16x16x32_f16(Xl[fj], Ahf[fi], acc2[fi][fj], 0, 0, 0);

    __syncthreads();
    cur ^= 1;
  }
  #undef LDFRAG
  #undef STAGE

  const float LSC = 1.0f / 2048.0f;
  const int nq = (lane >> 4) << 2;
  #pragma unroll
  for (int fi = 0; fi < 2; ++fi){
    float ssum = 0.f;
    #pragma unroll
    for (int fj = 0; fj < 4; ++fj){
      const int gcol = col0 + wc + (fj << 4) + nq;
      const float4 be = *(const float4*)(bias + gcol);
      const float4 wk = *(const float4*)(w2 + gcol);
      float h0 = fmaxf(acc[fi][fj][0] + LSC * acc2[fi][fj][0] + be.x, 0.f);
      float h1 = fmaxf(acc[fi][fj][1] + LSC * acc2[fi][fj][1] + be.y, 0.f);
      float h2 = fmaxf(acc[fi][fj][2] + LSC * acc2[fi][fj][2] + be.z, 0.f);
      float h3 = fmaxf(acc[fi][fj][3] + LSC * acc2[fi][fj][3] + be.w, 0.f);
      ssum = fmaf(h0, wk.x, ssum);
      ssum = fmaf(h1, wk.y, ssum);
      ssum = fmaf(h2, wk.z, ssum);
      ssum = fmaf(h3, wk.w, ssum);
    }
    ssum += __shfl_xor(ssum, 16);
    ssum += __shfl_xor(ssum, 32);
    if (lane < 16){
      const int pos = row0p + wr + (fi << 4) + lane;
      zexact[(size_t)pos * 256 + (bx << 1) + (wc >> 6)] = ssum;
    }
  }
}

// ===========================================================================
// tail kernels
// ===========================================================================
__global__ __launch_bounds__(256)
void zinit(int* __restrict__ rowList, int* __restrict__ nflag)
{
  const int i = blockIdx.x * 256 + threadIdx.x;
  if (i < MAXF) rowList[i] = 0;
  if (i == 0) *nflag = 0;
}

// approx kest -> provisional m; flag integer-adjacent rows for exact recompute
__global__ __launch_bounds__(256)
void zreduce_flag(const float* __restrict__ zpart, const float* __restrict__ bk2,
                  const int* __restrict__ kp, int* __restrict__ mrow,
                  int* __restrict__ rowList, int* __restrict__ nflag)
{
  const int row  = blockIdx.x * 4 + (threadIdx.x >> 6);
  const int lane = threadIdx.x & 63;
  const float* zp = zpart + (size_t)row * 256;
  float s = zp[lane] + zp[lane + 64] + zp[lane + 128] + zp[lane + 192];
  s += __shfl_xor(s, 1);
  s += __shfl_xor(s, 2);
  s += __shfl_xor(s, 4);
  s += __shfl_xor(s, 8);
  s += __shfl_xor(s, 16);
  s += __shfl_xor(s, 32);
  if (lane == 0){
    float z = s + bk2[0];
    float kest = 2.f * (float)(*kp) * (1.f / (1.f + expf(-z)));
    int m = (int)ceilf(kest);
    m = min(max(m, 0), 128);
    mrow[row] = m;
    const float frac = kest - floorf(kest);
    const float dmin = fminf(frac, 1.f - frac);
    if (dmin < 0.1f){
      int p = atomicAdd(nflag, 1);
      if (p < MAXF) rowList[p] = row;
    }
  }
}

// exact m for flagged rows
__global__ __launch_bounds__(256)
void zreduce2(const float* __restrict__ zexact, const int* __restrict__ rowList,
              const int* __restrict__ nflagp, const float* __restrict__ bk2,
              const int* __restrict__ kp, int* __restrict__ mrow)
{
  const int pos  = blockIdx.x * 4 + (threadIdx.x >> 6);
  const int lane = threadIdx.x & 63;
  const int nf = min(*nflagp, MAXF);
  if (pos >= nf) return;
  const float* zp = zexact + (size_t)pos * 256;
  float s = zp[lane] + zp[lane + 64] + zp[lane + 128] + zp[lane + 192];
  s += __shfl_xor(s, 1);
  s += __shfl_xor(s, 2);
  s += __shfl_xor(s, 4);
  s += __shfl_xor(s, 8);
  s += __shfl_xor(s, 16);
  s += __shfl_xor(s, 32);
  if (lane == 0){
    float z = s + bk2[0];
    float kest = 2.f * (float)(*kp) * (1.f / (1.f + expf(-z)));
    int m = (int)ceilf(kest);
    m = min(max(m, 0), 128);
    mrow[rowList[pos]] = m;
  }
}

__device__ __forceinline__ void radix_find(int* hist, int nbins, int need, int tid,
                                           int* out3, int* blksum)
{
  const int per  = nbins >> 8;
  const int base = tid * per;
  int bs = 0;
  for (int j = 0; j < per; ++j) bs += hist[base + j];
  blksum[tid] = bs;
  __syncthreads();
  if (tid == 0){
    int a2 = 0;
    for (int t = 255; t >= 0; --t){ int v = blksum[t]; blksum[t] = a2; a2 += v; }
  }
  __syncthreads();
  int ch = blksum[tid];
  for (int j = per - 1; j >= 0; --j){
    const int b = base + j;
    const int c = hist[b];
    if (ch < need && need <= ch + c){ out3[0] = b; out3[1] = need - ch; out3[2] = ch; }
    ch += c;
  }
  __syncthreads();
}

// Band select on approx acts (proven round-9): definite > vm+EPS2;
// ambiguous within +-EPS2 -> exact fp64 recompute -> fill.
__global__ __launch_bounds__(256)
void select_band(const float* __restrict__ acts, const float* __restrict__ x,
                 const float* __restrict__ bdec, const float* __restrict__ Wenc,
                 const int* __restrict__ mrow, int* __restrict__ selIdx,
                 float* __restrict__ selVal, int* __restrict__ scount)
{
  __shared__ int hist[2048];        // later reused as float xcs[2048]
  __shared__ int blksum[256];
  __shared__ int out3[4];
  __shared__ unsigned listU[2048];
  __shared__ int listI[2048];
  __shared__ int lcnt, dcnt, acnt;
  __shared__ unsigned ambU[64];
  __shared__ int ambI[64];
  __shared__ double ambE[64];
  __shared__ double wred[4];

  const int row = blockIdx.x, tid = threadIdx.x;
  const int m = mrow[row];
  const float* rp = acts + (size_t)row * FEAT;
  const int base = row << 7;

  for (int i = tid; i < 2048; i += 256) hist[i] = 0;
  __syncthreads();
  for (int it = 0; it < 16; ++it){
    const int i4 = (it << 8) + tid;
    const uint4 u4 = *(const uint4*)(rp + ((size_t)i4 << 2));
    if (u4.x) atomicAdd(&hist[u4.x >> 21], 1);
    if (u4.y) atomicAdd(&hist[u4.y >> 21], 1);
    if (u4.z) atomicAdd(&hist[u4.z >> 21], 1);
    if (u4.w) atomicAdd(&hist[u4.w >> 21], 1);
  }
  __syncthreads();
  radix_find(hist, 2048, m, tid, out3, blksum);
  const int bin1 = out3[0];
  const int rem1 = out3[1];
  const int bin1m1 = (bin1 > 1) ? bin1 - 1 : 1;

  if (tid == 0){ lcnt = 0; dcnt = 0; acnt = 0; }
  __syncthreads();
  for (int it = 0; it < 16; ++it){
    const int i4 = (it << 8) + tid;
    const uint4 u4 = *(const uint4*)(rp + ((size_t)i4 << 2));
    const int ib = i4 << 2;
    if (u4.x && (int)(u4.x >> 21) >= bin1m1){ int p = atomicAdd(&lcnt, 1); if (p < 2048){ listU[p] = u4.x; listI[p] = ib;     } }
    if (u4.y && (int)(u4.y >> 21) >= bin1m1){ int p = atomicAdd(&lcnt, 1); if (p < 2048){ listU[p] = u4.y; listI[p] = ib + 1; } }
    if (u4.z && (int)(u4.z >> 21) >= bin1m1){ int p = atomicAdd(&lcnt, 1); if (p < 2048){ listU[p] = u4.z; listI[p] = ib + 2; } }
    if (u4.w && (int)(u4.w >> 21) >= bin1m1){ int p = atomicAdd(&lcnt, 1); if (p < 2048){ listU[p] = u4.w; listI[p] = ib + 3; } }
  }
  __syncthreads();
  const int L = min(lcnt, 2048);

  for (int i = tid; i < 2048; i += 256) hist[i] = 0;
  __syncthreads();
  for (int i = tid; i < L; i += 256){
    unsigned u = listU[i];
    if ((int)(u >> 21) == bin1) atomicAdd(&hist[(u >> 10) & 0x7FF], 1);
  }
  __syncthreads();
  radix_find(hist, 2048, rem1, tid, out3, blksum);
  const int bin2 = out3[0];
  const int rem2 = out3[1];

  const unsigned topbits = (((unsigned)bin1 << 11) | (unsigned)bin2);
  for (int i = tid; i < 1024; i += 256) hist[i] = 0;
  __syncthreads();
  for (int i = tid; i < L; i += 256){
    unsigned u = listU[i];
    if ((u >> 10) == topbits) atomicAdd(&hist[u & 0x3FF], 1);
  }
  __syncthreads();
  radix_find(hist, 1024, rem2, tid, out3, blksum);
  const int bin3 = out3[0];

  const unsigned tbits = ((unsigned)bin1 << 21) | ((unsigned)bin2 << 10) | (unsigned)bin3;
  const float vm = __uint_as_float(tbits);
  const float EPS2 = 0.01f;
  const float lo_cut = vm - EPS2, hi_cut = vm + EPS2;

  for (int i = tid; i < L; i += 256){
    const float f = __uint_as_float(listU[i]);
    if (f > hi_cut){
      int p = atomicAdd(&dcnt, 1);
      selIdx[base + p] = listI[i];
      selVal[base + p] = f;
    } else if (f >= lo_cut){
      int p = atomicAdd(&acnt, 1);
      if (p < 64){ ambU[p] = listU[i]; ambI[p] = listI[i]; }
    }
  }
  __syncthreads();
  const int D = dcnt;
  const int A = min(acnt, 64);
  int need = m - D;
  if (need < 0) need = 0;
  if (need > A) need = A;

  if (need > 0){
    float* xcs = (float*)hist;
    for (int j = tid; j < DIM; j += 256)
      xcs[j] = x[(size_t)row * DIM + j] - bdec[j];
    __syncthreads();
    const int lane = tid & 63, wv = tid >> 6;
    for (int c = 0; c < A; ++c){
      const float* wrow = Wenc + (size_t)ambI[c] * DIM;
      double sd = 0.0;
      for (int j = tid; j < DIM; j += 256)
        sd += (double)xcs[j] * (double)wrow[j];
      #pragma unroll
      for (int off = 32; off; off >>= 1) sd += __shfl_xor(sd, off);
      if (lane == 0) wred[wv] = sd;
      __syncthreads();
      if (tid == 0) ambE[c] = wred[0] + wred[1] + wred[2] + wred[3];
      __syncthreads();
    }
    if (tid == 0){
      for (int e = 0; e < need; ++e){
        int best = -1;
        for (int c = 0; c < A; ++c){
          if (ambI[c] < 0) continue;
          if (best < 0 || ambE[c] > ambE[best] ||
              (ambE[c] == ambE[best] && ambI[c] < ambI[best])) best = c;
        }
        selIdx[base + D + e] = ambI[best];
        selVal[base + D + e] = __uint_as_float(ambU[best]);
        ambI[best] = -1;
      }
    }
  }
  if (tid == 0) scount[row] = D + need;
}

// W_dec [DIM][FEAT] fp32 -> WdT16 [FEAT][DIM] fp16
__global__ __launch_bounds__(256)
void transpose_dec(const float* __restrict__ Wd, _Float16* __restrict__ WdT16)
{
  __shared__ float t[64][65];
  const int f0 = blockIdx.x << 6, d0 = blockIdx.y << 6;
  const int tx = threadIdx.x & 15, ty = threadIdx.x >> 4;
  #pragma unroll
  for (int r = 0; r < 4; ++r){
    const int d = ty + (r << 4);
    const float4 v = *(const float4*)(Wd + (size_t)(d0 + d) * FEAT + f0 + (tx << 2));
    t[d][(tx << 2) + 0] = v.x;
    t[d][(tx << 2) + 1] = v.y;
    t[d][(tx << 2) + 2] = v.z;
    t[d][(tx << 2) + 3] = v.w;
  }
  __syncthreads();
  #pragma unroll
  for (int r = 0; r < 4; ++r){
    const int f = ty + (r << 4);
    ushort4 o;
    o.x = __builtin_bit_cast(unsigned short, (_Float16)t[(tx << 2) + 0][f]);
    o.y = __builtin_bit_cast(unsigned short, (_Float16)t[(tx << 2) + 1][f]);
    o.z = __builtin_bit_cast(unsigned short, (_Float16)t[(tx << 2) + 2][f]);
    o.w = __builtin_bit_cast(unsigned short, (_Float16)t[(tx << 2) + 3][f]);
    *(ushort4*)(WdT16 + (size_t)(f0 + f) * DIM + d0 + (tx << 2)) = o;
  }
}

__global__ __launch_bounds__(256)
void decode_k(const _Float16* __restrict__ WdT16, const int* __restrict__ selIdx,
              const float* __restrict__ selVal, const int* __restrict__ scount,
              const float* __restrict__ bdec, float* __restrict__ out)
{
  __shared__ int   sI[128];
  __shared__ float sV[128];
  const int row = blockIdx.x, tid = threadIdx.x;
  const int m = scount[row];
  if (tid < m){
    sI[tid] = selIdx[(row << 7) + tid];
    sV[tid] = selVal[(row << 7) + tid];
  }
  __syncthreads();
  const int d = tid << 3;
  float a[8];
  {
    const float4 b0 = *(const float4*)(bdec + d);
    const float4 b1 = *(const float4*)(bdec + d + 4);
    a[0] = b0.x; a[1] = b0.y; a[2] = b0.z; a[3] = b0.w;
    a[4] = b1.x; a[5] = b1.y; a[6] = b1.z; a[7] = b1.w;
  }
  for (int i = 0; i < m; ++i){
    const float v = sV[i];
    const h8v w = *(const h8v*)(WdT16 + (size_t)sI[i] * DIM + d);
    #pragma unroll
    for (int j = 0; j < 8; ++j)
      a[j] = fmaf(v, (float)w[j], a[j]);
  }
  float4 o0 = {a[0], a[1], a[2], a[3]};
  float4 o1 = {a[4], a[5], a[6], a[7]};
  *(float4*)(out + (size_t)row * DIM + d)     = o0;
  *(float4*)(out + (size_t)row * DIM + d + 4) = o1;
}

// ===========================================================================
extern "C" void kernel_launch(void* const* d_in, const int* in_sizes, int n_in,
                              void* d_out, int out_size, void* d_ws, size_t ws_size,
                              hipStream_t stream)
{
  const float* x    = (const float*)d_in[0];
  const float* Wenc = (const float*)d_in[1];
  const float* benc = (const float*)d_in[2];
  const float* Wk1  = (const float*)d_in[3];
  const float* bk1  = (const float*)d_in[4];
  const float* Wk2  = (const float*)d_in[5];
  const float* bk2  = (const float*)d_in[6];
  const float* Wdec = (const float*)d_in[7];
  const float* bdec = (const float*)d_in[8];
  const int*   kp   = (const int*)d_in[9];
  float* out = (float*)d_out;

  char* ws = (char*)d_ws;
  const size_t XS_BYTES   = (size_t)BATCH * DIM * 2;      // 16 MB per plane
  const size_t ACTS_BYTES = (size_t)BATCH * FEAT * 4;     // 256 MB
  const size_t WP_BYTES   = (size_t)FEAT * DIM * 2;       // 64 MB per plane

  unsigned short* xs0 = (unsigned short*)ws;
  unsigned short* xs1 = (unsigned short*)(ws + XS_BYTES);
  char* p = ws + 2 * XS_BYTES;
  float* acts = (float*)p;
  _Float16* WdT16 = (_Float16*)p;          // aliased after select
  p += ACTS_BYTES;
  unsigned short* wp0 = (unsigned short*)p;
  unsigned short* wp1 = (unsigned short*)(p + WP_BYTES);
  p += 2 * WP_BYTES;
  float* zpart  = (float*)p;               p += 4194304;
  int*   mrow   = (int*)p;                 p += 16384;
  int*   selIdx = (int*)p;                 p += 2097152;
  float* selVal = (float*)p;               p += 2097152;
  int*   scount = (int*)p;                 p += 16384;
  int*   rowList= (int*)p;                 p += MAXF * 4;
  int*   nflag  = (int*)p;                 p += 128;
  float* zexact = (float*)p;               p += (size_t)MAXF * 256 * 4;

  (void)ws_size; (void)in_sizes; (void)n_in; (void)out_size;

  splitX<<<dim3(BATCH * DIM / 1024), dim3(256), 0, stream>>>(x, bdec, xs0, xs1);
  splitW<<<dim3(FEAT * DIM / 1024), dim3(256), 0, stream>>>(Wk1, wp0, wp1);
  // approx kest (1-product fp16, fused w2 reduce)
  gemma<1><<<dim3(4096), dim3(256), 0, stream>>>(xs0, wp0, bk1, Wk2, nullptr, zpart);
  zinit<<<dim3(MAXF / 256), dim3(256), 0, stream>>>(rowList, nflag);
  zreduce_flag<<<dim3(BATCH / 4), dim3(256), 0, stream>>>(zpart, bk2, kp, mrow,
                                                          rowList, nflag);
  // exact recompute of flagged rows only
  gemmx<<<dim3(16 * 128), dim3(512), 0, stream>>>(xs0, xs1, wp0, wp1, bk1, Wk2,
                                                  rowList, nflag, zexact);
  zreduce2<<<dim3(MAXF / 4), dim3(256), 0, stream>>>(zexact, rowList, nflag,
                                                     bk2, kp, mrow);
  // approx acts GEMM (hi planes only)
  splitW1<<<dim3(FEAT * DIM / 1024), dim3(256), 0, stream>>>(Wenc, wp0);
  gemma<0><<<dim3(4096), dim3(256), 0, stream>>>(xs0, wp0, benc, nullptr, acts, nullptr);
  select_band<<<dim3(BATCH), dim3(256), 0, stream>>>(acts, x, bdec, Wenc, mrow,
                                                     selIdx, selVal, scount);
  transpose_dec<<<dim3(FEAT / 64, DIM / 64), dim3(256), 0, stream>>>(Wdec, WdT16);
  decode_k<<<dim3(BATCH), dim3(256), 0, stream>>>(WdT16, selIdx, selVal, scount, bdec, out);
}

// Round 11
// 1167.410 us; speedup vs baseline: 2.0343x; 1.0737x over previous
//
#include <hip/hip_runtime.h>
#include <hip/hip_bf16.h>
#include <cstdint>
#include <cstddef>

#define BATCH 4096
#define DIM   2048
#define FEAT  16384
#define MAXF  2048          // cap on flagged rows for exact kest recompute

typedef __attribute__((ext_vector_type(8))) short s8v;
typedef __attribute__((ext_vector_type(8))) _Float16 h8v;
typedef __attribute__((ext_vector_type(4))) float f4v;

__device__ __forceinline__ void split2(float v, unsigned short &h, unsigned short &l){
  _Float16 hf = (_Float16)v;
  _Float16 lf = (_Float16)((v - (float)hf) * 2048.0f);
  h = __builtin_bit_cast(unsigned short, hf);
  l = __builtin_bit_cast(unsigned short, lf);
}

__device__ __forceinline__ void gload16(const void* g, void* l){
  __builtin_amdgcn_global_load_lds(
      (const __attribute__((address_space(1))) void*)g,
      (__attribute__((address_space(3))) void*)l, 16, 0, 0);
}

// ===========================================================================
// split kernels
// ===========================================================================
__global__ __launch_bounds__(256)
void splitX(const float* __restrict__ x, const float* __restrict__ bdec,
            unsigned short* __restrict__ p0, unsigned short* __restrict__ p1)
{
  const size_t i = ((size_t)blockIdx.x * 256 + threadIdx.x) * 4;
  const int col = (int)(i & (DIM - 1));
  const float4 v = *(const float4*)(x + i);
  const float4 b = *(const float4*)(bdec + col);
  float e0 = v.x - b.x, e1 = v.y - b.y, e2 = v.z - b.z, e3 = v.w - b.w;
  ushort4 H, L;
  split2(e0, H.x, L.x); split2(e1, H.y, L.y);
  split2(e2, H.z, L.z); split2(e3, H.w, L.w);
  *(ushort4*)(p0 + i) = H; *(ushort4*)(p1 + i) = L;
}

__global__ __launch_bounds__(256)
void splitW(const float* __restrict__ w,
            unsigned short* __restrict__ p0, unsigned short* __restrict__ p1)
{
  const size_t i = ((size_t)blockIdx.x * 256 + threadIdx.x) * 4;
  const float4 v = *(const float4*)(w + i);
  ushort4 H, L;
  split2(v.x, H.x, L.x); split2(v.y, H.y, L.y);
  split2(v.z, H.z, L.z); split2(v.w, H.w, L.w);
  *(ushort4*)(p0 + i) = H; *(ushort4*)(p1 + i) = L;
}

// hi-plane only
__global__ __launch_bounds__(256)
void splitW1(const float* __restrict__ w, unsigned short* __restrict__ p0)
{
  const size_t i = ((size_t)blockIdx.x * 256 + threadIdx.x) * 4;
  const float4 v = *(const float4*)(w + i);
  ushort4 H;
  H.x = __builtin_bit_cast(unsigned short, (_Float16)v.x);
  H.y = __builtin_bit_cast(unsigned short, (_Float16)v.y);
  H.z = __builtin_bit_cast(unsigned short, (_Float16)v.z);
  H.w = __builtin_bit_cast(unsigned short, (_Float16)v.w);
  *(ushort4*)(p0 + i) = H;
}

// ===========================================================================
// Fused dual 1-product GEMM (hi planes, all gload16 staging, NO ds_writes):
//   waves 0-3: acts = relu(A*B1^T + benc)      (B1 = Wenc hi)
//   waves 4-7: zpart = w2-reduce(relu(A*B2^T + bk1))   (B2 = Wk1 hi)
// A staged once. 128x128 tiles, BK=32, dbuf, 48 KB LDS -> 3 blocks/CU.
// Per-output arithmetic identical to round-10 gemma (same MFMA order).
// ===========================================================================
__global__ __launch_bounds__(512, 3)
void gemmd(const unsigned short* __restrict__ Ah_, const unsigned short* __restrict__ B1h_,
           const unsigned short* __restrict__ B2h_,
           const float* __restrict__ benc, const float* __restrict__ bk1,
           const float* __restrict__ w2,
           float* __restrict__ acts, float* __restrict__ zpart)
{
  __shared__ unsigned short sAB[2][3][128][32];   // 48 KB: [buf][A|B1|B2]
  const int tid  = threadIdx.x;
  const int lane = tid & 63, wv = tid >> 6;       // wv 0..7

  const int bid = blockIdx.x;
  const int xcd = bid & 7;
  const int idx = bid >> 3;
  const int sq  = idx >> 6;
  const int s   = idx & 63;
  const int bx  = (xcd << 4) | ((sq & 1) << 3) | (s & 7);
  const int by  = ((sq >> 1) << 3) | (s >> 3);
  const int row0 = by << 7, col0 = bx << 7;

  const int role = wv >> 2;                 // 0: acts, 1: kest
  const int wloc = wv & 3;
  const int wr = (wloc & 1) << 6, wc = (wloc >> 1) << 6;

  f4v acc[4][4];
  #pragma unroll
  for (int i = 0; i < 4; ++i)
    #pragma unroll
    for (int j = 0; j < 4; ++j)
      acc[i][j] = (f4v){0.f, 0.f, 0.f, 0.f};

  // staging: 24 chunks of 1 KB (8 A + 8 B1 + 8 B2); 3 per wave
  const unsigned short* gsrc[3];
  unsigned ldsoff[3];
  #pragma unroll
  for (int j = 0; j < 3; ++j){
    const int q = wv * 3 + j;          // 0..23
    const int mat = q >> 3;            // 0=A, 1=B1, 2=B2
    const int chunk = q & 7;
    const int r  = (chunk << 4) + (lane >> 2);      // 0..127
    const int gl = (lane & 3) ^ ((r >> 1) & 3);
    const int rowg = ((mat == 0) ? row0 : col0) + r;
    const unsigned short* P = (mat == 0) ? Ah_ : ((mat == 1) ? B1h_ : B2h_);
    gsrc[j]  = P + (size_t)rowg * DIM + (gl << 3);
    ldsoff[j] = (unsigned)(mat * 8192 + chunk * 1024);
  }

  const int fr16 = lane & 15;
  const int kg   = lane >> 4;
  const int bmat = 1 + role;
  int ra[4], rb[4];
  #pragma unroll
  for (int f = 0; f < 4; ++f){ ra[f] = wr + (f << 4) + fr16; rb[f] = wc + (f << 4) + fr16; }

  #define LDFRAGD(bf, mat, r) \
    (*(const h8v*)((const char*)sAB + (bf) * 24576 + (mat) * 8192 + (r) * 64 + (((kg ^ (((r) >> 1) & 3)) << 4))))
  #define STAGED(bf, ko)                                                      \
    {                                                                         \
      _Pragma("unroll")                                                       \
      for (int j = 0; j < 3; ++j)                                             \
        gload16(gsrc[j] + (ko), (char*)sAB + (bf) * 24576 + ldsoff[j]);       \
    }

  int cur = 0;
  STAGED(0, 0);
  __syncthreads();

  for (int kt = 0; kt < DIM / 32; ++kt){
    if (kt < DIM / 32 - 1) STAGED(cur ^ 1, (kt + 1) << 5);

    h8v Ahf[4], Bhf[4];
    #pragma unroll
    for (int f = 0; f < 4; ++f) Ahf[f] = LDFRAGD(cur, 0, ra[f]);
    #pragma unroll
    for (int f = 0; f < 4; ++f) Bhf[f] = LDFRAGD(cur, bmat, rb[f]);
    #pragma unroll
    for (int fi = 0; fi < 4; ++fi)
      #pragma unroll
      for (int fj = 0; fj < 4; ++fj)
        acc[fi][fj] = __builtin_amdgcn_mfma_f32_16x16x32_f16(Bhf[fj], Ahf[fi], acc[fi][fj], 0, 0, 0);

    __syncthreads();
    cur ^= 1;
  }
  #undef LDFRAGD
  #undef STAGED

  const int mloc = lane & 15;
  const int nq   = (lane >> 4) << 2;
  if (role == 0){
    #pragma unroll
    for (int fi = 0; fi < 4; ++fi){
      const int grow = row0 + wr + (fi << 4) + mloc;
      #pragma unroll
      for (int fj = 0; fj < 4; ++fj){
        const int gcol = col0 + wc + (fj << 4) + nq;
        const float4 be = *(const float4*)(benc + gcol);
        f4v v;
        v[0] = fmaxf(acc[fi][fj][0] + be.x, 0.f);
        v[1] = fmaxf(acc[fi][fj][1] + be.y, 0.f);
        v[2] = fmaxf(acc[fi][fj][2] + be.z, 0.f);
        v[3] = fmaxf(acc[fi][fj][3] + be.w, 0.f);
        __builtin_nontemporal_store(v, (f4v*)(acts + (size_t)grow * FEAT + gcol));
      }
    }
  } else {
    #pragma unroll
    for (int fi = 0; fi < 4; ++fi){
      float ssum = 0.f;
      #pragma unroll
      for (int fj = 0; fj < 4; ++fj){
        const int gcol = col0 + wc + (fj << 4) + nq;
        const float4 be = *(const float4*)(bk1 + gcol);
        const float4 wk = *(const float4*)(w2 + gcol);
        float h0 = fmaxf(acc[fi][fj][0] + be.x, 0.f);
        float h1 = fmaxf(acc[fi][fj][1] + be.y, 0.f);
        float h2 = fmaxf(acc[fi][fj][2] + be.z, 0.f);
        float h3 = fmaxf(acc[fi][fj][3] + be.w, 0.f);
        ssum = fmaf(h0, wk.x, ssum);
        ssum = fmaf(h1, wk.y, ssum);
        ssum = fmaf(h2, wk.z, ssum);
        ssum = fmaf(h3, wk.w, ssum);
      }
      ssum += __shfl_xor(ssum, 16);
      ssum += __shfl_xor(ssum, 32);
      if (lane < 16){
        const int grow = row0 + wr + (fi << 4) + lane;
        zpart[(size_t)grow * 256 + (bx << 1) + (wc >> 6)] = ssum;
      }
    }
  }
}

// ===========================================================================
// Exact kest GEMM on GATHERED flagged rows (3-product fp32-equivalent).
// ===========================================================================
__global__ __launch_bounds__(512, 4)
void gemmx(const unsigned short* __restrict__ Ah_, const unsigned short* __restrict__ Al_,
           const unsigned short* __restrict__ Bh_, const unsigned short* __restrict__ Bl_,
           const float* __restrict__ bias, const float* __restrict__ w2,
           const int* __restrict__ rowList, const int* __restrict__ nflagp,
           float* __restrict__ zexact)
{
  const int panel = blockIdx.x >> 7;          // 0..15
  const int bx    = blockIdx.x & 127;
  const int row0p = panel << 7;
  if (row0p >= *nflagp) return;
  const int col0 = bx << 7;

  __shared__ unsigned short sAB[2][2][128][64];
  const int tid  = threadIdx.x;
  const int lane = tid & 63, wv = tid >> 6;
  const int wr = (wv & 3) << 5, wc = (wv >> 2) << 6;

  f4v acc[2][4], acc2[2][4];
  #pragma unroll
  for (int i = 0; i < 2; ++i)
    #pragma unroll
    for (int j = 0; j < 4; ++j){
      acc[i][j]  = (f4v){0.f, 0.f, 0.f, 0.f};
      acc2[i][j] = (f4v){0.f, 0.f, 0.f, 0.f};
    }

  const unsigned short* gsrc[4];
  unsigned ldsoff[4];
  #pragma unroll
  for (int j = 0; j < 4; ++j){
    const int q = (wv << 2) + j;
    const int mat = q >> 4;
    const int chunk = q & 15;
    const int r  = (chunk << 3) + (lane >> 3);
    const int gl = (lane & 7) ^ (r & 7);
    const int co = (gl & 3) << 3;
    const unsigned short* hi = (mat == 0) ? Ah_ : Bh_;
    const unsigned short* lo = (mat == 0) ? Al_ : Bl_;
    const int rowg = (mat == 0) ? rowList[row0p + r] : (col0 + r);
    gsrc[j]  = ((gl < 4) ? hi : lo) + (size_t)rowg * DIM + co;
    ldsoff[j] = (unsigned)(mat * 16384 + chunk * 1024);
  }

  const int fr16 = lane & 15;
  const int kg   = lane >> 4;
  int ra[2], rb[4];
  #pragma unroll
  for (int f = 0; f < 2; ++f) ra[f] = wr + (f << 4) + fr16;
  #pragma unroll
  for (int f = 0; f < 4; ++f) rb[f] = wc + (f << 4) + fr16;

  #define LDFRAG(bf, mat, r, hb) \
    (*(const h8v*)((const char*)sAB + (bf) * 32768 + (mat) * 16384 + (r) * 128 + (((((hb) + kg) ^ ((r) & 7)) << 4))))
  #define STAGE(bf, ko)                                                       \
    {                                                                         \
      _Pragma("unroll")                                                       \
      for (int j = 0; j < 4; ++j)                                             \
        gload16(gsrc[j] + (ko), (char*)sAB + (bf) * 32768 + ldsoff[j]);       \
    }

  int cur = 0;
  STAGE(0, 0);
  __syncthreads();

  for (int kt = 0; kt < DIM / 32; ++kt){
    if (kt < DIM / 32 - 1) STAGE(cur ^ 1, (kt + 1) << 5);

    h8v Ahf[2], Bhf[4], Xl[4];
    #pragma unroll
    for (int f = 0; f < 2; ++f) Ahf[f] = LDFRAG(cur, 0, ra[f], 0);
    #pragma unroll
    for (int f = 0; f < 4; ++f) Bhf[f] = LDFRAG(cur, 1, rb[f], 0);
    #pragma unroll
    for (int fi = 0; fi < 2; ++fi)
      #pragma unroll
      for (int fj = 0; fj < 4; ++fj)
        acc[fi][fj] = __builtin_amdgcn_mfma_f32_16x16x32_f16(Bhf[fj], Ahf[fi], acc[fi][fj], 0, 0, 0);
    #pragma unroll
    for (int f = 0; f < 2; ++f) Xl[f] = LDFRAG(cur, 0, ra[f], 4);
    #pragma unroll
    for (int fi = 0; fi < 2; ++fi)
      #pragma unroll
      for (int fj = 0; fj < 4; ++fj)
        acc2[fi][fj] = __builtin_amdgcn_mfma_f32_16x16x32_f16(Bhf[fj], Xl[fi], acc2[fi][fj], 0, 0, 0);
    #pragma unroll
    for (int f = 0; f < 4; ++f) Xl[f] = LDFRAG(cur, 1, rb[f], 4);
    #pragma unroll
    for (int fi = 0; fi < 2; ++fi)
      #pragma unroll
      for (int fj = 0; fj < 4; ++fj)
        acc2[fi][fj] = __builtin_amdgcn_mfma_f32_16x16x32_f16(Xl[fj], Ahf[fi], acc2[fi][fj], 0, 0, 0);

    __syncthreads();
    cur ^= 1;
  }
  #undef LDFRAG
  #undef STAGE

  const float LSC = 1.0f / 2048.0f;
  const int nq = (lane >> 4) << 2;
  #pragma unroll
  for (int fi = 0; fi < 2; ++fi){
    float ssum = 0.f;
    #pragma unroll
    for (int fj = 0; fj < 4; ++fj){
      const int gcol = col0 + wc + (fj << 4) + nq;
      const float4 be = *(const float4*)(bias + gcol);
      const float4 wk = *(const float4*)(w2 + gcol);
      float h0 = fmaxf(acc[fi][fj][0] + LSC * acc2[fi][fj][0] + be.x, 0.f);
      float h1 = fmaxf(acc[fi][fj][1] + LSC * acc2[fi][fj][1] + be.y, 0.f);
      float h2 = fmaxf(acc[fi][fj][2] + LSC * acc2[fi][fj][2] + be.z, 0.f);
      float h3 = fmaxf(acc[fi][fj][3] + LSC * acc2[fi][fj][3] + be.w, 0.f);
      ssum = fmaf(h0, wk.x, ssum);
      ssum = fmaf(h1, wk.y, ssum);
      ssum = fmaf(h2, wk.z, ssum);
      ssum = fmaf(h3, wk.w, ssum);
    }
    ssum += __shfl_xor(ssum, 16);
    ssum += __shfl_xor(ssum, 32);
    if (lane < 16){
      const int pos = row0p + wr + (fi << 4) + lane;
      zexact[(size_t)pos * 256 + (bx << 1) + (wc >> 6)] = ssum;
    }
  }
}

// ===========================================================================
// tail kernels
// ===========================================================================
__global__ __launch_bounds__(256)
void zinit(int* __restrict__ rowList, int* __restrict__ nflag)
{
  const int i = blockIdx.x * 256 + threadIdx.x;
  if (i < MAXF) rowList[i] = 0;
  if (i == 0) *nflag = 0;
}

__global__ __launch_bounds__(256)
void zreduce_flag(const float* __restrict__ zpart, const float* __restrict__ bk2,
                  const int* __restrict__ kp, int* __restrict__ mrow,
                  int* __restrict__ rowList, int* __restrict__ nflag)
{
  const int row  = blockIdx.x * 4 + (threadIdx.x >> 6);
  const int lane = threadIdx.x & 63;
  const float* zp = zpart + (size_t)row * 256;
  float s = zp[lane] + zp[lane + 64] + zp[lane + 128] + zp[lane + 192];
  s += __shfl_xor(s, 1);
  s += __shfl_xor(s, 2);
  s += __shfl_xor(s, 4);
  s += __shfl_xor(s, 8);
  s += __shfl_xor(s, 16);
  s += __shfl_xor(s, 32);
  if (lane == 0){
    float z = s + bk2[0];
    float kest = 2.f * (float)(*kp) * (1.f / (1.f + expf(-z)));
    int m = (int)ceilf(kest);
    m = min(max(m, 0), 128);
    mrow[row] = m;
    const float frac = kest - floorf(kest);
    const float dmin = fminf(frac, 1.f - frac);
    if (dmin < 0.1f){
      int p = atomicAdd(nflag, 1);
      if (p < MAXF) rowList[p] = row;
    }
  }
}

__global__ __launch_bounds__(256)
void zreduce2(const float* __restrict__ zexact, const int* __restrict__ rowList,
              const int* __restrict__ nflagp, const float* __restrict__ bk2,
              const int* __restrict__ kp, int* __restrict__ mrow)
{
  const int pos  = blockIdx.x * 4 + (threadIdx.x >> 6);
  const int lane = threadIdx.x & 63;
  const int nf = min(*nflagp, MAXF);
  if (pos >= nf) return;
  const float* zp = zexact + (size_t)pos * 256;
  float s = zp[lane] + zp[lane + 64] + zp[lane + 128] + zp[lane + 192];
  s += __shfl_xor(s, 1);
  s += __shfl_xor(s, 2);
  s += __shfl_xor(s, 4);
  s += __shfl_xor(s, 8);
  s += __shfl_xor(s, 16);
  s += __shfl_xor(s, 32);
  if (lane == 0){
    float z = s + bk2[0];
    float kest = 2.f * (float)(*kp) * (1.f / (1.f + expf(-z)));
    int m = (int)ceilf(kest);
    m = min(max(m, 0), 128);
    mrow[rowList[pos]] = m;
  }
}

__device__ __forceinline__ void radix_find(int* hist, int nbins, int need, int tid,
                                           int* out3, int* blksum)
{
  const int per  = nbins >> 8;
  const int base = tid * per;
  int bs = 0;
  for (int j = 0; j < per; ++j) bs += hist[base + j];
  blksum[tid] = bs;
  __syncthreads();
  if (tid == 0){
    int a2 = 0;
    for (int t = 255; t >= 0; --t){ int v = blksum[t]; blksum[t] = a2; a2 += v; }
  }
  __syncthreads();
  int ch = blksum[tid];
  for (int j = per - 1; j >= 0; --j){
    const int b = base + j;
    const int c = hist[b];
    if (ch < need && need <= ch + c){ out3[0] = b; out3[1] = need - ch; out3[2] = ch; }
    ch += c;
  }
  __syncthreads();
}

// Band select on approx acts (proven round-9/10)
__global__ __launch_bounds__(256)
void select_band(const float* __restrict__ acts, const float* __restrict__ x,
                 const float* __restrict__ bdec, const float* __restrict__ Wenc,
                 const int* __restrict__ mrow, int* __restrict__ selIdx,
                 float* __restrict__ selVal, int* __restrict__ scount)
{
  __shared__ int hist[2048];        // later reused as float xcs[2048]
  __shared__ int blksum[256];
  __shared__ int out3[4];
  __shared__ unsigned listU[2048];
  __shared__ int listI[2048];
  __shared__ int lcnt, dcnt, acnt;
  __shared__ unsigned ambU[64];
  __shared__ int ambI[64];
  __shared__ double ambE[64];
  __shared__ double wred[4];

  const int row = blockIdx.x, tid = threadIdx.x;
  const int m = mrow[row];
  const float* rp = acts + (size_t)row * FEAT;
  const int base = row << 7;

  for (int i = tid; i < 2048; i += 256) hist[i] = 0;
  __syncthreads();
  for (int it = 0; it < 16; ++it){
    const int i4 = (it << 8) + tid;
    const uint4 u4 = *(const uint4*)(rp + ((size_t)i4 << 2));
    if (u4.x) atomicAdd(&hist[u4.x >> 21], 1);
    if (u4.y) atomicAdd(&hist[u4.y >> 21], 1);
    if (u4.z) atomicAdd(&hist[u4.z >> 21], 1);
    if (u4.w) atomicAdd(&hist[u4.w >> 21], 1);
  }
  __syncthreads();
  radix_find(hist, 2048, m, tid, out3, blksum);
  const int bin1 = out3[0];
  const int rem1 = out3[1];
  const int bin1m1 = (bin1 > 1) ? bin1 - 1 : 1;

  if (tid == 0){ lcnt = 0; dcnt = 0; acnt = 0; }
  __syncthreads();
  for (int it = 0; it < 16; ++it){
    const int i4 = (it << 8) + tid;
    const uint4 u4 = *(const uint4*)(rp + ((size_t)i4 << 2));
    const int ib = i4 << 2;
    if (u4.x && (int)(u4.x >> 21) >= bin1m1){ int p = atomicAdd(&lcnt, 1); if (p < 2048){ listU[p] = u4.x; listI[p] = ib;     } }
    if (u4.y && (int)(u4.y >> 21) >= bin1m1){ int p = atomicAdd(&lcnt, 1); if (p < 2048){ listU[p] = u4.y; listI[p] = ib + 1; } }
    if (u4.z && (int)(u4.z >> 21) >= bin1m1){ int p = atomicAdd(&lcnt, 1); if (p < 2048){ listU[p] = u4.z; listI[p] = ib + 2; } }
    if (u4.w && (int)(u4.w >> 21) >= bin1m1){ int p = atomicAdd(&lcnt, 1); if (p < 2048){ listU[p] = u4.w; listI[p] = ib + 3; } }
  }
  __syncthreads();
  const int L = min(lcnt, 2048);

  for (int i = tid; i < 2048; i += 256) hist[i] = 0;
  __syncthreads();
  for (int i = tid; i < L; i += 256){
    unsigned u = listU[i];
    if ((int)(u >> 21) == bin1) atomicAdd(&hist[(u >> 10) & 0x7FF], 1);
  }
  __syncthreads();
  radix_find(hist, 2048, rem1, tid, out3, blksum);
  const int bin2 = out3[0];
  const int rem2 = out3[1];

  const unsigned topbits = (((unsigned)bin1 << 11) | (unsigned)bin2);
  for (int i = tid; i < 1024; i += 256) hist[i] = 0;
  __syncthreads();
  for (int i = tid; i < L; i += 256){
    unsigned u = listU[i];
    if ((u >> 10) == topbits) atomicAdd(&hist[u & 0x3FF], 1);
  }
  __syncthreads();
  radix_find(hist, 1024, rem2, tid, out3, blksum);
  const int bin3 = out3[0];

  const unsigned tbits = ((unsigned)bin1 << 21) | ((unsigned)bin2 << 10) | (unsigned)bin3;
  const float vm = __uint_as_float(tbits);
  const float EPS2 = 0.01f;
  const float lo_cut = vm - EPS2, hi_cut = vm + EPS2;

  for (int i = tid; i < L; i += 256){
    const float f = __uint_as_float(listU[i]);
    if (f > hi_cut){
      int p = atomicAdd(&dcnt, 1);
      selIdx[base + p] = listI[i];
      selVal[base + p] = f;
    } else if (f >= lo_cut){
      int p = atomicAdd(&acnt, 1);
      if (p < 64){ ambU[p] = listU[i]; ambI[p] = listI[i]; }
    }
  }
  __syncthreads();
  const int D = dcnt;
  const int A = min(acnt, 64);
  int need = m - D;
  if (need < 0) need = 0;
  if (need > A) need = A;

  if (need > 0){
    float* xcs = (float*)hist;
    for (int j = tid; j < DIM; j += 256)
      xcs[j] = x[(size_t)row * DIM + j] - bdec[j];
    __syncthreads();
    const int lane = tid & 63, wv = tid >> 6;
    for (int c = 0; c < A; ++c){
      const float* wrow = Wenc + (size_t)ambI[c] * DIM;
      double sd = 0.0;
      for (int j = tid; j < DIM; j += 256)
        sd += (double)xcs[j] * (double)wrow[j];
      #pragma unroll
      for (int off = 32; off; off >>= 1) sd += __shfl_xor(sd, off);
      if (lane == 0) wred[wv] = sd;
      __syncthreads();
      if (tid == 0) ambE[c] = wred[0] + wred[1] + wred[2] + wred[3];
      __syncthreads();
    }
    if (tid == 0){
      for (int e = 0; e < need; ++e){
        int best = -1;
        for (int c = 0; c < A; ++c){
          if (ambI[c] < 0) continue;
          if (best < 0 || ambE[c] > ambE[best] ||
              (ambE[c] == ambE[best] && ambI[c] < ambI[best])) best = c;
        }
        selIdx[base + D + e] = ambI[best];
        selVal[base + D + e] = __uint_as_float(ambU[best]);
        ambI[best] = -1;
      }
    }
  }
  if (tid == 0) scount[row] = D + need;
}

// W_dec [DIM][FEAT] fp32 -> WdT16 [FEAT][DIM] fp16
__global__ __launch_bounds__(256)
void transpose_dec(const float* __restrict__ Wd, _Float16* __restrict__ WdT16)
{
  __shared__ float t[64][65];
  const int f0 = blockIdx.x << 6, d0 = blockIdx.y << 6;
  const int tx = threadIdx.x & 15, ty = threadIdx.x >> 4;
  #pragma unroll
  for (int r = 0; r < 4; ++r){
    const int d = ty + (r << 4);
    const float4 v = *(const float4*)(Wd + (size_t)(d0 + d) * FEAT + f0 + (tx << 2));
    t[d][(tx << 2) + 0] = v.x;
    t[d][(tx << 2) + 1] = v.y;
    t[d][(tx << 2) + 2] = v.z;
    t[d][(tx << 2) + 3] = v.w;
  }
  __syncthreads();
  #pragma unroll
  for (int r = 0; r < 4; ++r){
    const int f = ty + (r << 4);
    ushort4 o;
    o.x = __builtin_bit_cast(unsigned short, (_Float16)t[(tx << 2) + 0][f]);
    o.y = __builtin_bit_cast(unsigned short, (_Float16)t[(tx << 2) + 1][f]);
    o.z = __builtin_bit_cast(unsigned short, (_Float16)t[(tx << 2) + 2][f]);
    o.w = __builtin_bit_cast(unsigned short, (_Float16)t[(tx << 2) + 3][f]);
    *(ushort4*)(WdT16 + (size_t)(f0 + f) * DIM + d0 + (tx << 2)) = o;
  }
}

__global__ __launch_bounds__(256)
void decode_k(const _Float16* __restrict__ WdT16, const int* __restrict__ selIdx,
              const float* __restrict__ selVal, const int* __restrict__ scount,
              const float* __restrict__ bdec, float* __restrict__ out)
{
  __shared__ int   sI[128];
  __shared__ float sV[128];
  const int row = blockIdx.x, tid = threadIdx.x;
  const int m = scount[row];
  if (tid < m){
    sI[tid] = selIdx[(row << 7) + tid];
    sV[tid] = selVal[(row << 7) + tid];
  }
  __syncthreads();
  const int d = tid << 3;
  float a[8];
  {
    const float4 b0 = *(const float4*)(bdec + d);
    const float4 b1 = *(const float4*)(bdec + d + 4);
    a[0] = b0.x; a[1] = b0.y; a[2] = b0.z; a[3] = b0.w;
    a[4] = b1.x; a[5] = b1.y; a[6] = b1.z; a[7] = b1.w;
  }
  for (int i = 0; i < m; ++i){
    const float v = sV[i];
    const h8v w = *(const h8v*)(WdT16 + (size_t)sI[i] * DIM + d);
    #pragma unroll
    for (int j = 0; j < 8; ++j)
      a[j] = fmaf(v, (float)w[j], a[j]);
  }
  float4 o0 = {a[0], a[1], a[2], a[3]};
  float4 o1 = {a[4], a[5], a[6], a[7]};
  *(float4*)(out + (size_t)row * DIM + d)     = o0;
  *(float4*)(out + (size_t)row * DIM + d + 4) = o1;
}

// ===========================================================================
extern "C" void kernel_launch(void* const* d_in, const int* in_sizes, int n_in,
                              void* d_out, int out_size, void* d_ws, size_t ws_size,
                              hipStream_t stream)
{
  const float* x    = (const float*)d_in[0];
  const float* Wenc = (const float*)d_in[1];
  const float* benc = (const float*)d_in[2];
  const float* Wk1  = (const float*)d_in[3];
  const float* bk1  = (const float*)d_in[4];
  const float* Wk2  = (const float*)d_in[5];
  const float* bk2  = (const float*)d_in[6];
  const float* Wdec = (const float*)d_in[7];
  const float* bdec = (const float*)d_in[8];
  const int*   kp   = (const int*)d_in[9];
  float* out = (float*)d_out;

  char* ws = (char*)d_ws;
  const size_t XS_BYTES   = (size_t)BATCH * DIM * 2;      // 16 MB per plane
  const size_t ACTS_BYTES = (size_t)BATCH * FEAT * 4;     // 256 MB
  const size_t WP_BYTES   = (size_t)FEAT * DIM * 2;       // 64 MB per plane

  unsigned short* xs0 = (unsigned short*)ws;
  unsigned short* xs1 = (unsigned short*)(ws + XS_BYTES);
  char* p = ws + 2 * XS_BYTES;
  float* acts = (float*)p;
  _Float16* WdT16 = (_Float16*)p;          // aliased after select
  p += ACTS_BYTES;
  unsigned short* wk0 = (unsigned short*)p;     // Wk1 hi
  unsigned short* wk1 = (unsigned short*)(p + WP_BYTES);      // Wk1 lo
  unsigned short* we0 = (unsigned short*)(p + 2 * WP_BYTES);  // Wenc hi
  p += 3 * WP_BYTES;
  float* zpart  = (float*)p;               p += 4194304;
  int*   mrow   = (int*)p;                 p += 16384;
  int*   selIdx = (int*)p;                 p += 2097152;
  float* selVal = (float*)p;               p += 2097152;
  int*   scount = (int*)p;                 p += 16384;
  int*   rowList= (int*)p;                 p += MAXF * 4;
  int*   nflag  = (int*)p;                 p += 128;
  float* zexact = (float*)p;               p += (size_t)MAXF * 256 * 4;

  (void)ws_size; (void)in_sizes; (void)n_in; (void)out_size;

  splitX<<<dim3(BATCH * DIM / 1024), dim3(256), 0, stream>>>(x, bdec, xs0, xs1);
  splitW<<<dim3(FEAT * DIM / 1024), dim3(256), 0, stream>>>(Wk1, wk0, wk1);
  splitW1<<<dim3(FEAT * DIM / 1024), dim3(256), 0, stream>>>(Wenc, we0);
  // fused dual GEMM: acts (approx) + kest zpart (approx)
  gemmd<<<dim3(4096), dim3(512), 0, stream>>>(xs0, we0, wk0, benc, bk1, Wk2,
                                              acts, zpart);
  zinit<<<dim3(MAXF / 256), dim3(256), 0, stream>>>(rowList, nflag);
  zreduce_flag<<<dim3(BATCH / 4), dim3(256), 0, stream>>>(zpart, bk2, kp, mrow,
                                                          rowList, nflag);
  // exact recompute of flagged rows only
  gemmx<<<dim3(16 * 128), dim3(512), 0, stream>>>(xs0, xs1, wk0, wk1, bk1, Wk2,
                                                  rowList, nflag, zexact);
  zreduce2<<<dim3(MAXF / 4), dim3(256), 0, stream>>>(zexact, rowList, nflag,
                                                     bk2, kp, mrow);
  select_band<<<dim3(BATCH), dim3(256), 0, stream>>>(acts, x, bdec, Wenc, mrow,
                                                     selIdx, selVal, scount);
  transpose_dec<<<dim3(FEAT / 64, DIM / 64), dim3(256), 0, stream>>>(Wdec, WdT16);
  decode_k<<<dim3(BATCH), dim3(256), 0, stream>>>(WdT16, selIdx, selVal, scount, bdec, out);
}

// Round 13
// 1126.771 us; speedup vs baseline: 2.1076x; 1.0361x over previous
//
#include <hip/hip_runtime.h>
#include <hip/hip_bf16.h>
#include <cstdint>
#include <cstddef>

#define BATCH 4096
#define DIM   2048
#define FEAT  16384
#define MAXF  2048          // cap on flagged rows for exact kest recompute

typedef __attribute__((ext_vector_type(8))) _Float16 h8v;
typedef __attribute__((ext_vector_type(4))) float f4v;
typedef __attribute__((ext_vector_type(4))) unsigned short us4v;

__device__ __forceinline__ void split2(float v, unsigned short &h, unsigned short &l){
  _Float16 hf = (_Float16)v;
  _Float16 lf = (_Float16)((v - (float)hf) * 2048.0f);
  h = __builtin_bit_cast(unsigned short, hf);
  l = __builtin_bit_cast(unsigned short, lf);
}

__device__ __forceinline__ void gload16(const void* g, void* l){
  __builtin_amdgcn_global_load_lds(
      (const __attribute__((address_space(1))) void*)g,
      (__attribute__((address_space(3))) void*)l, 16, 0, 0);
}

// ===========================================================================
// split kernels
// ===========================================================================
__global__ __launch_bounds__(256)
void splitX(const float* __restrict__ x, const float* __restrict__ bdec,
            unsigned short* __restrict__ p0, unsigned short* __restrict__ p1)
{
  const size_t i = ((size_t)blockIdx.x * 256 + threadIdx.x) * 4;
  const int col = (int)(i & (DIM - 1));
  const float4 v = *(const float4*)(x + i);
  const float4 b = *(const float4*)(bdec + col);
  float e0 = v.x - b.x, e1 = v.y - b.y, e2 = v.z - b.z, e3 = v.w - b.w;
  ushort4 H, L;
  split2(e0, H.x, L.x); split2(e1, H.y, L.y);
  split2(e2, H.z, L.z); split2(e3, H.w, L.w);
  *(ushort4*)(p0 + i) = H; *(ushort4*)(p1 + i) = L;
}

__global__ __launch_bounds__(256)
void splitW(const float* __restrict__ w,
            unsigned short* __restrict__ p0, unsigned short* __restrict__ p1)
{
  const size_t i = ((size_t)blockIdx.x * 256 + threadIdx.x) * 4;
  const float4 v = *(const float4*)(w + i);
  ushort4 H, L;
  split2(v.x, H.x, L.x); split2(v.y, H.y, L.y);
  split2(v.z, H.z, L.z); split2(v.w, H.w, L.w);
  *(ushort4*)(p0 + i) = H; *(ushort4*)(p1 + i) = L;
}

// hi-plane only
__global__ __launch_bounds__(256)
void splitW1(const float* __restrict__ w, unsigned short* __restrict__ p0)
{
  const size_t i = ((size_t)blockIdx.x * 256 + threadIdx.x) * 4;
  const float4 v = *(const float4*)(w + i);
  ushort4 H;
  H.x = __builtin_bit_cast(unsigned short, (_Float16)v.x);
  H.y = __builtin_bit_cast(unsigned short, (_Float16)v.y);
  H.z = __builtin_bit_cast(unsigned short, (_Float16)v.z);
  H.w = __builtin_bit_cast(unsigned short, (_Float16)v.w);
  *(ushort4*)(p0 + i) = H;
}

// ===========================================================================
// Fused dual 1-product GEMM, dual-product-per-wave:
// 4 waves (256t); each wave: 12 ds_reads (A,B1,B2 frags) -> 32 MFMA
// (acc1 += B1*A, acc2 += B2*A). A-frags shared between both products.
//   acc1 -> acts16 = fp16(relu(A*B1^T + benc))
//   acc2 -> zpart  = w2-reduce(relu(A*B2^T + bk1))
// 48 KB LDS dbuf -> up to 3 blocks/CU. Same staging layout as r10/r11.
// ===========================================================================
__global__ __launch_bounds__(256, 2)
void gemmd(const unsigned short* __restrict__ Ah_, const unsigned short* __restrict__ B1h_,
           const unsigned short* __restrict__ B2h_,
           const float* __restrict__ benc, const float* __restrict__ bk1,
           const float* __restrict__ w2,
           _Float16* __restrict__ acts16, float* __restrict__ zpart)
{
  __shared__ unsigned short sAB[2][3][128][32];   // 48 KB: [buf][A|B1|B2]
  const int tid  = threadIdx.x;
  const int lane = tid & 63, wv = tid >> 6;       // wv 0..3

  const int bid = blockIdx.x;
  const int xcd = bid & 7;
  const int idx = bid >> 3;
  const int sq  = idx >> 6;
  const int s   = idx & 63;
  const int bx  = (xcd << 4) | ((sq & 1) << 3) | (s & 7);
  const int by  = ((sq >> 1) << 3) | (s >> 3);
  const int row0 = by << 7, col0 = bx << 7;

  const int wr = (wv & 1) << 6, wc = (wv >> 1) << 6;

  f4v acc1[4][4], acc2[4][4];
  #pragma unroll
  for (int i = 0; i < 4; ++i)
    #pragma unroll
    for (int j = 0; j < 4; ++j){
      acc1[i][j] = (f4v){0.f, 0.f, 0.f, 0.f};
      acc2[i][j] = (f4v){0.f, 0.f, 0.f, 0.f};
    }

  // staging: 24 chunks of 1 KB (8 A + 8 B1 + 8 B2); 6 per wave
  const unsigned short* gsrc[6];
  unsigned ldsoff[6];
  #pragma unroll
  for (int j = 0; j < 6; ++j){
    const int q = wv * 6 + j;          // 0..23
    const int mat = q >> 3;            // 0=A, 1=B1, 2=B2
    const int chunk = q & 7;
    const int r  = (chunk << 4) + (lane >> 2);      // 0..127
    const int gl = (lane & 3) ^ ((r >> 1) & 3);
    const int rowg = ((mat == 0) ? row0 : col0) + r;
    const unsigned short* P = (mat == 0) ? Ah_ : ((mat == 1) ? B1h_ : B2h_);
    gsrc[j]  = P + (size_t)rowg * DIM + (gl << 3);
    ldsoff[j] = (unsigned)(mat * 8192 + chunk * 1024);
  }

  const int fr16 = lane & 15;
  const int kg   = lane >> 4;
  int ra[4], rb[4];
  #pragma unroll
  for (int f = 0; f < 4; ++f){ ra[f] = wr + (f << 4) + fr16; rb[f] = wc + (f << 4) + fr16; }

  #define LDFRAGD(bf, mat, r) \
    (*(const h8v*)((const char*)sAB + (bf) * 24576 + (mat) * 8192 + (r) * 64 + (((kg ^ (((r) >> 1) & 3)) << 4))))
  #define STAGED(bf, ko)                                                      \
    {                                                                         \
      _Pragma("unroll")                                                       \
      for (int j = 0; j < 6; ++j)                                             \
        gload16(gsrc[j] + (ko), (char*)sAB + (bf) * 24576 + ldsoff[j]);       \
    }

  int cur = 0;
  STAGED(0, 0);
  __syncthreads();

  for (int kt = 0; kt < DIM / 32; ++kt){
    if (kt < DIM / 32 - 1) STAGED(cur ^ 1, (kt + 1) << 5);

    h8v Ahf[4], Bf[4];
    #pragma unroll
    for (int f = 0; f < 4; ++f) Ahf[f] = LDFRAGD(cur, 0, ra[f]);
    #pragma unroll
    for (int f = 0; f < 4; ++f) Bf[f] = LDFRAGD(cur, 1, rb[f]);
    #pragma unroll
    for (int fi = 0; fi < 4; ++fi)
      #pragma unroll
      for (int fj = 0; fj < 4; ++fj)
        acc1[fi][fj] = __builtin_amdgcn_mfma_f32_16x16x32_f16(Bf[fj], Ahf[fi], acc1[fi][fj], 0, 0, 0);
    #pragma unroll
    for (int f = 0; f < 4; ++f) Bf[f] = LDFRAGD(cur, 2, rb[f]);
    #pragma unroll
    for (int fi = 0; fi < 4; ++fi)
      #pragma unroll
      for (int fj = 0; fj < 4; ++fj)
        acc2[fi][fj] = __builtin_amdgcn_mfma_f32_16x16x32_f16(Bf[fj], Ahf[fi], acc2[fi][fj], 0, 0, 0);

    __syncthreads();
    cur ^= 1;
  }
  #undef LDFRAGD
  #undef STAGED

  const int mloc = lane & 15;
  const int nq   = (lane >> 4) << 2;
  // acts epilogue (fp16 store)
  #pragma unroll
  for (int fi = 0; fi < 4; ++fi){
    const int grow = row0 + wr + (fi << 4) + mloc;
    #pragma unroll
    for (int fj = 0; fj < 4; ++fj){
      const int gcol = col0 + wc + (fj << 4) + nq;
      const float4 be = *(const float4*)(benc + gcol);
      us4v h;
      h[0] = __builtin_bit_cast(unsigned short, (_Float16)fmaxf(acc1[fi][fj][0] + be.x, 0.f));
      h[1] = __builtin_bit_cast(unsigned short, (_Float16)fmaxf(acc1[fi][fj][1] + be.y, 0.f));
      h[2] = __builtin_bit_cast(unsigned short, (_Float16)fmaxf(acc1[fi][fj][2] + be.z, 0.f));
      h[3] = __builtin_bit_cast(unsigned short, (_Float16)fmaxf(acc1[fi][fj][3] + be.w, 0.f));
      __builtin_nontemporal_store(h, (us4v*)(acts16 + (size_t)grow * FEAT + gcol));
    }
  }
  // kest epilogue
  #pragma unroll
  for (int fi = 0; fi < 4; ++fi){
    float ssum = 0.f;
    #pragma unroll
    for (int fj = 0; fj < 4; ++fj){
      const int gcol = col0 + wc + (fj << 4) + nq;
      const float4 be = *(const float4*)(bk1 + gcol);
      const float4 wk = *(const float4*)(w2 + gcol);
      float h0 = fmaxf(acc2[fi][fj][0] + be.x, 0.f);
      float h1 = fmaxf(acc2[fi][fj][1] + be.y, 0.f);
      float h2 = fmaxf(acc2[fi][fj][2] + be.z, 0.f);
      float h3 = fmaxf(acc2[fi][fj][3] + be.w, 0.f);
      ssum = fmaf(h0, wk.x, ssum);
      ssum = fmaf(h1, wk.y, ssum);
      ssum = fmaf(h2, wk.z, ssum);
      ssum = fmaf(h3, wk.w, ssum);
    }
    ssum += __shfl_xor(ssum, 16);
    ssum += __shfl_xor(ssum, 32);
    if (lane < 16){
      const int grow = row0 + wr + (fi << 4) + lane;
      zpart[(size_t)grow * 256 + (bx << 1) + (wc >> 6)] = ssum;
    }
  }
}

// ===========================================================================
// Exact kest GEMM on GATHERED flagged rows (3-product fp32-equivalent).
// ===========================================================================
__global__ __launch_bounds__(512, 4)
void gemmx(const unsigned short* __restrict__ Ah_, const unsigned short* __restrict__ Al_,
           const unsigned short* __restrict__ Bh_, const unsigned short* __restrict__ Bl_,
           const float* __restrict__ bias, const float* __restrict__ w2,
           const int* __restrict__ rowList, const int* __restrict__ nflagp,
           float* __restrict__ zexact)
{
  const int panel = blockIdx.x >> 7;          // 0..15
  const int bx    = blockIdx.x & 127;
  const int row0p = panel << 7;
  if (row0p >= *nflagp) return;
  const int col0 = bx << 7;

  __shared__ unsigned short sAB[2][2][128][64];
  const int tid  = threadIdx.x;
  const int lane = tid & 63, wv = tid >> 6;
  const int wr = (wv & 3) << 5, wc = (wv >> 2) << 6;

  f4v acc[2][4], acc2[2][4];
  #pragma unroll
  for (int i = 0; i < 2; ++i)
    #pragma unroll
    for (int j = 0; j < 4; ++j){
      acc[i][j]  = (f4v){0.f, 0.f, 0.f, 0.f};
      acc2[i][j] = (f4v){0.f, 0.f, 0.f, 0.f};
    }

  const unsigned short* gsrc[4];
  unsigned ldsoff[4];
  #pragma unroll
  for (int j = 0; j < 4; ++j){
    const int q = (wv << 2) + j;
    const int mat = q >> 4;
    const int chunk = q & 15;
    const int r  = (chunk << 3) + (lane >> 3);
    const int gl = (lane & 7) ^ (r & 7);
    const int co = (gl & 3) << 3;
    const unsigned short* hi = (mat == 0) ? Ah_ : Bh_;
    const unsigned short* lo = (mat == 0) ? Al_ : Bl_;
    const int rowg = (mat == 0) ? rowList[row0p + r] : (col0 + r);
    gsrc[j]  = ((gl < 4) ? hi : lo) + (size_t)rowg * DIM + co;
    ldsoff[j] = (unsigned)(mat * 16384 + chunk * 1024);
  }

  const int fr16 = lane & 15;
  const int kg   = lane >> 4;
  int ra[2], rb[4];
  #pragma unroll
  for (int f = 0; f < 2; ++f) ra[f] = wr + (f << 4) + fr16;
  #pragma unroll
  for (int f = 0; f < 4; ++f) rb[f] = wc + (f << 4) + fr16;

  #define LDFRAG(bf, mat, r, hb) \
    (*(const h8v*)((const char*)sAB + (bf) * 32768 + (mat) * 16384 + (r) * 128 + (((((hb) + kg) ^ ((r) & 7)) << 4))))
  #define STAGE(bf, ko)                                                       \
    {                                                                         \
      _Pragma("unroll")                                                       \
      for (int j = 0; j < 4; ++j)                                             \
        gload16(gsrc[j] + (ko), (char*)sAB + (bf) * 32768 + ldsoff[j]);       \
    }

  int cur = 0;
  STAGE(0, 0);
  __syncthreads();

  for (int kt = 0; kt < DIM / 32; ++kt){
    if (kt < DIM / 32 - 1) STAGE(cur ^ 1, (kt + 1) << 5);

    h8v Ahf[2], Bhf[4], Xl[4];
    #pragma unroll
    for (int f = 0; f < 2; ++f) Ahf[f] = LDFRAG(cur, 0, ra[f], 0);
    #pragma unroll
    for (int f = 0; f < 4; ++f) Bhf[f] = LDFRAG(cur, 1, rb[f], 0);
    #pragma unroll
    for (int fi = 0; fi < 2; ++fi)
      #pragma unroll
      for (int fj = 0; fj < 4; ++fj)
        acc[fi][fj] = __builtin_amdgcn_mfma_f32_16x16x32_f16(Bhf[fj], Ahf[fi], acc[fi][fj], 0, 0, 0);
    #pragma unroll
    for (int f = 0; f < 2; ++f) Xl[f] = LDFRAG(cur, 0, ra[f], 4);
    #pragma unroll
    for (int fi = 0; fi < 2; ++fi)
      #pragma unroll
      for (int fj = 0; fj < 4; ++fj)
        acc2[fi][fj] = __builtin_amdgcn_mfma_f32_16x16x32_f16(Bhf[fj], Xl[fi], acc2[fi][fj], 0, 0, 0);
    #pragma unroll
    for (int f = 0; f < 4; ++f) Xl[f] = LDFRAG(cur, 1, rb[f], 4);
    #pragma unroll
    for (int fi = 0; fi < 2; ++fi)
      #pragma unroll
      for (int fj = 0; fj < 4; ++fj)
        acc2[fi][fj] = __builtin_amdgcn_mfma_f32_16x16x32_f16(Xl[fj], Ahf[fi], acc2[fi][fj], 0, 0, 0);

    __syncthreads();
    cur ^= 1;
  }
  #undef LDFRAG
  #undef STAGE

  const float LSC = 1.0f / 2048.0f;
  const int nq = (lane >> 4) << 2;
  #pragma unroll
  for (int fi = 0; fi < 2; ++fi){
    float ssum = 0.f;
    #pragma unroll
    for (int fj = 0; fj < 4; ++fj){
      const int gcol = col0 + wc + (fj << 4) + nq;
      const float4 be = *(const float4*)(bias + gcol);
      const float4 wk = *(const float4*)(w2 + gcol);
      float h0 = fmaxf(acc[fi][fj][0] + LSC * acc2[fi][fj][0] + be.x, 0.f);
      float h1 = fmaxf(acc[fi][fj][1] + LSC * acc2[fi][fj][1] + be.y, 0.f);
      float h2 = fmaxf(acc[fi][fj][2] + LSC * acc2[fi][fj][2] + be.z, 0.f);
      float h3 = fmaxf(acc[fi][fj][3] + LSC * acc2[fi][fj][3] + be.w, 0.f);
      ssum = fmaf(h0, wk.x, ssum);
      ssum = fmaf(h1, wk.y, ssum);
      ssum = fmaf(h2, wk.z, ssum);
      ssum = fmaf(h3, wk.w, ssum);
    }
    ssum += __shfl_xor(ssum, 16);
    ssum += __shfl_xor(ssum, 32);
    if (lane < 16){
      const int pos = row0p + wr + (fi << 4) + lane;
      zexact[(size_t)pos * 256 + (bx << 1) + (wc >> 6)] = ssum;
    }
  }
}

// ===========================================================================
// tail kernels
// ===========================================================================
__global__ __launch_bounds__(256)
void zinit(int* __restrict__ rowList, int* __restrict__ nflag)
{
  const int i = blockIdx.x * 256 + threadIdx.x;
  if (i < MAXF) rowList[i] = 0;
  if (i == 0) *nflag = 0;
}

__global__ __launch_bounds__(256)
void zreduce_flag(const float* __restrict__ zpart, const float* __restrict__ bk2,
                  const int* __restrict__ kp, int* __restrict__ mrow,
                  int* __restrict__ rowList, int* __restrict__ nflag)
{
  const int row  = blockIdx.x * 4 + (threadIdx.x >> 6);
  const int lane = threadIdx.x & 63;
  const float* zp = zpart + (size_t)row * 256;
  float s = zp[lane] + zp[lane + 64] + zp[lane + 128] + zp[lane + 192];
  s += __shfl_xor(s, 1);
  s += __shfl_xor(s, 2);
  s += __shfl_xor(s, 4);
  s += __shfl_xor(s, 8);
  s += __shfl_xor(s, 16);
  s += __shfl_xor(s, 32);
  if (lane == 0){
    float z = s + bk2[0];
    float kest = 2.f * (float)(*kp) * (1.f / (1.f + expf(-z)));
    int m = (int)ceilf(kest);
    m = min(max(m, 0), 128);
    mrow[row] = m;
    const float frac = kest - floorf(kest);
    const float dmin = fminf(frac, 1.f - frac);
    if (dmin < 0.1f){
      int p = atomicAdd(nflag, 1);
      if (p < MAXF) rowList[p] = row;
    }
  }
}

__global__ __launch_bounds__(256)
void zreduce2(const float* __restrict__ zexact, const int* __restrict__ rowList,
              const int* __restrict__ nflagp, const float* __restrict__ bk2,
              const int* __restrict__ kp, int* __restrict__ mrow)
{
  const int pos  = blockIdx.x * 4 + (threadIdx.x >> 6);
  const int lane = threadIdx.x & 63;
  const int nf = min(*nflagp, MAXF);
  if (pos >= nf) return;
  const float* zp = zexact + (size_t)pos * 256;
  float s = zp[lane] + zp[lane + 64] + zp[lane + 128] + zp[lane + 192];
  s += __shfl_xor(s, 1);
  s += __shfl_xor(s, 2);
  s += __shfl_xor(s, 4);
  s += __shfl_xor(s, 8);
  s += __shfl_xor(s, 16);
  s += __shfl_xor(s, 32);
  if (lane == 0){
    float z = s + bk2[0];
    float kest = 2.f * (float)(*kp) * (1.f / (1.f + expf(-z)));
    int m = (int)ceilf(kest);
    m = min(max(m, 0), 128);
    mrow[rowList[pos]] = m;
  }
}

__device__ __forceinline__ void radix_find(int* hist, int nbins, int need, int tid,
                                           int* out3, int* blksum)
{
  const int per  = nbins >> 8;
  const int base = tid * per;
  int bs = 0;
  for (int j = 0; j < per; ++j) bs += hist[base + j];
  blksum[tid] = bs;
  __syncthreads();
  if (tid == 0){
    int a2 = 0;
    for (int t = 255; t >= 0; --t){ int v = blksum[t]; blksum[t] = a2; a2 += v; }
  }
  __syncthreads();
  int ch = blksum[tid];
  for (int j = per - 1; j >= 0; --j){
    const int b = base + j;
    const int c = hist[b];
    if (ch < need && need <= ch + c){ out3[0] = b; out3[1] = need - ch; out3[2] = ch; }
    ch += c;
  }
  __syncthreads();
}

// Band select on fp16 approx acts:
//  - radix-find m-th approx value vm (2048-bin hist on u16 bits [15:5],
//    then exact low-5-bit scan among bin1 candidates)
//  - definite: approx > vm + EPS2; ambiguous within +-EPS2 -> exact fp64
__global__ __launch_bounds__(256)
void select_band(const _Float16* __restrict__ acts16, const float* __restrict__ x,
                 const float* __restrict__ bdec, const float* __restrict__ Wenc,
                 const int* __restrict__ mrow, int* __restrict__ selIdx,
                 float* __restrict__ selVal, int* __restrict__ scount)
{
  __shared__ int hist[2048];        // later reused as float xcs[2048]
  __shared__ int blksum[256];
  __shared__ int out3[4];
  __shared__ unsigned short listU[2048];
  __shared__ int listI[2048];
  __shared__ int h32[32];
  __shared__ int lcnt, dcnt, acnt;
  __shared__ unsigned short ambU[64];
  __shared__ int ambI[64];
  __shared__ double ambE[64];
  __shared__ double wred[4];

  const int row = blockIdx.x, tid = threadIdx.x;
  const int m = mrow[row];
  const unsigned short* rp = (const unsigned short*)(acts16 + (size_t)row * FEAT);
  const int base = row << 7;

  for (int i = tid; i < 2048; i += 256) hist[i] = 0;
  __syncthreads();
  // pass 1: hist of u16 >> 5 (8 fp16 per uint4 read)
  for (int it = 0; it < 8; ++it){
    const int i8 = (it << 8) + tid;               // 0..2047
    const uint4 u4 = *(const uint4*)(rp + i8 * 8);
    #pragma unroll
    for (int w = 0; w < 4; ++w){
      const unsigned ww = (&u4.x)[w];
      const unsigned a = ww & 0xFFFFu, b = ww >> 16;
      if (a) atomicAdd(&hist[a >> 5], 1);
      if (b) atomicAdd(&hist[b >> 5], 1);
    }
  }
  __syncthreads();
  radix_find(hist, 2048, m, tid, out3, blksum);
  const int bin1 = out3[0];
  const int rem1 = out3[1];
  const int bin1m1 = (bin1 > 1) ? bin1 - 1 : 1;

  if (tid == 0){ lcnt = 0; dcnt = 0; acnt = 0; }
  if (tid < 32) h32[tid] = 0;
  __syncthreads();
  // pass 2: collect (u16, idx) for bins >= bin1-1
  for (int it = 0; it < 8; ++it){
    const int i8 = (it << 8) + tid;
    const uint4 u4 = *(const uint4*)(rp + i8 * 8);
    const int ib = i8 << 3;
    #pragma unroll
    for (int w = 0; w < 4; ++w){
      const unsigned ww = (&u4.x)[w];
      const unsigned a = ww & 0xFFFFu, b = ww >> 16;
      if ((int)(a >> 5) >= bin1m1){
        int p = atomicAdd(&lcnt, 1);
        if (p < 2048){ listU[p] = (unsigned short)a; listI[p] = ib + 2 * w; }
      }
      if ((int)(b >> 5) >= bin1m1){
        int p = atomicAdd(&lcnt, 1);
        if (p < 2048){ listU[p] = (unsigned short)b; listI[p] = ib + 2 * w + 1; }
      }
    }
  }
  __syncthreads();
  const int L = min(lcnt, 2048);

  // exact vm: rem1-th largest low-5-bit value among bin1 elements
  for (int i = tid; i < L; i += 256){
    const unsigned u = listU[i];
    if ((int)(u >> 5) == bin1) atomicAdd(&h32[u & 31], 1);
  }
  __syncthreads();
  if (tid == 0){
    int c = 0, b3 = 0;
    for (int j = 31; j >= 0; --j){
      c += h32[j];
      if (c >= rem1){ b3 = j; break; }
    }
    out3[3] = b3;
  }
  __syncthreads();
  const unsigned short vm16 = (unsigned short)(((unsigned)bin1 << 5) | (unsigned)out3[3]);
  const float vmf = (float)__builtin_bit_cast(_Float16, vm16);
  const float EPS2 = 0.01f;
  const float lo_cut = vmf - EPS2, hi_cut = vmf + EPS2;

  for (int i = tid; i < L; i += 256){
    const float f = (float)__builtin_bit_cast(_Float16, listU[i]);
    if (f > hi_cut){
      int p = atomicAdd(&dcnt, 1);
      selIdx[base + p] = listI[i];
      selVal[base + p] = f;
    } else if (f >= lo_cut){
      int p = atomicAdd(&acnt, 1);
      if (p < 64){ ambU[p] = listU[i]; ambI[p] = listI[i]; }
    }
  }
  __syncthreads();
  const int D = dcnt;
  const int A = min(acnt, 64);
  int need = m - D;
  if (need < 0) need = 0;
  if (need > A) need = A;

  if (need > 0){
    float* xcs = (float*)hist;
    for (int j = tid; j < DIM; j += 256)
      xcs[j] = x[(size_t)row * DIM + j] - bdec[j];
    __syncthreads();
    const int lane = tid & 63, wv = tid >> 6;
    for (int c = 0; c < A; ++c){
      const float* wrow = Wenc + (size_t)ambI[c] * DIM;
      double sd = 0.0;
      for (int j = tid; j < DIM; j += 256)
        sd += (double)xcs[j] * (double)wrow[j];
      #pragma unroll
      for (int off = 32; off; off >>= 1) sd += __shfl_xor(sd, off);
      if (lane == 0) wred[wv] = sd;
      __syncthreads();
      if (tid == 0) ambE[c] = wred[0] + wred[1] + wred[2] + wred[3];
      __syncthreads();
    }
    if (tid == 0){
      for (int e = 0; e < need; ++e){
        int best = -1;
        for (int c = 0; c < A; ++c){
          if (ambI[c] < 0) continue;
          if (best < 0 || ambE[c] > ambE[best] ||
              (ambE[c] == ambE[best] && ambI[c] < ambI[best])) best = c;
        }
        selIdx[base + D + e] = ambI[best];
        selVal[base + D + e] = (float)__builtin_bit_cast(_Float16, ambU[best]);
        ambI[best] = -1;
      }
    }
  }
  if (tid == 0) scount[row] = D + need;
}

// W_dec [DIM][FEAT] fp32 -> WdT16 [FEAT][DIM] fp16
__global__ __launch_bounds__(256)
void transpose_dec(const float* __restrict__ Wd, _Float16* __restrict__ WdT16)
{
  __shared__ float t[64][65];
  const int f0 = blockIdx.x << 6, d0 = blockIdx.y << 6;
  const int tx = threadIdx.x & 15, ty = threadIdx.x >> 4;
  #pragma unroll
  for (int r = 0; r < 4; ++r){
    const int d = ty + (r << 4);
    const float4 v = *(const float4*)(Wd + (size_t)(d0 + d) * FEAT + f0 + (tx << 2));
    t[d][(tx << 2) + 0] = v.x;
    t[d][(tx << 2) + 1] = v.y;
    t[d][(tx << 2) + 2] = v.z;
    t[d][(tx << 2) + 3] = v.w;
  }
  __syncthreads();
  #pragma unroll
  for (int r = 0; r < 4; ++r){
    const int f = ty + (r << 4);
    ushort4 o;
    o.x = __builtin_bit_cast(unsigned short, (_Float16)t[(tx << 2) + 0][f]);
    o.y = __builtin_bit_cast(unsigned short, (_Float16)t[(tx << 2) + 1][f]);
    o.z = __builtin_bit_cast(unsigned short, (_Float16)t[(tx << 2) + 2][f]);
    o.w = __builtin_bit_cast(unsigned short, (_Float16)t[(tx << 2) + 3][f]);
    *(ushort4*)(WdT16 + (size_t)(f0 + f) * DIM + d0 + (tx << 2)) = o;
  }
}

__global__ __launch_bounds__(256)
void decode_k(const _Float16* __restrict__ WdT16, const int* __restrict__ selIdx,
              const float* __restrict__ selVal, const int* __restrict__ scount,
              const float* __restrict__ bdec, float* __restrict__ out)
{
  __shared__ int   sI[128];
  __shared__ float sV[128];
  const int row = blockIdx.x, tid = threadIdx.x;
  const int m = scount[row];
  if (tid < m){
    sI[tid] = selIdx[(row << 7) + tid];
    sV[tid] = selVal[(row << 7) + tid];
  }
  __syncthreads();
  const int d = tid << 3;
  float a[8];
  {
    const float4 b0 = *(const float4*)(bdec + d);
    const float4 b1 = *(const float4*)(bdec + d + 4);
    a[0] = b0.x; a[1] = b0.y; a[2] = b0.z; a[3] = b0.w;
    a[4] = b1.x; a[5] = b1.y; a[6] = b1.z; a[7] = b1.w;
  }
  for (int i = 0; i < m; ++i){
    const float v = sV[i];
    const h8v w = *(const h8v*)(WdT16 + (size_t)sI[i] * DIM + d);
    #pragma unroll
    for (int j = 0; j < 8; ++j)
      a[j] = fmaf(v, (float)w[j], a[j]);
  }
  float4 o0 = {a[0], a[1], a[2], a[3]};
  float4 o1 = {a[4], a[5], a[6], a[7]};
  *(float4*)(out + (size_t)row * DIM + d)     = o0;
  *(float4*)(out + (size_t)row * DIM + d + 4) = o1;
}

// ===========================================================================
extern "C" void kernel_launch(void* const* d_in, const int* in_sizes, int n_in,
                              void* d_out, int out_size, void* d_ws, size_t ws_size,
                              hipStream_t stream)
{
  const float* x    = (const float*)d_in[0];
  const float* Wenc = (const float*)d_in[1];
  const float* benc = (const float*)d_in[2];
  const float* Wk1  = (const float*)d_in[3];
  const float* bk1  = (const float*)d_in[4];
  const float* Wk2  = (const float*)d_in[5];
  const float* bk2  = (const float*)d_in[6];
  const float* Wdec = (const float*)d_in[7];
  const float* bdec = (const float*)d_in[8];
  const int*   kp   = (const int*)d_in[9];
  float* out = (float*)d_out;

  char* ws = (char*)d_ws;
  const size_t XS_BYTES   = (size_t)BATCH * DIM * 2;      // 16 MB per plane
  const size_t ACTS_BYTES = (size_t)BATCH * FEAT * 4;     // keep 256 MB reservation
  const size_t WP_BYTES   = (size_t)FEAT * DIM * 2;       // 64 MB per plane

  unsigned short* xs0 = (unsigned short*)ws;
  unsigned short* xs1 = (unsigned short*)(ws + XS_BYTES);
  char* p = ws + 2 * XS_BYTES;
  _Float16* acts16 = (_Float16*)p;         // 128 MB used
  _Float16* WdT16  = (_Float16*)p;         // aliased after select (64 MB)
  p += ACTS_BYTES;
  unsigned short* wk0 = (unsigned short*)p;                   // Wk1 hi
  unsigned short* wk1 = (unsigned short*)(p + WP_BYTES);      // Wk1 lo
  unsigned short* we0 = (unsigned short*)(p + 2 * WP_BYTES);  // Wenc hi
  p += 3 * WP_BYTES;
  float* zpart  = (float*)p;               p += 4194304;
  int*   mrow   = (int*)p;                 p += 16384;
  int*   selIdx = (int*)p;                 p += 2097152;
  float* selVal = (float*)p;               p += 2097152;
  int*   scount = (int*)p;                 p += 16384;
  int*   rowList= (int*)p;                 p += MAXF * 4;
  int*   nflag  = (int*)p;                 p += 128;
  float* zexact = (float*)p;               p += (size_t)MAXF * 256 * 4;

  (void)ws_size; (void)in_sizes; (void)n_in; (void)out_size;

  splitX<<<dim3(BATCH * DIM / 1024), dim3(256), 0, stream>>>(x, bdec, xs0, xs1);
  splitW<<<dim3(FEAT * DIM / 1024), dim3(256), 0, stream>>>(Wk1, wk0, wk1);
  splitW1<<<dim3(FEAT * DIM / 1024), dim3(256), 0, stream>>>(Wenc, we0);
  // fused dual GEMM: acts16 (approx) + kest zpart (approx)
  gemmd<<<dim3(4096), dim3(256), 0, stream>>>(xs0, we0, wk0, benc, bk1, Wk2,
                                              acts16, zpart);
  zinit<<<dim3(MAXF / 256), dim3(256), 0, stream>>>(rowList, nflag);
  zreduce_flag<<<dim3(BATCH / 4), dim3(256), 0, stream>>>(zpart, bk2, kp, mrow,
                                                          rowList, nflag);
  // exact recompute of flagged rows only
  gemmx<<<dim3(16 * 128), dim3(512), 0, stream>>>(xs0, xs1, wk0, wk1, bk1, Wk2,
                                                  rowList, nflag, zexact);
  zreduce2<<<dim3(MAXF / 4), dim3(256), 0, stream>>>(zexact, rowList, nflag,
                                                     bk2, kp, mrow);
  select_band<<<dim3(BATCH), dim3(256), 0, stream>>>(acts16, x, bdec, Wenc, mrow,
                                                     selIdx, selVal, scount);
  transpose_dec<<<dim3(FEAT / 64, DIM / 64), dim3(256), 0, stream>>>(Wdec, WdT16);
  decode_k<<<dim3(BATCH), dim3(256), 0, stream>>>(WdT16, selIdx, selVal, scount, bdec, out);
}